// Round 1
// 392.438 us; speedup vs baseline: 1.0704x; 1.0704x over previous
//
#include <hip/hip_runtime.h>
#include <hip/hip_bf16.h>

typedef unsigned short ushort_t;
typedef __attribute__((ext_vector_type(8))) short short8;
typedef __attribute__((ext_vector_type(4))) float floatx4;

#define B_  2
#define S_  2048
#define DM_ 2048
#define H_  16
#define DH_ 128

#define AS1(p) ((const __attribute__((address_space(1))) void*)(p))
#define AS3(p) ((__attribute__((address_space(3))) void*)(p))

static __device__ __forceinline__ float b2f(ushort_t u) {
  __hip_bfloat16 h = *reinterpret_cast<__hip_bfloat16*>(&u);
  return __bfloat162float(h);
}
static __device__ __forceinline__ ushort_t f2b(float f) {
  __hip_bfloat16 h = __float2bfloat16(f);
  return *reinterpret_cast<ushort_t*>(&h);
}

// ---------------------------------------------------------------------------
// x (f32) -> bf16, 8 elems/thread.
// ---------------------------------------------------------------------------
__global__ __launch_bounds__(256) void convert_f32_bf16(const float* __restrict__ in,
                                                        ushort_t* __restrict__ out) {
  size_t i = ((size_t)blockIdx.x * 256 + threadIdx.x) * 8;
  float4 a = *(const float4*)(in + i);
  float4 b = *(const float4*)(in + i + 4);
  ushort_t tmp[8] = {f2b(a.x), f2b(a.y), f2b(a.z), f2b(a.w),
                     f2b(b.x), f2b(b.y), f2b(b.z), f2b(b.w)};
  *(uint4*)(out + i) = *(const uint4*)tmp;
}

// ---------------------------------------------------------------------------
// out[c][r] = bf16(in[r][colOff + c]); in f32 [R][inC], out bf16 [64*gx][R].
// ---------------------------------------------------------------------------
__global__ __launch_bounds__(256) void transpose_f32_to_bf16T(const float* __restrict__ in,
                                                              ushort_t* __restrict__ out,
                                                              int R, int inC, int colOff) {
  __shared__ ushort_t tile[64][72];
  const int tid = threadIdx.x;
  const int r0 = blockIdx.y * 64, c0 = blockIdx.x * 64;
#pragma unroll
  for (int p = 0; p < 2; ++p) {
    int li = tid + p * 256;
    int r = li >> 3, cs = (li & 7) * 8;
    const float* src = in + (size_t)(r0 + r) * inC + colOff + c0 + cs;
    float4 a = *(const float4*)src;
    float4 b = *(const float4*)(src + 4);
    ushort_t tmp[8] = {f2b(a.x), f2b(a.y), f2b(a.z), f2b(a.w),
                       f2b(b.x), f2b(b.y), f2b(b.z), f2b(b.w)};
    *(uint4*)&tile[r][cs] = *(const uint4*)tmp;
  }
  __syncthreads();
#pragma unroll
  for (int p = 0; p < 2; ++p) {
    int li = tid + p * 256;
    int cR = li >> 3, rs = (li & 7) * 8;
    ushort_t tmp[8];
#pragma unroll
    for (int e = 0; e < 8; ++e) tmp[e] = tile[rs + e][cR];
    *(uint4*)(out + (size_t)(c0 + cR) * R + r0 + rs) = *(const uint4*)tmp;
  }
}

// ---------------------------------------------------------------------------
// GEMM v2 (128x128 tile, kept for the M/N=2048 GEMMs where a 256^2 grid
// would only fill half the CUs).
// MODE 0: C bf16, ld=N.  MODE 1: C f32, ld=N.
// ---------------------------------------------------------------------------
template <int MODE>
__global__ __launch_bounds__(256) void gemm_bt_async(const ushort_t* __restrict__ A,
                                                     const ushort_t* __restrict__ Bt,
                                                     void* __restrict__ C0,
                                                     void* __restrict__ C1,
                                                     int M, int N, int K) {
  __shared__ alignas(16) ushort_t As[2][128 * 32];
  __shared__ alignas(16) ushort_t Bs[2][128 * 32];
  const int tid = threadIdx.x;
  const int wave = tid >> 6, lane = tid & 63;
  const int l15 = lane & 15, quad = lane >> 4;
  const int wr = (wave >> 1) * 64, wc = (wave & 1) * 64;
  const int lin = blockIdx.y * gridDim.x + blockIdx.x;
  const int band = lin / (4 * gridDim.x);
  const int rin = lin % (4 * gridDim.x);
  const int by = band * 4 + (rin & 3);
  const int bx = rin >> 2;
  const size_t m0 = (size_t)by * 128, n0 = (size_t)bx * 128;
  const int srow = lane >> 2, scol = (lane & 3) * 8;

  floatx4 zero = {0.f, 0.f, 0.f, 0.f};
  floatx4 acc[4][4];
#pragma unroll
  for (int i = 0; i < 4; ++i)
#pragma unroll
    for (int j = 0; j < 4; ++j) acc[i][j] = zero;

  auto stage = [&](int kt, int bf) {
#pragma unroll
    for (int i = 0; i < 2; ++i) {
      int c = wave * 2 + i;
      int row = c * 16 + srow;
      __builtin_amdgcn_global_load_lds(AS1(A + (m0 + row) * K + kt + scol),
                                       AS3((char*)As[bf] + c * 1024), 16, 0, 0);
      __builtin_amdgcn_global_load_lds(AS1(Bt + (n0 + row) * K + kt + scol),
                                       AS3((char*)Bs[bf] + c * 1024), 16, 0, 0);
    }
  };

  stage(0, 0);
  const int niter = K / 32;
  for (int it = 0; it < niter; ++it) {
    const int cur = it & 1;
    __syncthreads();
    if (it + 1 < niter) stage((it + 1) * 32, cur ^ 1);

    short8 af[4], bfr[4];
#pragma unroll
    for (int i = 0; i < 4; ++i)
      af[i] = *(const short8*)&As[cur][(wr + i * 16 + l15) * 32 + quad * 8];
#pragma unroll
    for (int j = 0; j < 4; ++j)
      bfr[j] = *(const short8*)&Bs[cur][(wc + j * 16 + l15) * 32 + quad * 8];
#pragma unroll
    for (int i = 0; i < 4; ++i)
#pragma unroll
      for (int j = 0; j < 4; ++j)
        acc[i][j] = __builtin_amdgcn_mfma_f32_16x16x32_bf16(af[i], bfr[j], acc[i][j], 0, 0, 0);
  }

#pragma unroll
  for (int i = 0; i < 4; ++i)
#pragma unroll
    for (int j = 0; j < 4; ++j)
#pragma unroll
      for (int r = 0; r < 4; ++r) {
        size_t row = m0 + wr + i * 16 + quad * 4 + r;
        size_t col = n0 + wc + j * 16 + l15;
        if (MODE == 1)
          ((float*)C0)[row * N + col] = acc[i][j][r];
        else
          ((ushort_t*)C0)[row * N + col] = f2b(acc[i][j][r]);
      }
}

// ---------------------------------------------------------------------------
// GEMM 256x256, BK=64, 8 waves (2Mx4N), 8-phase schedule with counted vmcnt.
// LDS 128 KiB: As[2][256*64], Bs[2][256*64], XOR-swizzled (cb ^= (row&7)<<4).
// Swizzle applied on the pre-swizzled GLOBAL source of global_load_lds
// (linear LDS dest) and again on the ds_read address (both-sides involution).
// Per K-tile: 4 phases, each { ds_read subtile | stage 1 half-tile |
//   s_barrier | setprio(1) 16 MFMA setprio(0) | s_barrier }, vmcnt(4) once
// per tile (drain to 0 only in the last two tiles).  Assumes K >= 128.
// MODE 2: C bf16 split: cols [0,2048)->C0, [2048,4096)->C1, ld=2048.
// ---------------------------------------------------------------------------
#define SBAR() __builtin_amdgcn_sched_barrier(0)
#define BARR() __builtin_amdgcn_s_barrier()

#define LDS_A(qm, bb)                                                          \
  _Pragma("unroll") for (int mi = 0; mi < 4; ++mi) {                           \
    _Pragma("unroll") for (int ks = 0; ks < 2; ++ks) {                         \
      const int r_ = arow + (qm) * 64 + mi * 16;                               \
      const int cb_ = ((ks) * 64 + quad * 16) ^ swz;                           \
      afr[qm][mi][ks] =                                                        \
          *(const short8*)((const char*)As[bb] + r_ * 128 + cb_);              \
    }                                                                          \
  }

#define LDS_B(qn, bb)                                                          \
  _Pragma("unroll") for (int ni = 0; ni < 2; ++ni) {                           \
    _Pragma("unroll") for (int ks = 0; ks < 2; ++ks) {                         \
      const int r_ = brow + (qn) * 32 + ni * 16;                               \
      const int cb_ = ((ks) * 64 + quad * 16) ^ swz;                           \
      bfr[qn][ni][ks] =                                                        \
          *(const short8*)((const char*)Bs[bb] + r_ * 128 + cb_);              \
    }                                                                          \
  }

#define MMA_Q(qm, qn)                                                          \
  _Pragma("unroll") for (int mi = 0; mi < 4; ++mi) {                           \
    _Pragma("unroll") for (int ni = 0; ni < 2; ++ni) {                         \
      floatx4 t_ = acc[(qm) * 4 + mi][(qn) * 2 + ni];                          \
      t_ = __builtin_amdgcn_mfma_f32_16x16x32_bf16(afr[qm][mi][0],             \
                                                   bfr[qn][ni][0], t_, 0, 0, 0); \
      t_ = __builtin_amdgcn_mfma_f32_16x16x32_bf16(afr[qm][mi][1],             \
                                                   bfr[qn][ni][1], t_, 0, 0, 0); \
      acc[(qm) * 4 + mi][(qn) * 2 + ni] = t_;                                  \
    }                                                                          \
  }

template <int MODE>
__global__ __launch_bounds__(512, 2) void gemm_bt_256(const ushort_t* __restrict__ A,
                                                      const ushort_t* __restrict__ Bt,
                                                      void* __restrict__ C0,
                                                      void* __restrict__ C1,
                                                      int M, int N, int K) {
  __shared__ alignas(16) ushort_t As[2][256 * 64];
  __shared__ alignas(16) ushort_t Bs[2][256 * 64];
  const int tid = threadIdx.x;
  const int wave = tid >> 6, lane = tid & 63;
  const int l15 = lane & 15, quad = lane >> 4;
  const int wm = wave >> 2, wn = wave & 3;  // 2 x 4 wave grid
  const size_t m0 = (size_t)blockIdx.y * 256, n0 = (size_t)blockIdx.x * 256;
  const int nkt = K >> 6;  // K-tiles of 64

  // staging lane constants: chunk = 8 rows x 128B; source k pre-swizzled so
  // the linear LDS dest holds swizzled data.
  const int srow = lane >> 3;                 // row within 8-row chunk
  const int skk = ((lane & 7) ^ srow) * 8;    // swizzled k offset (bf16)

  // frag-read constants
  const int arow = wm * 128 + l15;
  const int brow = wn * 64 + l15;
  const int swz = (l15 & 7) << 4;

  floatx4 zero = {0.f, 0.f, 0.f, 0.f};
  floatx4 acc[8][4];
#pragma unroll
  for (int i = 0; i < 8; ++i)
#pragma unroll
    for (int j = 0; j < 4; ++j) acc[i][j] = zero;

  short8 afr[2][4][2];  // [qm][mi][ks]
  short8 bfr[2][2][2];  // [qn][ni][ks]

  // half-tiles: 0=A rows 0..127, 1=A rows 128..255, 2=B rows 0..127, 3=B rows 128..255
  auto stage_half = [&](int t, int ht) {
    if (t >= nkt) return;
    const int bb = t & 1;
    const int h = ht & 1;
    const int kt64 = t << 6;
    const ushort_t* G = (ht < 2) ? A : Bt;
    const size_t r0 = (ht < 2) ? m0 : n0;
    char* dst = (char*)((ht < 2) ? As[bb] : Bs[bb]) + h * 16384;
#pragma unroll
    for (int i = 0; i < 2; ++i) {
      const int c = wave * 2 + i;
      const size_t gr = r0 + h * 128 + c * 8 + srow;
      __builtin_amdgcn_global_load_lds(AS1(G + gr * K + kt64 + skk),
                                       AS3(dst + c * 1024), 16, 0, 0);
    }
  };

  // prologue: tile 0 fully + A-halves of tile 1 (12 loads/thread)
  stage_half(0, 0); stage_half(0, 1); stage_half(0, 2); stage_half(0, 3);
  stage_half(1, 0); stage_half(1, 1);
  SBAR();
  if (nkt > 1) { asm volatile("s_waitcnt vmcnt(4)" ::: "memory"); }
  else         { asm volatile("s_waitcnt vmcnt(0)" ::: "memory"); }
  SBAR(); BARR(); SBAR();

  for (int kt = 0; kt < nkt; ++kt) {
    const int bb = kt & 1;
    // ---- phase 1: read A[qm0]+B[qn0]; stage B-half0 of tile kt+1 -> other buf
    LDS_A(0, bb); LDS_B(0, bb);
    stage_half(kt + 1, 2);
    SBAR(); BARR(); SBAR();
    __builtin_amdgcn_s_setprio(1);
    MMA_Q(0, 0);
    __builtin_amdgcn_s_setprio(0);
    SBAR(); BARR(); SBAR();
    // ---- phase 2: read A[qm1]; stage B-half1 of tile kt+1 -> other buf
    LDS_A(1, bb);
    stage_half(kt + 1, 3);
    SBAR(); BARR(); SBAR();
    __builtin_amdgcn_s_setprio(1);
    MMA_Q(1, 0);
    __builtin_amdgcn_s_setprio(0);
    SBAR(); BARR(); SBAR();
    // ---- phase 3: read B[qn1]; stage A-half0 of tile kt+2 -> this buf
    //      (As[bb] reads retired by phase-2 closing barrier)
    LDS_B(1, bb);
    stage_half(kt + 2, 0);
    SBAR(); BARR(); SBAR();
    __builtin_amdgcn_s_setprio(1);
    MMA_Q(1, 1);
    __builtin_amdgcn_s_setprio(0);
    SBAR(); BARR(); SBAR();
    // ---- phase 4: stage A-half1 of tile kt+2 -> this buf
    stage_half(kt + 2, 1);
    SBAR(); BARR(); SBAR();
    __builtin_amdgcn_s_setprio(1);
    MMA_Q(0, 1);
    __builtin_amdgcn_s_setprio(0);
    SBAR();
    // counted wait: retire all of tile kt+1 (8 oldest), keep tile kt+2's
    // A-halves (4) in flight; drain only when no further prefetch exists.
    if (kt + 2 < nkt) { asm volatile("s_waitcnt vmcnt(4)" ::: "memory"); }
    else              { asm volatile("s_waitcnt vmcnt(0)" ::: "memory"); }
    SBAR(); BARR(); SBAR();
  }

  // epilogue
  if (MODE == 2) {
    ushort_t* Cb = (n0 >= 2048) ? (ushort_t*)C1 : (ushort_t*)C0;
    size_t nc0 = n0 & 2047;
#pragma unroll
    for (int mi8 = 0; mi8 < 8; ++mi8)
#pragma unroll
      for (int nj = 0; nj < 4; ++nj)
#pragma unroll
        for (int r = 0; r < 4; ++r) {
          size_t row = m0 + wm * 128 + (mi8 >> 2) * 64 + (mi8 & 3) * 16 + quad * 4 + r;
          size_t col = nc0 + wn * 64 + (nj >> 1) * 32 + (nj & 1) * 16 + l15;
          Cb[row * 2048 + col] = f2b(acc[mi8][nj][r]);
        }
  } else {
#pragma unroll
    for (int mi8 = 0; mi8 < 8; ++mi8)
#pragma unroll
      for (int nj = 0; nj < 4; ++nj)
#pragma unroll
        for (int r = 0; r < 4; ++r) {
          size_t row = m0 + wm * 128 + (mi8 >> 2) * 64 + (mi8 & 3) * 16 + quad * 4 + r;
          size_t col = n0 + wn * 64 + (nj >> 1) * 32 + (nj & 1) * 16 + l15;
          if (MODE == 1)
            ((float*)C0)[row * N + col] = acc[mi8][nj][r];
          else
            ((ushort_t*)C0)[row * N + col] = f2b(acc[mi8][nj][r]);
        }
  }
}

// ---------------------------------------------------------------------------
// unit-norm + RoPE (even heads) + gain-fold, in place. One wave per (b,s,h).
// ---------------------------------------------------------------------------
__global__ __launch_bounds__(256) void norm_rope(ushort_t* __restrict__ Q,
                                                 ushort_t* __restrict__ Kb,
                                                 const float* __restrict__ gain) {
  const int tid = threadIdx.x;
  const int wave = tid >> 6, lane = tid & 63;
  const int idx = blockIdx.x * 4 + wave;  // ((b*S+s)*H + h)
  const int h = idx & 15;
  const int s = (idx >> 4) & (S_ - 1);
  const size_t off = (size_t)(idx >> 4) * DM_ + h * DH_;

  float q1 = b2f(Q[off + lane]),  q2 = b2f(Q[off + 64 + lane]);
  float k1 = b2f(Kb[off + lane]), k2 = b2f(Kb[off + 64 + lane]);

  float sq = q1 * q1 + q2 * q2;
  float sk = k1 * k1 + k2 * k2;
#pragma unroll
  for (int o = 1; o < 64; o <<= 1) {
    sq += __shfl_xor(sq, o, 64);
    sk += __shfl_xor(sk, o, 64);
  }
  float rq = rsqrtf(sq + 1e-6f), rk = rsqrtf(sk + 1e-6f);
  q1 *= rq; q2 *= rq; k1 *= rk; k2 *= rk;

  float qo1 = q1, qo2 = q2, ko1 = k1, ko2 = k2;
  if ((h & 1) == 0) {  // ROPE_MASK tiles [1,0] over heads: even heads roped
    float invf = powf(10000.0f, -(float)lane * (1.0f / 64.0f));
    float th = (float)s * invf;
    float c = cosf(th), sn = sinf(th);
    qo1 = q1 * c - q2 * sn;  qo2 = q1 * sn + q2 * c;
    ko1 = k1 * c - k2 * sn;  ko2 = k1 * sn + k2 * c;
  }
  float g = gain[h];
  qo1 *= g; qo2 *= g;

  Q[off + lane]       = f2b(qo1);
  Q[off + 64 + lane]  = f2b(qo2);
  Kb[off + lane]      = f2b(ko1);
  Kb[off + 64 + lane] = f2b(ko2);
}

// ---------------------------------------------------------------------------
// Flash attention v3: balanced tile pairs {p, 31-p}, fixed-max softmax
// (M0=13), double-buffered K/V, per-wave Ps, 1 barrier/iter.
// V layout: [dim][b*S+s]. Y written in place over Q.
// ---------------------------------------------------------------------------
__global__ __launch_bounds__(256, 2) void attn(ushort_t* __restrict__ QY,
                                               const ushort_t* __restrict__ Kg,
                                               const ushort_t* __restrict__ Vg) {
  __shared__ alignas(16) ushort_t Ks[2][64 * 128];
  __shared__ alignas(16) ushort_t Vs[2][128 * 64];
  __shared__ alignas(16) ushort_t Ps[2][4][16 * 64];

  const float M0 = 13.0f;
  const int tid = threadIdx.x;
  const int wave = tid >> 6, lane = tid & 63;
  const int l15 = lane & 15, quad = lane >> 4;
  const int bh = blockIdx.y;
  const int b = bh >> 4, h = bh & 15;
  const int p = blockIdx.x;
  const int qt[2] = {p, 31 - p};

  const ushort_t* Kgb = Kg + (size_t)b * S_ * DM_ + h * DH_;
  const ushort_t* Vgb = Vg + (size_t)(h * DH_) * (B_ * S_) + b * S_;

  short8 aq[2][4];
#pragma unroll
  for (int t = 0; t < 2; ++t) {
    const ushort_t* Qg =
        QY + (size_t)(b * S_ + qt[t] * 64 + wave * 16 + l15) * DM_ + h * DH_;
#pragma unroll
    for (int ks = 0; ks < 4; ++ks)
      aq[t][ks] = *(const short8*)(Qg + ks * 32 + quad * 8);
  }

  float lsum[2][4] = {{0.f, 0.f, 0.f, 0.f}, {0.f, 0.f, 0.f, 0.f}};
  floatx4 zero = {0.f, 0.f, 0.f, 0.f};
  floatx4 oacc[2][8];
#pragma unroll
  for (int t = 0; t < 2; ++t)
#pragma unroll
    for (int d = 0; d < 8; ++d) oacc[t][d] = zero;

  const int krow_in = lane >> 4, ksd = lane & 15;
  const int vrow_in = lane >> 3, vsd = lane & 7;

  auto stage = [&](int kt, int bf) {
#pragma unroll
    for (int i = 0; i < 4; ++i) {
      int c = wave * 4 + i;
      {
        int r = c * 4 + krow_in;
        int sg = ksd ^ (r & 7);
        __builtin_amdgcn_global_load_lds(
            AS1(Kgb + (size_t)(kt * 64 + r) * DM_ + sg * 8),
            AS3((char*)Ks[bf] + c * 1024), 16, 0, 0);
      }
      {
        int r = c * 8 + vrow_in;
        int sg = vsd ^ (r & 7);
        __builtin_amdgcn_global_load_lds(
            AS1(Vgb + (size_t)r * (B_ * S_) + kt * 64 + sg * 8),
            AS3((char*)Vs[bf] + c * 1024), 16, 0, 0);
      }
    }
  };

  stage(0, 0);

  for (int kt = 0; kt <= qt[1]; ++kt) {
    const int cur = kt & 1;
    __syncthreads();
    if (kt < qt[1]) stage(kt + 1, cur ^ 1);

#pragma unroll
    for (int t = 0; t < 2; ++t) {
      if (t == 0 && kt > qt[0]) continue;
      floatx4 sacc[4];
#pragma unroll
      for (int j = 0; j < 4; ++j) sacc[j] = zero;
#pragma unroll
      for (int ks = 0; ks < 4; ++ks) {
#pragma unroll
        for (int j = 0; j < 4; ++j) {
          int row = j * 16 + l15;
          int sl = (ks * 4 + quad) ^ (row & 7);
          short8 bk = *(const short8*)&Ks[cur][row * 128 + sl * 8];
          sacc[j] = __builtin_amdgcn_mfma_f32_16x16x32_bf16(aq[t][ks], bk, sacc[j], 0, 0, 0);
        }
      }
      if (kt == qt[t]) {
#pragma unroll
        for (int j = 0; j < 4; ++j)
#pragma unroll
          for (int r = 0; r < 4; ++r) {
            int key = j * 16 + l15;
            int qr = wave * 16 + quad * 4 + r;
            if (key > qr) sacc[j][r] = -1e30f;
          }
      }
#pragma unroll
      for (int j = 0; j < 4; ++j)
#pragma unroll
        for (int r = 0; r < 4; ++r) {
          float pv = __expf(sacc[j][r] - M0);
          sacc[j][r] = pv;
          lsum[t][r] += pv;
        }
#pragma unroll
      for (int j = 0; j < 4; ++j)
#pragma unroll
        for (int r = 0; r < 4; ++r) {
          int row = quad * 4 + r;
          int col = j * 16 + l15;
          int g = col >> 3, w = col & 7;
          Ps[t][wave][row * 64 + ((g ^ (row & 7)) << 3) + w] = f2b(sacc[j][r]);
        }
#pragma unroll
      for (int ks2 = 0; ks2 < 2; ++ks2) {
        short8 ap = *(const short8*)&Ps[t][wave][l15 * 64 +
                                                (((ks2 * 4 + quad) ^ (l15 & 7)) << 3)];
#pragma unroll
        for (int d = 0; d < 8; ++d) {
          int row = d * 16 + l15;
          int sl = (ks2 * 4 + quad) ^ (row & 7);
          short8 bv = *(const short8*)&Vs[cur][row * 64 + sl * 8];
          oacc[t][d] = __builtin_amdgcn_mfma_f32_16x16x32_bf16(ap, bv, oacc[t][d], 0, 0, 0);
        }
      }
    }
  }

#pragma unroll
  for (int t = 0; t < 2; ++t) {
#pragma unroll
    for (int r = 0; r < 4; ++r) {
#pragma unroll
      for (int o = 1; o < 16; o <<= 1) lsum[t][r] += __shfl_xor(lsum[t][r], o, 64);
      float inv = 1.0f / lsum[t][r];
      size_t row = (size_t)(b * S_ + qt[t] * 64 + wave * 16 + quad * 4 + r);
#pragma unroll
      for (int d = 0; d < 8; ++d) {
        size_t col = (size_t)h * DH_ + d * 16 + l15;
        QY[row * DM_ + col] = f2b(oacc[t][d][r] * inv);
      }
    }
  }
}

// ---------------------------------------------------------------------------
extern "C" void kernel_launch(void* const* d_in, const int* in_sizes, int n_in,
                              void* d_out, int out_size, void* d_ws, size_t ws_size,
                              hipStream_t stream) {
  const float* x      = (const float*)d_in[0];
  const float* w_qkv  = (const float*)d_in[1];
  const float* w_out  = (const float*)d_in[2];
  const float* q_gain = (const float*)d_in[3];
  float* out = (float*)d_out;

  // ws (56 MiB, proven): Qraw | Kraw | Vt | wvT
  // d_out (32 MiB) doubles as scratch until the final GEMM: xbf | wqkT
  char* ws = (char*)d_ws;
  const size_t bsd = (size_t)B_ * S_ * DM_;  // 8,388,608 elems
  ushort_t* Qraw = (ushort_t*)ws;
  ushort_t* Kraw = Qraw + bsd;
  ushort_t* Vt   = Kraw + bsd;                    // [dim][b*S+s]
  ushort_t* wvT  = Vt + bsd;                      // [2048][2048]
  ushort_t* xbf  = (ushort_t*)d_out;              // [4096][2048] bf16
  ushort_t* wqkT = xbf + bsd;                     // [4096][2048] bf16 (Wq|Wk)^T
  ushort_t* woutT = Kraw;                         // after attn, Kraw is dead

  convert_f32_bf16<<<dim3(bsd / (8 * 256)), 256, 0, stream>>>(x, xbf);
  transpose_f32_to_bf16T<<<dim3(64, 32), 256, 0, stream>>>(w_qkv, wqkT, DM_, 3 * DM_, 0);
  transpose_f32_to_bf16T<<<dim3(32, 32), 256, 0, stream>>>(w_qkv, wvT, DM_, 3 * DM_, 2 * DM_);

  // Q and K in one fused GEMM (split-C epilogue), 256^2 8-phase kernel:
  // grid 16x16 = 256 blocks = 1 block/CU.
  gemm_bt_256<2><<<dim3(16, 16), 512, 0, stream>>>(xbf, wqkT, Qraw, Kraw,
                                                   B_ * S_, 2 * DM_, DM_);
  // V^T = WvT * x^T  -> Vt[dim][b*S+s]  (M=2048: keep 128^2 kernel, full grid)
  gemm_bt_async<0><<<dim3(32, 16), 256, 0, stream>>>(wvT, xbf, Vt, nullptr,
                                                     DM_, B_ * S_, DM_);
  norm_rope<<<dim3(B_ * S_ * H_ / 4), 256, 0, stream>>>(Qraw, Kraw, q_gain);
  attn<<<dim3(S_ / 128, B_ * H_), 256, 0, stream>>>(Qraw, Kraw, Vt);
  // w_out^T into dead Kraw region, then final GEMM (f32 out over d_out)
  transpose_f32_to_bf16T<<<dim3(32, 32), 256, 0, stream>>>(w_out, woutT, DM_, DM_, 0);
  gemm_bt_async<1><<<dim3(16, 32), 256, 0, stream>>>(Qraw, woutT, out, nullptr,
                                                     B_ * S_, DM_, DM_);
}

// Round 2
// 372.669 us; speedup vs baseline: 1.1272x; 1.0530x over previous
//
#include <hip/hip_runtime.h>
#include <hip/hip_bf16.h>

typedef unsigned short ushort_t;
typedef __attribute__((ext_vector_type(8))) short short8;
typedef __attribute__((ext_vector_type(4))) float floatx4;

#define B_  2
#define S_  2048
#define DM_ 2048
#define H_  16
#define DH_ 128

#define AS1(p) ((const __attribute__((address_space(1))) void*)(p))
#define AS3(p) ((__attribute__((address_space(3))) void*)(p))

static __device__ __forceinline__ float b2f(ushort_t u) {
  __hip_bfloat16 h = *reinterpret_cast<__hip_bfloat16*>(&u);
  return __bfloat162float(h);
}
static __device__ __forceinline__ ushort_t f2b(float f) {
  __hip_bfloat16 h = __float2bfloat16(f);
  return *reinterpret_cast<ushort_t*>(&h);
}
static __device__ __forceinline__ float fast_exp2(float x) {
#if defined(__has_builtin)
#if __has_builtin(__builtin_amdgcn_exp2f)
  return __builtin_amdgcn_exp2f(x);
#else
  return exp2f(x);
#endif
#else
  return exp2f(x);
#endif
}

// ---------------------------------------------------------------------------
// x (f32) -> bf16, 8 elems/thread.
// ---------------------------------------------------------------------------
__global__ __launch_bounds__(256) void convert_f32_bf16(const float* __restrict__ in,
                                                        ushort_t* __restrict__ out) {
  size_t i = ((size_t)blockIdx.x * 256 + threadIdx.x) * 8;
  float4 a = *(const float4*)(in + i);
  float4 b = *(const float4*)(in + i + 4);
  ushort_t tmp[8] = {f2b(a.x), f2b(a.y), f2b(a.z), f2b(a.w),
                     f2b(b.x), f2b(b.y), f2b(b.z), f2b(b.w)};
  *(uint4*)(out + i) = *(const uint4*)tmp;
}

// ---------------------------------------------------------------------------
// out[c][r] = bf16(in[r][colOff + c]); in f32 [R][inC], out bf16 [64*gx][R].
// ---------------------------------------------------------------------------
__global__ __launch_bounds__(256) void transpose_f32_to_bf16T(const float* __restrict__ in,
                                                              ushort_t* __restrict__ out,
                                                              int R, int inC, int colOff) {
  __shared__ ushort_t tile[64][72];
  const int tid = threadIdx.x;
  const int r0 = blockIdx.y * 64, c0 = blockIdx.x * 64;
#pragma unroll
  for (int p = 0; p < 2; ++p) {
    int li = tid + p * 256;
    int r = li >> 3, cs = (li & 7) * 8;
    const float* src = in + (size_t)(r0 + r) * inC + colOff + c0 + cs;
    float4 a = *(const float4*)src;
    float4 b = *(const float4*)(src + 4);
    ushort_t tmp[8] = {f2b(a.x), f2b(a.y), f2b(a.z), f2b(a.w),
                       f2b(b.x), f2b(b.y), f2b(b.z), f2b(b.w)};
    *(uint4*)&tile[r][cs] = *(const uint4*)tmp;
  }
  __syncthreads();
#pragma unroll
  for (int p = 0; p < 2; ++p) {
    int li = tid + p * 256;
    int cR = li >> 3, rs = (li & 7) * 8;
    ushort_t tmp[8];
#pragma unroll
    for (int e = 0; e < 8; ++e) tmp[e] = tile[rs + e][cR];
    *(uint4*)(out + (size_t)(c0 + cR) * R + r0 + rs) = *(const uint4*)tmp;
  }
}

// ---------------------------------------------------------------------------
// GEMM v2 (128x128 tile, kept for the M/N=2048 GEMMs where a 256^2 grid
// would only fill half the CUs).
// MODE 0: C bf16, ld=N.  MODE 1: C f32, ld=N.
// ---------------------------------------------------------------------------
template <int MODE>
__global__ __launch_bounds__(256) void gemm_bt_async(const ushort_t* __restrict__ A,
                                                     const ushort_t* __restrict__ Bt,
                                                     void* __restrict__ C0,
                                                     void* __restrict__ C1,
                                                     int M, int N, int K) {
  __shared__ alignas(16) ushort_t As[2][128 * 32];
  __shared__ alignas(16) ushort_t Bs[2][128 * 32];
  const int tid = threadIdx.x;
  const int wave = tid >> 6, lane = tid & 63;
  const int l15 = lane & 15, quad = lane >> 4;
  const int wr = (wave >> 1) * 64, wc = (wave & 1) * 64;
  const int lin = blockIdx.y * gridDim.x + blockIdx.x;
  const int band = lin / (4 * gridDim.x);
  const int rin = lin % (4 * gridDim.x);
  const int by = band * 4 + (rin & 3);
  const int bx = rin >> 2;
  const size_t m0 = (size_t)by * 128, n0 = (size_t)bx * 128;
  const int srow = lane >> 2, scol = (lane & 3) * 8;

  floatx4 zero = {0.f, 0.f, 0.f, 0.f};
  floatx4 acc[4][4];
#pragma unroll
  for (int i = 0; i < 4; ++i)
#pragma unroll
    for (int j = 0; j < 4; ++j) acc[i][j] = zero;

  auto stage = [&](int kt, int bf) {
#pragma unroll
    for (int i = 0; i < 2; ++i) {
      int c = wave * 2 + i;
      int row = c * 16 + srow;
      __builtin_amdgcn_global_load_lds(AS1(A + (m0 + row) * K + kt + scol),
                                       AS3((char*)As[bf] + c * 1024), 16, 0, 0);
      __builtin_amdgcn_global_load_lds(AS1(Bt + (n0 + row) * K + kt + scol),
                                       AS3((char*)Bs[bf] + c * 1024), 16, 0, 0);
    }
  };

  stage(0, 0);
  const int niter = K / 32;
  for (int it = 0; it < niter; ++it) {
    const int cur = it & 1;
    __syncthreads();
    if (it + 1 < niter) stage((it + 1) * 32, cur ^ 1);

    short8 af[4], bfr[4];
#pragma unroll
    for (int i = 0; i < 4; ++i)
      af[i] = *(const short8*)&As[cur][(wr + i * 16 + l15) * 32 + quad * 8];
#pragma unroll
    for (int j = 0; j < 4; ++j)
      bfr[j] = *(const short8*)&Bs[cur][(wc + j * 16 + l15) * 32 + quad * 8];
#pragma unroll
    for (int i = 0; i < 4; ++i)
#pragma unroll
      for (int j = 0; j < 4; ++j)
        acc[i][j] = __builtin_amdgcn_mfma_f32_16x16x32_bf16(af[i], bfr[j], acc[i][j], 0, 0, 0);
  }

#pragma unroll
  for (int i = 0; i < 4; ++i)
#pragma unroll
    for (int j = 0; j < 4; ++j)
#pragma unroll
      for (int r = 0; r < 4; ++r) {
        size_t row = m0 + wr + i * 16 + quad * 4 + r;
        size_t col = n0 + wc + j * 16 + l15;
        if (MODE == 1)
          ((float*)C0)[row * N + col] = acc[i][j][r];
        else
          ((ushort_t*)C0)[row * N + col] = f2b(acc[i][j][r]);
      }
}

// ---------------------------------------------------------------------------
// GEMM 256x256, BK=64, 8 waves (2Mx4N), 4-phase schedule, counted vmcnt.
// Round-1 change: 2-K-TILE prefetch distance. Per wave, all A-reads of tile
// kt finish by ph2 and all B-reads by ph3, so BOTH A halves of tile kt+2
// stage at ph3 and BOTH B halves at ph4 (same buffer parity as kt). One
// vmcnt(8) per tile retires tile kt+1's 8 loads while kt+2's 8 stay in
// flight -> ~960cy issue-to-use cover (> HBM ~900cy) vs ~640cy before.
// MODE 2: C bf16 split: cols [0,2048)->C0, [2048,4096)->C1, ld=2048.
// ---------------------------------------------------------------------------
#define SBAR() __builtin_amdgcn_sched_barrier(0)
#define BARR() __builtin_amdgcn_s_barrier()

#define LDS_A(qm, bb)                                                          \
  _Pragma("unroll") for (int mi = 0; mi < 4; ++mi) {                           \
    _Pragma("unroll") for (int ks = 0; ks < 2; ++ks) {                         \
      const int r_ = arow + (qm) * 64 + mi * 16;                               \
      const int cb_ = ((ks) * 64 + quad * 16) ^ swz;                           \
      afr[qm][mi][ks] =                                                        \
          *(const short8*)((const char*)As[bb] + r_ * 128 + cb_);              \
    }                                                                          \
  }

#define LDS_B(qn, bb)                                                          \
  _Pragma("unroll") for (int ni = 0; ni < 2; ++ni) {                           \
    _Pragma("unroll") for (int ks = 0; ks < 2; ++ks) {                         \
      const int r_ = brow + (qn) * 32 + ni * 16;                               \
      const int cb_ = ((ks) * 64 + quad * 16) ^ swz;                           \
      bfr[qn][ni][ks] =                                                        \
          *(const short8*)((const char*)Bs[bb] + r_ * 128 + cb_);              \
    }                                                                          \
  }

#define MMA_Q(qm, qn)                                                          \
  _Pragma("unroll") for (int mi = 0; mi < 4; ++mi) {                           \
    _Pragma("unroll") for (int ni = 0; ni < 2; ++ni) {                         \
      floatx4 t_ = acc[(qm) * 4 + mi][(qn) * 2 + ni];                          \
      t_ = __builtin_amdgcn_mfma_f32_16x16x32_bf16(afr[qm][mi][0],             \
                                                   bfr[qn][ni][0], t_, 0, 0, 0); \
      t_ = __builtin_amdgcn_mfma_f32_16x16x32_bf16(afr[qm][mi][1],             \
                                                   bfr[qn][ni][1], t_, 0, 0, 0); \
      acc[(qm) * 4 + mi][(qn) * 2 + ni] = t_;                                  \
    }                                                                          \
  }

template <int MODE>
__global__ __launch_bounds__(512, 2) void gemm_bt_256(const ushort_t* __restrict__ A,
                                                      const ushort_t* __restrict__ Bt,
                                                      void* __restrict__ C0,
                                                      void* __restrict__ C1,
                                                      int M, int N, int K) {
  __shared__ alignas(16) ushort_t As[2][256 * 64];
  __shared__ alignas(16) ushort_t Bs[2][256 * 64];
  const int tid = threadIdx.x;
  const int wave = tid >> 6, lane = tid & 63;
  const int l15 = lane & 15, quad = lane >> 4;
  const int wm = wave >> 2, wn = wave & 3;  // 2 x 4 wave grid
  const size_t m0 = (size_t)blockIdx.y * 256, n0 = (size_t)blockIdx.x * 256;
  const int nkt = K >> 6;  // K-tiles of 64

  // staging lane constants: chunk = 8 rows x 128B; source k pre-swizzled so
  // the linear LDS dest holds swizzled data.
  const int srow = lane >> 3;                 // row within 8-row chunk
  const int skk = ((lane & 7) ^ srow) * 8;    // swizzled k offset (bf16)

  // frag-read constants
  const int arow = wm * 128 + l15;
  const int brow = wn * 64 + l15;
  const int swz = (l15 & 7) << 4;

  floatx4 zero = {0.f, 0.f, 0.f, 0.f};
  floatx4 acc[8][4];
#pragma unroll
  for (int i = 0; i < 8; ++i)
#pragma unroll
    for (int j = 0; j < 4; ++j) acc[i][j] = zero;

  short8 afr[2][4][2];  // [qm][mi][ks]
  short8 bfr[2][2][2];  // [qn][ni][ks]

  // half-tiles: 0=A rows 0..127, 1=A rows 128..255, 2=B rows 0..127, 3=B rows 128..255
  auto stage_half = [&](int t, int ht) {
    if (t >= nkt) return;
    const int bb = t & 1;
    const int h = ht & 1;
    const int kt64 = t << 6;
    const ushort_t* G = (ht < 2) ? A : Bt;
    const size_t r0 = (ht < 2) ? m0 : n0;
    char* dst = (char*)((ht < 2) ? As[bb] : Bs[bb]) + h * 16384;
#pragma unroll
    for (int i = 0; i < 2; ++i) {
      const int c = wave * 2 + i;
      const size_t gr = r0 + h * 128 + c * 8 + srow;
      __builtin_amdgcn_global_load_lds(AS1(G + gr * K + kt64 + skk),
                                       AS3(dst + c * 1024), 16, 0, 0);
    }
  };

  // prologue: tiles 0 and 1 fully staged (16 loads/thread)
  stage_half(0, 0); stage_half(0, 1); stage_half(0, 2); stage_half(0, 3);
  stage_half(1, 0); stage_half(1, 1); stage_half(1, 2); stage_half(1, 3);
  SBAR();
  if (nkt > 1) { asm volatile("s_waitcnt vmcnt(8)" ::: "memory"); }
  else         { asm volatile("s_waitcnt vmcnt(0)" ::: "memory"); }
  SBAR(); BARR(); SBAR();

  for (int kt = 0; kt < nkt; ++kt) {
    const int bb = kt & 1;
    // ---- phase 1: read A[qm0]+B[qn0]
    LDS_A(0, bb); LDS_B(0, bb);
    SBAR(); BARR(); SBAR();
    __builtin_amdgcn_s_setprio(1);
    MMA_Q(0, 0);
    __builtin_amdgcn_s_setprio(0);
    SBAR(); BARR(); SBAR();
    // ---- phase 2: read A[qm1]  (all A-reads of this tile done after this)
    LDS_A(1, bb);
    SBAR(); BARR(); SBAR();
    __builtin_amdgcn_s_setprio(1);
    MMA_Q(1, 0);
    __builtin_amdgcn_s_setprio(0);
    SBAR(); BARR(); SBAR();
    // ---- phase 3: read B[qn1]; stage BOTH A halves of tile kt+2 -> this buf
    LDS_B(1, bb);
    stage_half(kt + 2, 0); stage_half(kt + 2, 1);
    SBAR(); BARR(); SBAR();
    __builtin_amdgcn_s_setprio(1);
    MMA_Q(1, 1);
    __builtin_amdgcn_s_setprio(0);
    SBAR(); BARR(); SBAR();
    // ---- phase 4: stage BOTH B halves of tile kt+2 -> this buf
    stage_half(kt + 2, 2); stage_half(kt + 2, 3);
    SBAR(); BARR(); SBAR();
    __builtin_amdgcn_s_setprio(1);
    MMA_Q(0, 1);
    __builtin_amdgcn_s_setprio(0);
    SBAR();
    // retire tile kt+1's 8 loads; keep tile kt+2's 8 in flight.
    if (kt + 2 < nkt) { asm volatile("s_waitcnt vmcnt(8)" ::: "memory"); }
    else              { asm volatile("s_waitcnt vmcnt(0)" ::: "memory"); }
    SBAR(); BARR(); SBAR();
  }

  // epilogue
  if (MODE == 2) {
    ushort_t* Cb = (n0 >= 2048) ? (ushort_t*)C1 : (ushort_t*)C0;
    size_t nc0 = n0 & 2047;
#pragma unroll
    for (int mi8 = 0; mi8 < 8; ++mi8)
#pragma unroll
      for (int nj = 0; nj < 4; ++nj)
#pragma unroll
        for (int r = 0; r < 4; ++r) {
          size_t row = m0 + wm * 128 + (mi8 >> 2) * 64 + (mi8 & 3) * 16 + quad * 4 + r;
          size_t col = nc0 + wn * 64 + (nj >> 1) * 32 + (nj & 1) * 16 + l15;
          Cb[row * 2048 + col] = f2b(acc[mi8][nj][r]);
        }
  } else {
#pragma unroll
    for (int mi8 = 0; mi8 < 8; ++mi8)
#pragma unroll
      for (int nj = 0; nj < 4; ++nj)
#pragma unroll
        for (int r = 0; r < 4; ++r) {
          size_t row = m0 + wm * 128 + (mi8 >> 2) * 64 + (mi8 & 3) * 16 + quad * 4 + r;
          size_t col = n0 + wn * 64 + (nj >> 1) * 32 + (nj & 1) * 16 + l15;
          if (MODE == 1)
            ((float*)C0)[row * N + col] = acc[mi8][nj][r];
          else
            ((ushort_t*)C0)[row * N + col] = f2b(acc[mi8][nj][r]);
        }
  }
}

// ---------------------------------------------------------------------------
// unit-norm + RoPE (even heads) + gain-fold (gain * log2e for exp2 softmax),
// in place. Vectorized: 16 lanes per row, 4 rows per wave, uint2 (4 bf16)
// loads/stores per half.
// ---------------------------------------------------------------------------
__global__ __launch_bounds__(256) void norm_rope(ushort_t* __restrict__ Q,
                                                 ushort_t* __restrict__ Kb,
                                                 const float* __restrict__ gain) {
  const int tid = threadIdx.x;
  const int wave = tid >> 6, lane = tid & 63;
  const int g16 = lane >> 4, sl = lane & 15;
  const int idx = (blockIdx.x * 4 + wave) * 4 + g16;  // ((b*S+s)*H + h)
  const int h = idx & 15;
  const int s = (idx >> 4) & (S_ - 1);
  const size_t off = (size_t)(idx >> 4) * DM_ + h * DH_ + sl * 4;

  ushort_t qv1[4], qv2[4], kv1[4], kv2[4];
  *(uint2*)qv1 = *(const uint2*)(Q + off);
  *(uint2*)qv2 = *(const uint2*)(Q + off + 64);
  *(uint2*)kv1 = *(const uint2*)(Kb + off);
  *(uint2*)kv2 = *(const uint2*)(Kb + off + 64);

  float q1[4], q2[4], k1[4], k2[4];
  float sq = 0.f, sk = 0.f;
#pragma unroll
  for (int e = 0; e < 4; ++e) {
    q1[e] = b2f(qv1[e]); q2[e] = b2f(qv2[e]);
    k1[e] = b2f(kv1[e]); k2[e] = b2f(kv2[e]);
    sq += q1[e] * q1[e] + q2[e] * q2[e];
    sk += k1[e] * k1[e] + k2[e] * k2[e];
  }
#pragma unroll
  for (int o = 1; o < 16; o <<= 1) {
    sq += __shfl_xor(sq, o, 64);
    sk += __shfl_xor(sk, o, 64);
  }
  float rq = rsqrtf(sq + 1e-6f), rk = rsqrtf(sk + 1e-6f);
  const float g = gain[h] * 1.44269504f;  // fold log2(e): attn uses exp2
  const bool roped = (h & 1) == 0;        // ROPE_MASK tiles [1,0] over heads
#pragma unroll
  for (int e = 0; e < 4; ++e) {
    float a = q1[e] * rq, bq = q2[e] * rq;
    float c_ = k1[e] * rk, dk = k2[e] * rk;
    if (roped) {
      int j = sl * 4 + e;
      float invf = exp2f((float)j * -0.20762050593f);  // log2(10000)/64
      float th = (float)s * invf;
      float cc = cosf(th), sn = sinf(th);
      float na = a * cc - bq * sn, nb = a * sn + bq * cc;
      float nc = c_ * cc - dk * sn, nd = c_ * sn + dk * cc;
      a = na; bq = nb; c_ = nc; dk = nd;
    }
    qv1[e] = f2b(a * g); qv2[e] = f2b(bq * g);
    kv1[e] = f2b(c_);    kv2[e] = f2b(dk);
  }
  *(uint2*)(Q + off)       = *(const uint2*)qv1;
  *(uint2*)(Q + off + 64)  = *(const uint2*)qv2;
  *(uint2*)(Kb + off)      = *(const uint2*)kv1;
  *(uint2*)(Kb + off + 64) = *(const uint2*)kv2;
}

// ---------------------------------------------------------------------------
// Flash attention v3: balanced tile pairs {p, 31-p}, fixed-max softmax
// (exp2 form, log2e pre-folded into q-gain), double-buffered K/V, per-wave
// Ps, 1 barrier/iter. V layout: [dim][b*S+s]. Y written in place over Q.
// Round-1: grid swapped to (bh, p) so the 16 p-blocks sharing one head's
// K/V land on one XCD (id%8 = bh%8) -> per-XCD K/V set = 4 MB = L2 size.
// ---------------------------------------------------------------------------
__global__ __launch_bounds__(256, 2) void attn(ushort_t* __restrict__ QY,
                                               const ushort_t* __restrict__ Kg,
                                               const ushort_t* __restrict__ Vg) {
  __shared__ alignas(16) ushort_t Ks[2][64 * 128];
  __shared__ alignas(16) ushort_t Vs[2][128 * 64];
  __shared__ alignas(16) ushort_t Ps[2][4][16 * 64];

  const float M0 = 18.755035531f;  // 13 * log2(e)
  const int tid = threadIdx.x;
  const int wave = tid >> 6, lane = tid & 63;
  const int l15 = lane & 15, quad = lane >> 4;
  const int bh = blockIdx.x;            // XCD = (p*32+bh)%8 = bh%8
  const int b = bh >> 4, h = bh & 15;
  const int p = blockIdx.y;
  const int qt[2] = {p, 31 - p};

  const ushort_t* Kgb = Kg + (size_t)b * S_ * DM_ + h * DH_;
  const ushort_t* Vgb = Vg + (size_t)(h * DH_) * (B_ * S_) + b * S_;

  short8 aq[2][4];
#pragma unroll
  for (int t = 0; t < 2; ++t) {
    const ushort_t* Qg =
        QY + (size_t)(b * S_ + qt[t] * 64 + wave * 16 + l15) * DM_ + h * DH_;
#pragma unroll
    for (int ks = 0; ks < 4; ++ks)
      aq[t][ks] = *(const short8*)(Qg + ks * 32 + quad * 8);
  }

  float lsum[2][4] = {{0.f, 0.f, 0.f, 0.f}, {0.f, 0.f, 0.f, 0.f}};
  floatx4 zero = {0.f, 0.f, 0.f, 0.f};
  floatx4 oacc[2][8];
#pragma unroll
  for (int t = 0; t < 2; ++t)
#pragma unroll
    for (int d = 0; d < 8; ++d) oacc[t][d] = zero;

  const int krow_in = lane >> 4, ksd = lane & 15;
  const int vrow_in = lane >> 3, vsd = lane & 7;

  auto stage = [&](int kt, int bf) {
#pragma unroll
    for (int i = 0; i < 4; ++i) {
      int c = wave * 4 + i;
      {
        int r = c * 4 + krow_in;
        int sg = ksd ^ (r & 7);
        __builtin_amdgcn_global_load_lds(
            AS1(Kgb + (size_t)(kt * 64 + r) * DM_ + sg * 8),
            AS3((char*)Ks[bf] + c * 1024), 16, 0, 0);
      }
      {
        int r = c * 8 + vrow_in;
        int sg = vsd ^ (r & 7);
        __builtin_amdgcn_global_load_lds(
            AS1(Vgb + (size_t)r * (B_ * S_) + kt * 64 + sg * 8),
            AS3((char*)Vs[bf] + c * 1024), 16, 0, 0);
      }
    }
  };

  stage(0, 0);

  for (int kt = 0; kt <= qt[1]; ++kt) {
    const int cur = kt & 1;
    __syncthreads();
    if (kt < qt[1]) stage(kt + 1, cur ^ 1);

#pragma unroll
    for (int t = 0; t < 2; ++t) {
      if (t == 0 && kt > qt[0]) continue;
      floatx4 sacc[4];
#pragma unroll
      for (int j = 0; j < 4; ++j) sacc[j] = zero;
#pragma unroll
      for (int ks = 0; ks < 4; ++ks) {
#pragma unroll
        for (int j = 0; j < 4; ++j) {
          int row = j * 16 + l15;
          int sl = (ks * 4 + quad) ^ (row & 7);
          short8 bk = *(const short8*)&Ks[cur][row * 128 + sl * 8];
          sacc[j] = __builtin_amdgcn_mfma_f32_16x16x32_bf16(aq[t][ks], bk, sacc[j], 0, 0, 0);
        }
      }
      if (kt == qt[t]) {
#pragma unroll
        for (int j = 0; j < 4; ++j)
#pragma unroll
          for (int r = 0; r < 4; ++r) {
            int key = j * 16 + l15;
            int qr = wave * 16 + quad * 4 + r;
            if (key > qr) sacc[j][r] = -1e30f;
          }
      }
#pragma unroll
      for (int j = 0; j < 4; ++j)
#pragma unroll
        for (int r = 0; r < 4; ++r) {
          float pv = fast_exp2(sacc[j][r] - M0);
          sacc[j][r] = pv;
          lsum[t][r] += pv;
        }
#pragma unroll
      for (int j = 0; j < 4; ++j)
#pragma unroll
        for (int r = 0; r < 4; ++r) {
          int row = quad * 4 + r;
          int col = j * 16 + l15;
          int g = col >> 3, w = col & 7;
          Ps[t][wave][row * 64 + ((g ^ (row & 7)) << 3) + w] = f2b(sacc[j][r]);
        }
#pragma unroll
      for (int ks2 = 0; ks2 < 2; ++ks2) {
        short8 ap = *(const short8*)&Ps[t][wave][l15 * 64 +
                                                (((ks2 * 4 + quad) ^ (l15 & 7)) << 3)];
#pragma unroll
        for (int d = 0; d < 8; ++d) {
          int row = d * 16 + l15;
          int sl = (ks2 * 4 + quad) ^ (row & 7);
          short8 bv = *(const short8*)&Vs[cur][row * 64 + sl * 8];
          oacc[t][d] = __builtin_amdgcn_mfma_f32_16x16x32_bf16(ap, bv, oacc[t][d], 0, 0, 0);
        }
      }
    }
  }

#pragma unroll
  for (int t = 0; t < 2; ++t) {
#pragma unroll
    for (int r = 0; r < 4; ++r) {
#pragma unroll
      for (int o = 1; o < 16; o <<= 1) lsum[t][r] += __shfl_xor(lsum[t][r], o, 64);
      float inv = 1.0f / lsum[t][r];
      size_t row = (size_t)(b * S_ + qt[t] * 64 + wave * 16 + quad * 4 + r);
#pragma unroll
      for (int d = 0; d < 8; ++d) {
        size_t col = (size_t)h * DH_ + d * 16 + l15;
        QY[row * DM_ + col] = f2b(oacc[t][d][r] * inv);
      }
    }
  }
}

// ---------------------------------------------------------------------------
extern "C" void kernel_launch(void* const* d_in, const int* in_sizes, int n_in,
                              void* d_out, int out_size, void* d_ws, size_t ws_size,
                              hipStream_t stream) {
  const float* x      = (const float*)d_in[0];
  const float* w_qkv  = (const float*)d_in[1];
  const float* w_out  = (const float*)d_in[2];
  const float* q_gain = (const float*)d_in[3];
  float* out = (float*)d_out;

  // ws (56 MiB, proven): Qraw | Kraw | Vt | wvT
  // d_out (32 MiB) doubles as scratch until the final GEMM: xbf | wqkT
  char* ws = (char*)d_ws;
  const size_t bsd = (size_t)B_ * S_ * DM_;  // 8,388,608 elems
  ushort_t* Qraw = (ushort_t*)ws;
  ushort_t* Kraw = Qraw + bsd;
  ushort_t* Vt   = Kraw + bsd;                    // [dim][b*S+s]
  ushort_t* wvT  = Vt + bsd;                      // [2048][2048]
  ushort_t* xbf  = (ushort_t*)d_out;              // [4096][2048] bf16
  ushort_t* wqkT = xbf + bsd;                     // [4096][2048] bf16 (Wq|Wk)^T
  ushort_t* woutT = Kraw;                         // after attn, Kraw is dead

  convert_f32_bf16<<<dim3(bsd / (8 * 256)), 256, 0, stream>>>(x, xbf);
  transpose_f32_to_bf16T<<<dim3(64, 32), 256, 0, stream>>>(w_qkv, wqkT, DM_, 3 * DM_, 0);
  transpose_f32_to_bf16T<<<dim3(32, 32), 256, 0, stream>>>(w_qkv, wvT, DM_, 3 * DM_, 2 * DM_);

  // Q and K in one fused GEMM (split-C epilogue), 256^2 deep-pipeline kernel.
  gemm_bt_256<2><<<dim3(16, 16), 512, 0, stream>>>(xbf, wqkT, Qraw, Kraw,
                                                   B_ * S_, 2 * DM_, DM_);
  // V^T = WvT * x^T  -> Vt[dim][b*S+s]  (M=2048: keep 128^2 kernel, full grid)
  gemm_bt_async<0><<<dim3(32, 16), 256, 0, stream>>>(wvT, xbf, Vt, nullptr,
                                                     DM_, B_ * S_, DM_);
  norm_rope<<<dim3(B_ * S_ * H_ / 16), 256, 0, stream>>>(Qraw, Kraw, q_gain);
  attn<<<dim3(B_ * H_, S_ / 128), 256, 0, stream>>>(Qraw, Kraw, Vt);
  // w_out^T into dead Kraw region, then final GEMM (f32 out over d_out)
  transpose_f32_to_bf16T<<<dim3(32, 32), 256, 0, stream>>>(w_out, woutT, DM_, DM_, 0);
  gemm_bt_async<1><<<dim3(16, 32), 256, 0, stream>>>(Qraw, woutT, out, nullptr,
                                                     B_ * S_, DM_, DM_);
}

// Round 3
// 363.760 us; speedup vs baseline: 1.1548x; 1.0245x over previous
//
#include <hip/hip_runtime.h>
#include <hip/hip_bf16.h>

typedef unsigned short ushort_t;
typedef __attribute__((ext_vector_type(8))) short short8;
typedef __attribute__((ext_vector_type(4))) float floatx4;

#define B_  2
#define S_  2048
#define DM_ 2048
#define H_  16
#define DH_ 128

#define AS1(p) ((const __attribute__((address_space(1))) void*)(p))
#define AS3(p) ((__attribute__((address_space(3))) void*)(p))

static __device__ __forceinline__ float b2f(ushort_t u) {
  __hip_bfloat16 h = *reinterpret_cast<__hip_bfloat16*>(&u);
  return __bfloat162float(h);
}
static __device__ __forceinline__ ushort_t f2b(float f) {
  __hip_bfloat16 h = __float2bfloat16(f);
  return *reinterpret_cast<ushort_t*>(&h);
}
static __device__ __forceinline__ float fast_exp2(float x) {
#if defined(__has_builtin)
#if __has_builtin(__builtin_amdgcn_exp2f)
  return __builtin_amdgcn_exp2f(x);
#else
  return exp2f(x);
#endif
#else
  return exp2f(x);
#endif
}

// ---------------------------------------------------------------------------
// x (f32) -> bf16, 8 elems/thread.
// ---------------------------------------------------------------------------
__global__ __launch_bounds__(256) void convert_f32_bf16(const float* __restrict__ in,
                                                        ushort_t* __restrict__ out) {
  size_t i = ((size_t)blockIdx.x * 256 + threadIdx.x) * 8;
  float4 a = *(const float4*)(in + i);
  float4 b = *(const float4*)(in + i + 4);
  ushort_t tmp[8] = {f2b(a.x), f2b(a.y), f2b(a.z), f2b(a.w),
                     f2b(b.x), f2b(b.y), f2b(b.z), f2b(b.w)};
  *(uint4*)(out + i) = *(const uint4*)tmp;
}

// ---------------------------------------------------------------------------
// out[c][r] = bf16(in[r][colOff + c]); in f32 [R][inC], out bf16 [64*gx][R].
// ---------------------------------------------------------------------------
__global__ __launch_bounds__(256) void transpose_f32_to_bf16T(const float* __restrict__ in,
                                                              ushort_t* __restrict__ out,
                                                              int R, int inC, int colOff) {
  __shared__ ushort_t tile[64][72];
  const int tid = threadIdx.x;
  const int r0 = blockIdx.y * 64, c0 = blockIdx.x * 64;
#pragma unroll
  for (int p = 0; p < 2; ++p) {
    int li = tid + p * 256;
    int r = li >> 3, cs = (li & 7) * 8;
    const float* src = in + (size_t)(r0 + r) * inC + colOff + c0 + cs;
    float4 a = *(const float4*)src;
    float4 b = *(const float4*)(src + 4);
    ushort_t tmp[8] = {f2b(a.x), f2b(a.y), f2b(a.z), f2b(a.w),
                       f2b(b.x), f2b(b.y), f2b(b.z), f2b(b.w)};
    *(uint4*)&tile[r][cs] = *(const uint4*)tmp;
  }
  __syncthreads();
#pragma unroll
  for (int p = 0; p < 2; ++p) {
    int li = tid + p * 256;
    int cR = li >> 3, rs = (li & 7) * 8;
    ushort_t tmp[8];
#pragma unroll
    for (int e = 0; e < 8; ++e) tmp[e] = tile[rs + e][cR];
    *(uint4*)(out + (size_t)(c0 + cR) * R + r0 + rs) = *(const uint4*)tmp;
  }
}

#define SBAR() __builtin_amdgcn_sched_barrier(0)
#define BARR() __builtin_amdgcn_s_barrier()

// ---------------------------------------------------------------------------
// GEMM 256x256, BK=64, 8 waves (2Mx4N), 4-phase schedule, counted vmcnt.
// ROUND-1 SCHEDULE RESTORED (measured ~75us): staggered staging, one
// half-tile per phase: B0(kt+1) at ph1, B1(kt+1) at ph2 (other buffer),
// A0(kt+2) at ph3, A1(kt+2) at ph4 (same buffer; A-reads retired by ph2's
// closing barrier). vmcnt(4) per tile retires A(kt+1)+B(kt+1), keeps
// A(kt+2) in flight. Round-2's bunched 2-tile prefetch regressed (85us).
// MODE 2: C bf16 split: cols [0,2048)->C0, [2048,4096)->C1, ld=2048.
// ---------------------------------------------------------------------------
#define LDS_A(qm, bb)                                                          \
  _Pragma("unroll") for (int mi = 0; mi < 4; ++mi) {                           \
    _Pragma("unroll") for (int ks = 0; ks < 2; ++ks) {                         \
      const int r_ = arow + (qm) * 64 + mi * 16;                               \
      const int cb_ = ((ks) * 64 + quad * 16) ^ swz;                           \
      afr[qm][mi][ks] =                                                        \
          *(const short8*)((const char*)As[bb] + r_ * 128 + cb_);              \
    }                                                                          \
  }

#define LDS_B(qn, bb)                                                          \
  _Pragma("unroll") for (int ni = 0; ni < 2; ++ni) {                           \
    _Pragma("unroll") for (int ks = 0; ks < 2; ++ks) {                         \
      const int r_ = brow + (qn) * 32 + ni * 16;                               \
      const int cb_ = ((ks) * 64 + quad * 16) ^ swz;                           \
      bfr[qn][ni][ks] =                                                        \
          *(const short8*)((const char*)Bs[bb] + r_ * 128 + cb_);              \
    }                                                                          \
  }

#define MMA_Q(qm, qn)                                                          \
  _Pragma("unroll") for (int mi = 0; mi < 4; ++mi) {                           \
    _Pragma("unroll") for (int ni = 0; ni < 2; ++ni) {                         \
      floatx4 t_ = acc[(qm) * 4 + mi][(qn) * 2 + ni];                          \
      t_ = __builtin_amdgcn_mfma_f32_16x16x32_bf16(afr[qm][mi][0],             \
                                                   bfr[qn][ni][0], t_, 0, 0, 0); \
      t_ = __builtin_amdgcn_mfma_f32_16x16x32_bf16(afr[qm][mi][1],             \
                                                   bfr[qn][ni][1], t_, 0, 0, 0); \
      acc[(qm) * 4 + mi][(qn) * 2 + ni] = t_;                                  \
    }                                                                          \
  }

template <int MODE>
__global__ __launch_bounds__(512, 2) void gemm_bt_256(const ushort_t* __restrict__ A,
                                                      const ushort_t* __restrict__ Bt,
                                                      void* __restrict__ C0,
                                                      void* __restrict__ C1,
                                                      int M, int N, int K) {
  __shared__ alignas(16) ushort_t As[2][256 * 64];
  __shared__ alignas(16) ushort_t Bs[2][256 * 64];
  const int tid = threadIdx.x;
  const int wave = tid >> 6, lane = tid & 63;
  const int l15 = lane & 15, quad = lane >> 4;
  const int wm = wave >> 2, wn = wave & 3;  // 2 x 4 wave grid
  const size_t m0 = (size_t)blockIdx.y * 256, n0 = (size_t)blockIdx.x * 256;
  const int nkt = K >> 6;  // K-tiles of 64

  const int srow = lane >> 3;                 // row within 8-row chunk
  const int skk = ((lane & 7) ^ srow) * 8;    // swizzled k offset (bf16)

  const int arow = wm * 128 + l15;
  const int brow = wn * 64 + l15;
  const int swz = (l15 & 7) << 4;

  floatx4 zero = {0.f, 0.f, 0.f, 0.f};
  floatx4 acc[8][4];
#pragma unroll
  for (int i = 0; i < 8; ++i)
#pragma unroll
    for (int j = 0; j < 4; ++j) acc[i][j] = zero;

  short8 afr[2][4][2];  // [qm][mi][ks]
  short8 bfr[2][2][2];  // [qn][ni][ks]

  // half-tiles: 0=A rows 0..127, 1=A rows 128..255, 2=B rows 0..127, 3=B rows 128..255
  auto stage_half = [&](int t, int ht) {
    if (t >= nkt) return;
    const int bb = t & 1;
    const int h = ht & 1;
    const int kt64 = t << 6;
    const ushort_t* G = (ht < 2) ? A : Bt;
    const size_t r0 = (ht < 2) ? m0 : n0;
    char* dst = (char*)((ht < 2) ? As[bb] : Bs[bb]) + h * 16384;
#pragma unroll
    for (int i = 0; i < 2; ++i) {
      const int c = wave * 2 + i;
      const size_t gr = r0 + h * 128 + c * 8 + srow;
      __builtin_amdgcn_global_load_lds(AS1(G + gr * K + kt64 + skk),
                                       AS3(dst + c * 1024), 16, 0, 0);
    }
  };

  // prologue: tile 0 fully + A-halves of tile 1 (12 loads/thread)
  stage_half(0, 0); stage_half(0, 1); stage_half(0, 2); stage_half(0, 3);
  stage_half(1, 0); stage_half(1, 1);
  SBAR();
  if (nkt > 1) { asm volatile("s_waitcnt vmcnt(4)" ::: "memory"); }
  else         { asm volatile("s_waitcnt vmcnt(0)" ::: "memory"); }
  SBAR(); BARR(); SBAR();

  for (int kt = 0; kt < nkt; ++kt) {
    const int bb = kt & 1;
    // ---- phase 1: read A[qm0]+B[qn0]; stage B-half0 of tile kt+1 -> other buf
    LDS_A(0, bb); LDS_B(0, bb);
    stage_half(kt + 1, 2);
    SBAR(); BARR(); SBAR();
    __builtin_amdgcn_s_setprio(1);
    MMA_Q(0, 0);
    __builtin_amdgcn_s_setprio(0);
    SBAR(); BARR(); SBAR();
    // ---- phase 2: read A[qm1]; stage B-half1 of tile kt+1 -> other buf
    LDS_A(1, bb);
    stage_half(kt + 1, 3);
    SBAR(); BARR(); SBAR();
    __builtin_amdgcn_s_setprio(1);
    MMA_Q(1, 0);
    __builtin_amdgcn_s_setprio(0);
    SBAR(); BARR(); SBAR();
    // ---- phase 3: read B[qn1]; stage A-half0 of tile kt+2 -> this buf
    LDS_B(1, bb);
    stage_half(kt + 2, 0);
    SBAR(); BARR(); SBAR();
    __builtin_amdgcn_s_setprio(1);
    MMA_Q(1, 1);
    __builtin_amdgcn_s_setprio(0);
    SBAR(); BARR(); SBAR();
    // ---- phase 4: stage A-half1 of tile kt+2 -> this buf
    stage_half(kt + 2, 1);
    SBAR(); BARR(); SBAR();
    __builtin_amdgcn_s_setprio(1);
    MMA_Q(0, 1);
    __builtin_amdgcn_s_setprio(0);
    SBAR();
    if (kt + 2 < nkt) { asm volatile("s_waitcnt vmcnt(4)" ::: "memory"); }
    else              { asm volatile("s_waitcnt vmcnt(0)" ::: "memory"); }
    SBAR(); BARR(); SBAR();
  }

  // epilogue
  if (MODE == 2) {
    ushort_t* Cb = (n0 >= 2048) ? (ushort_t*)C1 : (ushort_t*)C0;
    size_t nc0 = n0 & 2047;
#pragma unroll
    for (int mi8 = 0; mi8 < 8; ++mi8)
#pragma unroll
      for (int nj = 0; nj < 4; ++nj)
#pragma unroll
        for (int r = 0; r < 4; ++r) {
          size_t row = m0 + wm * 128 + (mi8 >> 2) * 64 + (mi8 & 3) * 16 + quad * 4 + r;
          size_t col = nc0 + wn * 64 + (nj >> 1) * 32 + (nj & 1) * 16 + l15;
          Cb[row * 2048 + col] = f2b(acc[mi8][nj][r]);
        }
  } else {
#pragma unroll
    for (int mi8 = 0; mi8 < 8; ++mi8)
#pragma unroll
      for (int nj = 0; nj < 4; ++nj)
#pragma unroll
        for (int r = 0; r < 4; ++r) {
          size_t row = m0 + wm * 128 + (mi8 >> 2) * 64 + (mi8 & 3) * 16 + quad * 4 + r;
          size_t col = n0 + wn * 64 + (nj >> 1) * 32 + (nj & 1) * 16 + l15;
          if (MODE == 1)
            ((float*)C0)[row * N + col] = acc[mi8][nj][r];
          else
            ((ushort_t*)C0)[row * N + col] = f2b(acc[mi8][nj][r]);
        }
  }
}

// ---------------------------------------------------------------------------
// GEMM 128x128, BK=64, 4 waves (2Mx2N), 4-phase deep-pipeline (structural
// mirror of gemm_bt_256's proven schedule, halved dims), 64 KiB LDS ->
// 2 blocks/CU co-resident (cross-block overlap hides barrier stalls).
// Used for the M/N=2048 GEMMs: grids of 512 blocks = exactly 2/CU.
// MODE 0: C bf16, ld=N.  MODE 1: C f32, ld=N.
// ---------------------------------------------------------------------------
#define LDS_A8(mh, bb)                                                         \
  _Pragma("unroll") for (int mi = 0; mi < 2; ++mi) {                           \
    _Pragma("unroll") for (int ks = 0; ks < 2; ++ks) {                         \
      const int r_ = arow + ((mh) * 2 + mi) * 16;                              \
      const int cb_ = ((ks) * 64 + quad * 16) ^ swz;                           \
      afr[(mh) * 2 + mi][ks] =                                                 \
          *(const short8*)((const char*)As[bb] + r_ * 128 + cb_);              \
    }                                                                          \
  }

#define LDS_B8(nh, bb)                                                         \
  _Pragma("unroll") for (int ni = 0; ni < 2; ++ni) {                           \
    _Pragma("unroll") for (int ks = 0; ks < 2; ++ks) {                         \
      const int r_ = brow + ((nh) * 2 + ni) * 16;                              \
      const int cb_ = ((ks) * 64 + quad * 16) ^ swz;                           \
      bfr[(nh) * 2 + ni][ks] =                                                 \
          *(const short8*)((const char*)Bs[bb] + r_ * 128 + cb_);              \
    }                                                                          \
  }

#define MMA_H(mh, nh)                                                          \
  _Pragma("unroll") for (int mi = 0; mi < 2; ++mi) {                           \
    _Pragma("unroll") for (int ni = 0; ni < 2; ++ni) {                         \
      floatx4 t_ = acc[(mh) * 2 + mi][(nh) * 2 + ni];                          \
      t_ = __builtin_amdgcn_mfma_f32_16x16x32_bf16(afr[(mh) * 2 + mi][0],      \
                                                   bfr[(nh) * 2 + ni][0], t_, 0, 0, 0); \
      t_ = __builtin_amdgcn_mfma_f32_16x16x32_bf16(afr[(mh) * 2 + mi][1],      \
                                                   bfr[(nh) * 2 + ni][1], t_, 0, 0, 0); \
      acc[(mh) * 2 + mi][(nh) * 2 + ni] = t_;                                  \
    }                                                                          \
  }

template <int MODE>
__global__ __launch_bounds__(256, 2) void gemm_bt_128(const ushort_t* __restrict__ A,
                                                      const ushort_t* __restrict__ Bt,
                                                      void* __restrict__ C0,
                                                      int M, int N, int K) {
  __shared__ alignas(16) ushort_t As[2][128 * 64];
  __shared__ alignas(16) ushort_t Bs[2][128 * 64];
  const int tid = threadIdx.x;
  const int wave = tid >> 6, lane = tid & 63;
  const int l15 = lane & 15, quad = lane >> 4;
  const int wm = wave >> 1, wn = wave & 1;  // 2 x 2 wave grid
  // banded block swizzle (4-row bands) for L2 reuse, as before
  const int lin = blockIdx.y * gridDim.x + blockIdx.x;
  const int band = lin / (4 * gridDim.x);
  const int rin = lin % (4 * gridDim.x);
  const int by = band * 4 + (rin & 3);
  const int bx = rin >> 2;
  const size_t m0 = (size_t)by * 128, n0 = (size_t)bx * 128;
  const int nkt = K >> 6;

  const int srow = lane >> 3;
  const int skk = ((lane & 7) ^ srow) * 8;

  const int arow = wm * 64 + l15;
  const int brow = wn * 64 + l15;
  const int swz = (l15 & 7) << 4;

  floatx4 zero = {0.f, 0.f, 0.f, 0.f};
  floatx4 acc[4][4];
#pragma unroll
  for (int i = 0; i < 4; ++i)
#pragma unroll
    for (int j = 0; j < 4; ++j) acc[i][j] = zero;

  short8 afr[4][2];
  short8 bfr[4][2];

  // quarter-tiles: op A (qt 0..1 = rows 0..63 / 64..127), op B (qt 2..3).
  // each qt = 32 rows x 128B = 8KB = 2 loads/thread (4 waves x 2 chunks).
  auto stage_q = [&](int t, int qt_) {
    if (t >= nkt) return;
    const int bb = t & 1;
    const int h = qt_ & 1;
    const int kt64 = t << 6;
    const ushort_t* G = (qt_ < 2) ? A : Bt;
    const size_t r0 = (qt_ < 2) ? m0 : n0;
    char* dst = (char*)((qt_ < 2) ? As[bb] : Bs[bb]) + h * 8192;
#pragma unroll
    for (int i = 0; i < 2; ++i) {
      const int c = wave * 2 + i;
      const size_t gr = r0 + h * 64 + c * 8 + srow;
      __builtin_amdgcn_global_load_lds(AS1(G + gr * K + kt64 + skk),
                                       AS3(dst + c * 1024), 16, 0, 0);
    }
  };

  // prologue: tile 0 fully + A-quarters of tile 1 (12 loads/thread)
  stage_q(0, 0); stage_q(0, 1); stage_q(0, 2); stage_q(0, 3);
  stage_q(1, 0); stage_q(1, 1);
  SBAR();
  if (nkt > 1) { asm volatile("s_waitcnt vmcnt(4)" ::: "memory"); }
  else         { asm volatile("s_waitcnt vmcnt(0)" ::: "memory"); }
  SBAR(); BARR(); SBAR();

  for (int kt = 0; kt < nkt; ++kt) {
    const int bb = kt & 1;
    // ---- phase 1: read A[mh0]+B[nh0]; stage B-q0 of tile kt+1 -> other buf
    LDS_A8(0, bb); LDS_B8(0, bb);
    stage_q(kt + 1, 2);
    SBAR(); BARR(); SBAR();
    __builtin_amdgcn_s_setprio(1);
    MMA_H(0, 0);
    __builtin_amdgcn_s_setprio(0);
    SBAR(); BARR(); SBAR();
    // ---- phase 2: read A[mh1]; stage B-q1 of tile kt+1 -> other buf
    LDS_A8(1, bb);
    stage_q(kt + 1, 3);
    SBAR(); BARR(); SBAR();
    __builtin_amdgcn_s_setprio(1);
    MMA_H(1, 0);
    __builtin_amdgcn_s_setprio(0);
    SBAR(); BARR(); SBAR();
    // ---- phase 3: read B[nh1]; stage A-q0 of tile kt+2 -> this buf
    //      (A-reads of this tile retired by phase-2 closing barrier)
    LDS_B8(1, bb);
    stage_q(kt + 2, 0);
    SBAR(); BARR(); SBAR();
    __builtin_amdgcn_s_setprio(1);
    MMA_H(1, 1);
    __builtin_amdgcn_s_setprio(0);
    SBAR(); BARR(); SBAR();
    // ---- phase 4: stage A-q1 of tile kt+2 -> this buf
    stage_q(kt + 2, 1);
    SBAR(); BARR(); SBAR();
    __builtin_amdgcn_s_setprio(1);
    MMA_H(0, 1);
    __builtin_amdgcn_s_setprio(0);
    SBAR();
    if (kt + 2 < nkt) { asm volatile("s_waitcnt vmcnt(4)" ::: "memory"); }
    else              { asm volatile("s_waitcnt vmcnt(0)" ::: "memory"); }
    SBAR(); BARR(); SBAR();
  }

#pragma unroll
  for (int i = 0; i < 4; ++i)
#pragma unroll
    for (int j = 0; j < 4; ++j)
#pragma unroll
      for (int r = 0; r < 4; ++r) {
        size_t row = m0 + wm * 64 + i * 16 + quad * 4 + r;
        size_t col = n0 + wn * 64 + j * 16 + l15;
        if (MODE == 1)
          ((float*)C0)[row * N + col] = acc[i][j][r];
        else
          ((ushort_t*)C0)[row * N + col] = f2b(acc[i][j][r]);
      }
}

// ---------------------------------------------------------------------------
// unit-norm + RoPE (even heads) + gain-fold (gain * log2e for exp2 softmax),
// in place. Vectorized: 16 lanes per row, 4 rows per wave.
// ---------------------------------------------------------------------------
__global__ __launch_bounds__(256) void norm_rope(ushort_t* __restrict__ Q,
                                                 ushort_t* __restrict__ Kb,
                                                 const float* __restrict__ gain) {
  const int tid = threadIdx.x;
  const int wave = tid >> 6, lane = tid & 63;
  const int g16 = lane >> 4, sl = lane & 15;
  const int idx = (blockIdx.x * 4 + wave) * 4 + g16;  // ((b*S+s)*H + h)
  const int h = idx & 15;
  const int s = (idx >> 4) & (S_ - 1);
  const size_t off = (size_t)(idx >> 4) * DM_ + h * DH_ + sl * 4;

  ushort_t qv1[4], qv2[4], kv1[4], kv2[4];
  *(uint2*)qv1 = *(const uint2*)(Q + off);
  *(uint2*)qv2 = *(const uint2*)(Q + off + 64);
  *(uint2*)kv1 = *(const uint2*)(Kb + off);
  *(uint2*)kv2 = *(const uint2*)(Kb + off + 64);

  float q1[4], q2[4], k1[4], k2[4];
  float sq = 0.f, sk = 0.f;
#pragma unroll
  for (int e = 0; e < 4; ++e) {
    q1[e] = b2f(qv1[e]); q2[e] = b2f(qv2[e]);
    k1[e] = b2f(kv1[e]); k2[e] = b2f(kv2[e]);
    sq += q1[e] * q1[e] + q2[e] * q2[e];
    sk += k1[e] * k1[e] + k2[e] * k2[e];
  }
#pragma unroll
  for (int o = 1; o < 16; o <<= 1) {
    sq += __shfl_xor(sq, o, 64);
    sk += __shfl_xor(sk, o, 64);
  }
  float rq = rsqrtf(sq + 1e-6f), rk = rsqrtf(sk + 1e-6f);
  const float g = gain[h] * 1.44269504f;  // fold log2(e): attn uses exp2
  const bool roped = (h & 1) == 0;        // ROPE_MASK tiles [1,0] over heads
#pragma unroll
  for (int e = 0; e < 4; ++e) {
    float a = q1[e] * rq, bq = q2[e] * rq;
    float c_ = k1[e] * rk, dk = k2[e] * rk;
    if (roped) {
      int j = sl * 4 + e;
      float invf = exp2f((float)j * -0.20762050593f);  // log2(10000)/64
      float th = (float)s * invf;
      float cc = cosf(th), sn = sinf(th);
      float na = a * cc - bq * sn, nb = a * sn + bq * cc;
      float nc = c_ * cc - dk * sn, nd = c_ * sn + dk * cc;
      a = na; bq = nb; c_ = nc; dk = nd;
    }
    qv1[e] = f2b(a * g); qv2[e] = f2b(bq * g);
    kv1[e] = f2b(c_);    kv2[e] = f2b(dk);
  }
  *(uint2*)(Q + off)       = *(const uint2*)qv1;
  *(uint2*)(Q + off + 64)  = *(const uint2*)qv2;
  *(uint2*)(Kb + off)      = *(const uint2*)kv1;
  *(uint2*)(Kb + off + 64) = *(const uint2*)kv2;
}

// ---------------------------------------------------------------------------
// Flash attention v3: balanced tile pairs {p, 31-p}, fixed-max softmax
// (exp2 form, log2e pre-folded into q-gain), double-buffered K/V, per-wave
// Ps, 1 barrier/iter. V layout: [dim][b*S+s]. Y written in place over Q.
// Grid (bh, p): XCD = bh%8 -> per-XCD K/V working set fits its 4MB L2.
// ---------------------------------------------------------------------------
__global__ __launch_bounds__(256, 2) void attn(ushort_t* __restrict__ QY,
                                               const ushort_t* __restrict__ Kg,
                                               const ushort_t* __restrict__ Vg) {
  __shared__ alignas(16) ushort_t Ks[2][64 * 128];
  __shared__ alignas(16) ushort_t Vs[2][128 * 64];
  __shared__ alignas(16) ushort_t Ps[2][4][16 * 64];

  const float M0 = 18.755035531f;  // 13 * log2(e)
  const int tid = threadIdx.x;
  const int wave = tid >> 6, lane = tid & 63;
  const int l15 = lane & 15, quad = lane >> 4;
  const int bh = blockIdx.x;
  const int b = bh >> 4, h = bh & 15;
  const int p = blockIdx.y;
  const int qt[2] = {p, 31 - p};

  const ushort_t* Kgb = Kg + (size_t)b * S_ * DM_ + h * DH_;
  const ushort_t* Vgb = Vg + (size_t)(h * DH_) * (B_ * S_) + b * S_;

  short8 aq[2][4];
#pragma unroll
  for (int t = 0; t < 2; ++t) {
    const ushort_t* Qg =
        QY + (size_t)(b * S_ + qt[t] * 64 + wave * 16 + l15) * DM_ + h * DH_;
#pragma unroll
    for (int ks = 0; ks < 4; ++ks)
      aq[t][ks] = *(const short8*)(Qg + ks * 32 + quad * 8);
  }

  float lsum[2][4] = {{0.f, 0.f, 0.f, 0.f}, {0.f, 0.f, 0.f, 0.f}};
  floatx4 zero = {0.f, 0.f, 0.f, 0.f};
  floatx4 oacc[2][8];
#pragma unroll
  for (int t = 0; t < 2; ++t)
#pragma unroll
    for (int d = 0; d < 8; ++d) oacc[t][d] = zero;

  const int krow_in = lane >> 4, ksd = lane & 15;
  const int vrow_in = lane >> 3, vsd = lane & 7;

  auto stage = [&](int kt, int bf) {
#pragma unroll
    for (int i = 0; i < 4; ++i) {
      int c = wave * 4 + i;
      {
        int r = c * 4 + krow_in;
        int sg = ksd ^ (r & 7);
        __builtin_amdgcn_global_load_lds(
            AS1(Kgb + (size_t)(kt * 64 + r) * DM_ + sg * 8),
            AS3((char*)Ks[bf] + c * 1024), 16, 0, 0);
      }
      {
        int r = c * 8 + vrow_in;
        int sg = vsd ^ (r & 7);
        __builtin_amdgcn_global_load_lds(
            AS1(Vgb + (size_t)r * (B_ * S_) + kt * 64 + sg * 8),
            AS3((char*)Vs[bf] + c * 1024), 16, 0, 0);
      }
    }
  };

  stage(0, 0);

  for (int kt = 0; kt <= qt[1]; ++kt) {
    const int cur = kt & 1;
    __syncthreads();
    if (kt < qt[1]) stage(kt + 1, cur ^ 1);

#pragma unroll
    for (int t = 0; t < 2; ++t) {
      if (t == 0 && kt > qt[0]) continue;
      floatx4 sacc[4];
#pragma unroll
      for (int j = 0; j < 4; ++j) sacc[j] = zero;
#pragma unroll
      for (int ks = 0; ks < 4; ++ks) {
#pragma unroll
        for (int j = 0; j < 4; ++j) {
          int row = j * 16 + l15;
          int sl = (ks * 4 + quad) ^ (row & 7);
          short8 bk = *(const short8*)&Ks[cur][row * 128 + sl * 8];
          sacc[j] = __builtin_amdgcn_mfma_f32_16x16x32_bf16(aq[t][ks], bk, sacc[j], 0, 0, 0);
        }
      }
      if (kt == qt[t]) {
#pragma unroll
        for (int j = 0; j < 4; ++j)
#pragma unroll
          for (int r = 0; r < 4; ++r) {
            int key = j * 16 + l15;
            int qr = wave * 16 + quad * 4 + r;
            if (key > qr) sacc[j][r] = -1e30f;
          }
      }
#pragma unroll
      for (int j = 0; j < 4; ++j)
#pragma unroll
        for (int r = 0; r < 4; ++r) {
          float pv = fast_exp2(sacc[j][r] - M0);
          sacc[j][r] = pv;
          lsum[t][r] += pv;
        }
#pragma unroll
      for (int j = 0; j < 4; ++j)
#pragma unroll
        for (int r = 0; r < 4; ++r) {
          int row = quad * 4 + r;
          int col = j * 16 + l15;
          int g = col >> 3, w = col & 7;
          Ps[t][wave][row * 64 + ((g ^ (row & 7)) << 3) + w] = f2b(sacc[j][r]);
        }
#pragma unroll
      for (int ks2 = 0; ks2 < 2; ++ks2) {
        short8 ap = *(const short8*)&Ps[t][wave][l15 * 64 +
                                                (((ks2 * 4 + quad) ^ (l15 & 7)) << 3)];
#pragma unroll
        for (int d = 0; d < 8; ++d) {
          int row = d * 16 + l15;
          int sl = (ks2 * 4 + quad) ^ (row & 7);
          short8 bv = *(const short8*)&Vs[cur][row * 64 + sl * 8];
          oacc[t][d] = __builtin_amdgcn_mfma_f32_16x16x32_bf16(ap, bv, oacc[t][d], 0, 0, 0);
        }
      }
    }
  }

#pragma unroll
  for (int t = 0; t < 2; ++t) {
#pragma unroll
    for (int r = 0; r < 4; ++r) {
#pragma unroll
      for (int o = 1; o < 16; o <<= 1) lsum[t][r] += __shfl_xor(lsum[t][r], o, 64);
      float inv = 1.0f / lsum[t][r];
      size_t row = (size_t)(b * S_ + qt[t] * 64 + wave * 16 + quad * 4 + r);
#pragma unroll
      for (int d = 0; d < 8; ++d) {
        size_t col = (size_t)h * DH_ + d * 16 + l15;
        QY[row * DM_ + col] = f2b(oacc[t][d][r] * inv);
      }
    }
  }
}

// ---------------------------------------------------------------------------
extern "C" void kernel_launch(void* const* d_in, const int* in_sizes, int n_in,
                              void* d_out, int out_size, void* d_ws, size_t ws_size,
                              hipStream_t stream) {
  const float* x      = (const float*)d_in[0];
  const float* w_qkv  = (const float*)d_in[1];
  const float* w_out  = (const float*)d_in[2];
  const float* q_gain = (const float*)d_in[3];
  float* out = (float*)d_out;

  // ws (56 MiB, proven): Qraw | Kraw | Vt | wvT
  // d_out (32 MiB) doubles as scratch until the final GEMM: xbf | wqkT
  char* ws = (char*)d_ws;
  const size_t bsd = (size_t)B_ * S_ * DM_;  // 8,388,608 elems
  ushort_t* Qraw = (ushort_t*)ws;
  ushort_t* Kraw = Qraw + bsd;
  ushort_t* Vt   = Kraw + bsd;                    // [dim][b*S+s]
  ushort_t* wvT  = Vt + bsd;                      // [2048][2048]
  ushort_t* xbf  = (ushort_t*)d_out;              // [4096][2048] bf16
  ushort_t* wqkT = xbf + bsd;                     // [4096][2048] bf16 (Wq|Wk)^T
  ushort_t* woutT = Kraw;                         // after attn, Kraw is dead

  convert_f32_bf16<<<dim3(bsd / (8 * 256)), 256, 0, stream>>>(x, xbf);
  transpose_f32_to_bf16T<<<dim3(64, 32), 256, 0, stream>>>(w_qkv, wqkT, DM_, 3 * DM_, 0);
  transpose_f32_to_bf16T<<<dim3(32, 32), 256, 0, stream>>>(w_qkv, wvT, DM_, 3 * DM_, 2 * DM_);

  // Q and K in one fused GEMM (split-C epilogue), 256^2 deep-pipeline kernel.
  gemm_bt_256<2><<<dim3(16, 16), 512, 0, stream>>>(xbf, wqkT, Qraw, Kraw,
                                                   B_ * S_, 2 * DM_, DM_);
  // V^T = WvT * x^T  -> Vt[dim][b*S+s]  (M=2048: 128^2 pipeline, 512 blocks = 2/CU)
  gemm_bt_128<0><<<dim3(32, 16), 256, 0, stream>>>(wvT, xbf, Vt,
                                                   DM_, B_ * S_, DM_);
  norm_rope<<<dim3(B_ * S_ * H_ / 16), 256, 0, stream>>>(Qraw, Kraw, q_gain);
  attn<<<dim3(B_ * H_, S_ / 128), 256, 0, stream>>>(Qraw, Kraw, Vt);
  // w_out^T into dead Kraw region, then final GEMM (f32 out over d_out)
  transpose_f32_to_bf16T<<<dim3(32, 32), 256, 0, stream>>>(w_out, woutT, DM_, DM_, 0);
  gemm_bt_128<1><<<dim3(16, 32), 256, 0, stream>>>(Qraw, woutT, out,
                                                   B_ * S_, DM_, DM_);
}

// Round 4
// 352.640 us; speedup vs baseline: 1.1912x; 1.0315x over previous
//
#include <hip/hip_runtime.h>
#include <hip/hip_bf16.h>

typedef unsigned short ushort_t;
typedef __attribute__((ext_vector_type(8))) short short8;
typedef __attribute__((ext_vector_type(4))) float floatx4;

#define B_  2
#define S_  2048
#define DM_ 2048
#define H_  16
#define DH_ 128

#define AS1(p) ((const __attribute__((address_space(1))) void*)(p))
#define AS3(p) ((__attribute__((address_space(3))) void*)(p))

static __device__ __forceinline__ float b2f(ushort_t u) {
  __hip_bfloat16 h = *reinterpret_cast<__hip_bfloat16*>(&u);
  return __bfloat162float(h);
}
static __device__ __forceinline__ ushort_t f2b(float f) {
  __hip_bfloat16 h = __float2bfloat16(f);
  return *reinterpret_cast<ushort_t*>(&h);
}
static __device__ __forceinline__ float fast_exp2(float x) {
#if defined(__has_builtin)
#if __has_builtin(__builtin_amdgcn_exp2f)
  return __builtin_amdgcn_exp2f(x);
#else
  return exp2f(x);
#endif
#else
  return exp2f(x);
#endif
}

// ---------------------------------------------------------------------------
// x (f32) -> bf16, 8 elems/thread.
// ---------------------------------------------------------------------------
__global__ __launch_bounds__(256) void convert_f32_bf16(const float* __restrict__ in,
                                                        ushort_t* __restrict__ out) {
  size_t i = ((size_t)blockIdx.x * 256 + threadIdx.x) * 8;
  float4 a = *(const float4*)(in + i);
  float4 b = *(const float4*)(in + i + 4);
  ushort_t tmp[8] = {f2b(a.x), f2b(a.y), f2b(a.z), f2b(a.w),
                     f2b(b.x), f2b(b.y), f2b(b.z), f2b(b.w)};
  *(uint4*)(out + i) = *(const uint4*)tmp;
}

// ---------------------------------------------------------------------------
// out[c][r] = bf16(in[r][colOff + c]); in f32 [R][inC], out bf16 [64*gx][R].
// ---------------------------------------------------------------------------
__global__ __launch_bounds__(256) void transpose_f32_to_bf16T(const float* __restrict__ in,
                                                              ushort_t* __restrict__ out,
                                                              int R, int inC, int colOff) {
  __shared__ ushort_t tile[64][72];
  const int tid = threadIdx.x;
  const int r0 = blockIdx.y * 64, c0 = blockIdx.x * 64;
#pragma unroll
  for (int p = 0; p < 2; ++p) {
    int li = tid + p * 256;
    int r = li >> 3, cs = (li & 7) * 8;
    const float* src = in + (size_t)(r0 + r) * inC + colOff + c0 + cs;
    float4 a = *(const float4*)src;
    float4 b = *(const float4*)(src + 4);
    ushort_t tmp[8] = {f2b(a.x), f2b(a.y), f2b(a.z), f2b(a.w),
                       f2b(b.x), f2b(b.y), f2b(b.z), f2b(b.w)};
    *(uint4*)&tile[r][cs] = *(const uint4*)tmp;
  }
  __syncthreads();
#pragma unroll
  for (int p = 0; p < 2; ++p) {
    int li = tid + p * 256;
    int cR = li >> 3, rs = (li & 7) * 8;
    ushort_t tmp[8];
#pragma unroll
    for (int e = 0; e < 8; ++e) tmp[e] = tile[rs + e][cR];
    *(uint4*)(out + (size_t)(c0 + cR) * R + r0 + rs) = *(const uint4*)tmp;
  }
}

// ---------------------------------------------------------------------------
// Both w_qkv transposes in ONE launch (z selects target): z=0 -> (Wq|Wk)^T
// (64 col-blocks), z=1 -> Wv^T (32 col-blocks, colOff 2*DM_).
// ---------------------------------------------------------------------------
__global__ __launch_bounds__(256) void transpose_wqkv(const float* __restrict__ in,
                                                      ushort_t* __restrict__ outQK,
                                                      ushort_t* __restrict__ outV) {
  const int z = blockIdx.z;
  if (z == 1 && blockIdx.x >= 32) return;
  ushort_t* out = z ? outV : outQK;
  const int colOff = z ? 2 * DM_ : 0;
  const int R = DM_, inC = 3 * DM_;
  __shared__ ushort_t tile[64][72];
  const int tid = threadIdx.x;
  const int r0 = blockIdx.y * 64, c0 = blockIdx.x * 64;
#pragma unroll
  for (int p = 0; p < 2; ++p) {
    int li = tid + p * 256;
    int r = li >> 3, cs = (li & 7) * 8;
    const float* src = in + (size_t)(r0 + r) * inC + colOff + c0 + cs;
    float4 a = *(const float4*)src;
    float4 b = *(const float4*)(src + 4);
    ushort_t tmp[8] = {f2b(a.x), f2b(a.y), f2b(a.z), f2b(a.w),
                       f2b(b.x), f2b(b.y), f2b(b.z), f2b(b.w)};
    *(uint4*)&tile[r][cs] = *(const uint4*)tmp;
  }
  __syncthreads();
#pragma unroll
  for (int p = 0; p < 2; ++p) {
    int li = tid + p * 256;
    int cR = li >> 3, rs = (li & 7) * 8;
    ushort_t tmp[8];
#pragma unroll
    for (int e = 0; e < 8; ++e) tmp[e] = tile[rs + e][cR];
    *(uint4*)(out + (size_t)(c0 + cR) * R + r0 + rs) = *(const uint4*)tmp;
  }
}

#define SBAR() __builtin_amdgcn_sched_barrier(0)
#define BARR() __builtin_amdgcn_s_barrier()

// ---------------------------------------------------------------------------
// GEMM 256x256, BK=64, 8 waves (2Mx4N), 4-phase schedule, counted vmcnt.
// ROUND-3 CHANGE: ONE barrier per phase (closing only). The pre-MFMA barrier
// was pacing-only: every phase's ds_reads are consumed by that phase's MFMA
// (lgkm drains before barrier arrival), and every stage-write WAR hazard is
// separated from its last reader by >=1 phase-closing barrier:
//   ph1 stage B0(kt+1)->Bs[bb^1] rows 0..127:   last read ph1/ph3 of kt-1  OK
//   ph2 stage B1(kt+1)->Bs[bb^1] rows 128..255: last read ph1/ph3 of kt-1  OK
//   ph3 stage A0(kt+2)->As[bb]  rows 0..127:    last read ph1/ph2 (wm=0)   OK
//   ph4 stage A1(kt+2)->As[bb]  rows 128..255:  last read ph1/ph2 (wm=1)   OK
// Removing it lets waves drift within a phase -> cross-wave DS/MFMA overlap.
// MODE 2: C bf16 split: cols [0,2048)->C0, [2048,4096)->C1, ld=2048.
// ---------------------------------------------------------------------------
#define LDS_A(qm, bb)                                                          \
  _Pragma("unroll") for (int mi = 0; mi < 4; ++mi) {                           \
    _Pragma("unroll") for (int ks = 0; ks < 2; ++ks) {                         \
      const int r_ = arow + (qm) * 64 + mi * 16;                               \
      const int cb_ = ((ks) * 64 + quad * 16) ^ swz;                           \
      afr[qm][mi][ks] =                                                        \
          *(const short8*)((const char*)As[bb] + r_ * 128 + cb_);              \
    }                                                                          \
  }

#define LDS_B(qn, bb)                                                          \
  _Pragma("unroll") for (int ni = 0; ni < 2; ++ni) {                           \
    _Pragma("unroll") for (int ks = 0; ks < 2; ++ks) {                         \
      const int r_ = brow + (qn) * 32 + ni * 16;                               \
      const int cb_ = ((ks) * 64 + quad * 16) ^ swz;                           \
      bfr[qn][ni][ks] =                                                        \
          *(const short8*)((const char*)Bs[bb] + r_ * 128 + cb_);              \
    }                                                                          \
  }

#define MMA_Q(qm, qn)                                                          \
  _Pragma("unroll") for (int mi = 0; mi < 4; ++mi) {                           \
    _Pragma("unroll") for (int ni = 0; ni < 2; ++ni) {                         \
      floatx4 t_ = acc[(qm) * 4 + mi][(qn) * 2 + ni];                          \
      t_ = __builtin_amdgcn_mfma_f32_16x16x32_bf16(afr[qm][mi][0],             \
                                                   bfr[qn][ni][0], t_, 0, 0, 0); \
      t_ = __builtin_amdgcn_mfma_f32_16x16x32_bf16(afr[qm][mi][1],             \
                                                   bfr[qn][ni][1], t_, 0, 0, 0); \
      acc[(qm) * 4 + mi][(qn) * 2 + ni] = t_;                                  \
    }                                                                          \
  }

template <int MODE>
__global__ __launch_bounds__(512, 2) void gemm_bt_256(const ushort_t* __restrict__ A,
                                                      const ushort_t* __restrict__ Bt,
                                                      void* __restrict__ C0,
                                                      void* __restrict__ C1,
                                                      int M, int N, int K) {
  __shared__ alignas(16) ushort_t As[2][256 * 64];
  __shared__ alignas(16) ushort_t Bs[2][256 * 64];
  const int tid = threadIdx.x;
  const int wave = tid >> 6, lane = tid & 63;
  const int l15 = lane & 15, quad = lane >> 4;
  const int wm = wave >> 2, wn = wave & 3;  // 2 x 4 wave grid
  const size_t m0 = (size_t)blockIdx.y * 256, n0 = (size_t)blockIdx.x * 256;
  const int nkt = K >> 6;  // K-tiles of 64

  const int srow = lane >> 3;                 // row within 8-row chunk
  const int skk = ((lane & 7) ^ srow) * 8;    // swizzled k offset (bf16)

  const int arow = wm * 128 + l15;
  const int brow = wn * 64 + l15;
  const int swz = (l15 & 7) << 4;

  floatx4 zero = {0.f, 0.f, 0.f, 0.f};
  floatx4 acc[8][4];
#pragma unroll
  for (int i = 0; i < 8; ++i)
#pragma unroll
    for (int j = 0; j < 4; ++j) acc[i][j] = zero;

  short8 afr[2][4][2];  // [qm][mi][ks]
  short8 bfr[2][2][2];  // [qn][ni][ks]

  // half-tiles: 0=A rows 0..127, 1=A rows 128..255, 2=B rows 0..127, 3=B rows 128..255
  auto stage_half = [&](int t, int ht) {
    if (t >= nkt) return;
    const int bb = t & 1;
    const int h = ht & 1;
    const int kt64 = t << 6;
    const ushort_t* G = (ht < 2) ? A : Bt;
    const size_t r0 = (ht < 2) ? m0 : n0;
    char* dst = (char*)((ht < 2) ? As[bb] : Bs[bb]) + h * 16384;
#pragma unroll
    for (int i = 0; i < 2; ++i) {
      const int c = wave * 2 + i;
      const size_t gr = r0 + h * 128 + c * 8 + srow;
      __builtin_amdgcn_global_load_lds(AS1(G + gr * K + kt64 + skk),
                                       AS3(dst + c * 1024), 16, 0, 0);
    }
  };

  // prologue: tile 0 fully + A-halves of tile 1 (12 loads/thread)
  stage_half(0, 0); stage_half(0, 1); stage_half(0, 2); stage_half(0, 3);
  stage_half(1, 0); stage_half(1, 1);
  SBAR();
  if (nkt > 1) { asm volatile("s_waitcnt vmcnt(4)" ::: "memory"); }
  else         { asm volatile("s_waitcnt vmcnt(0)" ::: "memory"); }
  SBAR(); BARR(); SBAR();

  for (int kt = 0; kt < nkt; ++kt) {
    const int bb = kt & 1;
    // ---- phase 1: read A[qm0]+B[qn0]; stage B-half0 of tile kt+1 -> other buf
    LDS_A(0, bb); LDS_B(0, bb);
    stage_half(kt + 1, 2);
    SBAR();
    __builtin_amdgcn_s_setprio(1);
    MMA_Q(0, 0);
    __builtin_amdgcn_s_setprio(0);
    SBAR(); BARR(); SBAR();
    // ---- phase 2: read A[qm1]; stage B-half1 of tile kt+1 -> other buf
    LDS_A(1, bb);
    stage_half(kt + 1, 3);
    SBAR();
    __builtin_amdgcn_s_setprio(1);
    MMA_Q(1, 0);
    __builtin_amdgcn_s_setprio(0);
    SBAR(); BARR(); SBAR();
    // ---- phase 3: read B[qn1]; stage A-half0 of tile kt+2 -> this buf
    LDS_B(1, bb);
    stage_half(kt + 2, 0);
    SBAR();
    __builtin_amdgcn_s_setprio(1);
    MMA_Q(1, 1);
    __builtin_amdgcn_s_setprio(0);
    SBAR(); BARR(); SBAR();
    // ---- phase 4: stage A-half1 of tile kt+2 -> this buf
    stage_half(kt + 2, 1);
    SBAR();
    __builtin_amdgcn_s_setprio(1);
    MMA_Q(0, 1);
    __builtin_amdgcn_s_setprio(0);
    SBAR();
    if (kt + 2 < nkt) { asm volatile("s_waitcnt vmcnt(4)" ::: "memory"); }
    else              { asm volatile("s_waitcnt vmcnt(0)" ::: "memory"); }
    SBAR(); BARR(); SBAR();
  }

  // epilogue
  if (MODE == 2) {
    ushort_t* Cb = (n0 >= 2048) ? (ushort_t*)C1 : (ushort_t*)C0;
    size_t nc0 = n0 & 2047;
#pragma unroll
    for (int mi8 = 0; mi8 < 8; ++mi8)
#pragma unroll
      for (int nj = 0; nj < 4; ++nj)
#pragma unroll
        for (int r = 0; r < 4; ++r) {
          size_t row = m0 + wm * 128 + (mi8 >> 2) * 64 + (mi8 & 3) * 16 + quad * 4 + r;
          size_t col = nc0 + wn * 64 + (nj >> 1) * 32 + (nj & 1) * 16 + l15;
          Cb[row * 2048 + col] = f2b(acc[mi8][nj][r]);
        }
  } else {
#pragma unroll
    for (int mi8 = 0; mi8 < 8; ++mi8)
#pragma unroll
      for (int nj = 0; nj < 4; ++nj)
#pragma unroll
        for (int r = 0; r < 4; ++r) {
          size_t row = m0 + wm * 128 + (mi8 >> 2) * 64 + (mi8 & 3) * 16 + quad * 4 + r;
          size_t col = n0 + wn * 64 + (nj >> 1) * 32 + (nj & 1) * 16 + l15;
          if (MODE == 1)
            ((float*)C0)[row * N + col] = acc[mi8][nj][r];
          else
            ((ushort_t*)C0)[row * N + col] = f2b(acc[mi8][nj][r]);
        }
  }
}

// ---------------------------------------------------------------------------
// GEMM 128x128, BK=64, 4 waves (2Mx2N), 4-phase deep-pipeline, 64 KiB LDS ->
// 2 blocks/CU. Same single-barrier-per-phase change as gemm_bt_256 (WAR
// audit identical: A-quadrant reads finish by ph2-close; B-quadrant reads of
// the other buffer finish by ph3-close of the prior tile).
// MODE 0: C bf16, ld=N.  MODE 1: C f32, ld=N.
// ---------------------------------------------------------------------------
#define LDS_A8(mh, bb)                                                         \
  _Pragma("unroll") for (int mi = 0; mi < 2; ++mi) {                           \
    _Pragma("unroll") for (int ks = 0; ks < 2; ++ks) {                         \
      const int r_ = arow + ((mh) * 2 + mi) * 16;                              \
      const int cb_ = ((ks) * 64 + quad * 16) ^ swz;                           \
      afr[(mh) * 2 + mi][ks] =                                                 \
          *(const short8*)((const char*)As[bb] + r_ * 128 + cb_);              \
    }                                                                          \
  }

#define LDS_B8(nh, bb)                                                         \
  _Pragma("unroll") for (int ni = 0; ni < 2; ++ni) {                           \
    _Pragma("unroll") for (int ks = 0; ks < 2; ++ks) {                         \
      const int r_ = brow + ((nh) * 2 + ni) * 16;                              \
      const int cb_ = ((ks) * 64 + quad * 16) ^ swz;                           \
      bfr[(nh) * 2 + ni][ks] =                                                 \
          *(const short8*)((const char*)Bs[bb] + r_ * 128 + cb_);              \
    }                                                                          \
  }

#define MMA_H(mh, nh)                                                          \
  _Pragma("unroll") for (int mi = 0; mi < 2; ++mi) {                           \
    _Pragma("unroll") for (int ni = 0; ni < 2; ++ni) {                         \
      floatx4 t_ = acc[(mh) * 2 + mi][(nh) * 2 + ni];                          \
      t_ = __builtin_amdgcn_mfma_f32_16x16x32_bf16(afr[(mh) * 2 + mi][0],      \
                                                   bfr[(nh) * 2 + ni][0], t_, 0, 0, 0); \
      t_ = __builtin_amdgcn_mfma_f32_16x16x32_bf16(afr[(mh) * 2 + mi][1],      \
                                                   bfr[(nh) * 2 + ni][1], t_, 0, 0, 0); \
      acc[(mh) * 2 + mi][(nh) * 2 + ni] = t_;                                  \
    }                                                                          \
  }

template <int MODE>
__global__ __launch_bounds__(256, 2) void gemm_bt_128(const ushort_t* __restrict__ A,
                                                      const ushort_t* __restrict__ Bt,
                                                      void* __restrict__ C0,
                                                      int M, int N, int K) {
  __shared__ alignas(16) ushort_t As[2][128 * 64];
  __shared__ alignas(16) ushort_t Bs[2][128 * 64];
  const int tid = threadIdx.x;
  const int wave = tid >> 6, lane = tid & 63;
  const int l15 = lane & 15, quad = lane >> 4;
  const int wm = wave >> 1, wn = wave & 1;  // 2 x 2 wave grid
  const int lin = blockIdx.y * gridDim.x + blockIdx.x;
  const int band = lin / (4 * gridDim.x);
  const int rin = lin % (4 * gridDim.x);
  const int by = band * 4 + (rin & 3);
  const int bx = rin >> 2;
  const size_t m0 = (size_t)by * 128, n0 = (size_t)bx * 128;
  const int nkt = K >> 6;

  const int srow = lane >> 3;
  const int skk = ((lane & 7) ^ srow) * 8;

  const int arow = wm * 64 + l15;
  const int brow = wn * 64 + l15;
  const int swz = (l15 & 7) << 4;

  floatx4 zero = {0.f, 0.f, 0.f, 0.f};
  floatx4 acc[4][4];
#pragma unroll
  for (int i = 0; i < 4; ++i)
#pragma unroll
    for (int j = 0; j < 4; ++j) acc[i][j] = zero;

  short8 afr[4][2];
  short8 bfr[4][2];

  auto stage_q = [&](int t, int qt_) {
    if (t >= nkt) return;
    const int bb = t & 1;
    const int h = qt_ & 1;
    const int kt64 = t << 6;
    const ushort_t* G = (qt_ < 2) ? A : Bt;
    const size_t r0 = (qt_ < 2) ? m0 : n0;
    char* dst = (char*)((qt_ < 2) ? As[bb] : Bs[bb]) + h * 8192;
#pragma unroll
    for (int i = 0; i < 2; ++i) {
      const int c = wave * 2 + i;
      const size_t gr = r0 + h * 64 + c * 8 + srow;
      __builtin_amdgcn_global_load_lds(AS1(G + gr * K + kt64 + skk),
                                       AS3(dst + c * 1024), 16, 0, 0);
    }
  };

  stage_q(0, 0); stage_q(0, 1); stage_q(0, 2); stage_q(0, 3);
  stage_q(1, 0); stage_q(1, 1);
  SBAR();
  if (nkt > 1) { asm volatile("s_waitcnt vmcnt(4)" ::: "memory"); }
  else         { asm volatile("s_waitcnt vmcnt(0)" ::: "memory"); }
  SBAR(); BARR(); SBAR();

  for (int kt = 0; kt < nkt; ++kt) {
    const int bb = kt & 1;
    // ---- phase 1
    LDS_A8(0, bb); LDS_B8(0, bb);
    stage_q(kt + 1, 2);
    SBAR();
    __builtin_amdgcn_s_setprio(1);
    MMA_H(0, 0);
    __builtin_amdgcn_s_setprio(0);
    SBAR(); BARR(); SBAR();
    // ---- phase 2
    LDS_A8(1, bb);
    stage_q(kt + 1, 3);
    SBAR();
    __builtin_amdgcn_s_setprio(1);
    MMA_H(1, 0);
    __builtin_amdgcn_s_setprio(0);
    SBAR(); BARR(); SBAR();
    // ---- phase 3
    LDS_B8(1, bb);
    stage_q(kt + 2, 0);
    SBAR();
    __builtin_amdgcn_s_setprio(1);
    MMA_H(1, 1);
    __builtin_amdgcn_s_setprio(0);
    SBAR(); BARR(); SBAR();
    // ---- phase 4
    stage_q(kt + 2, 1);
    SBAR();
    __builtin_amdgcn_s_setprio(1);
    MMA_H(0, 1);
    __builtin_amdgcn_s_setprio(0);
    SBAR();
    if (kt + 2 < nkt) { asm volatile("s_waitcnt vmcnt(4)" ::: "memory"); }
    else              { asm volatile("s_waitcnt vmcnt(0)" ::: "memory"); }
    SBAR(); BARR(); SBAR();
  }

#pragma unroll
  for (int i = 0; i < 4; ++i)
#pragma unroll
    for (int j = 0; j < 4; ++j)
#pragma unroll
      for (int r = 0; r < 4; ++r) {
        size_t row = m0 + wm * 64 + i * 16 + quad * 4 + r;
        size_t col = n0 + wn * 64 + j * 16 + l15;
        if (MODE == 1)
          ((float*)C0)[row * N + col] = acc[i][j][r];
        else
          ((ushort_t*)C0)[row * N + col] = f2b(acc[i][j][r]);
      }
}

// ---------------------------------------------------------------------------
// unit-norm + RoPE (even heads) + gain-fold (gain * log2e for exp2 softmax),
// in place. Vectorized: 16 lanes per row, 4 rows per wave.
// ---------------------------------------------------------------------------
__global__ __launch_bounds__(256) void norm_rope(ushort_t* __restrict__ Q,
                                                 ushort_t* __restrict__ Kb,
                                                 const float* __restrict__ gain) {
  const int tid = threadIdx.x;
  const int wave = tid >> 6, lane = tid & 63;
  const int g16 = lane >> 4, sl = lane & 15;
  const int idx = (blockIdx.x * 4 + wave) * 4 + g16;  // ((b*S+s)*H + h)
  const int h = idx & 15;
  const int s = (idx >> 4) & (S_ - 1);
  const size_t off = (size_t)(idx >> 4) * DM_ + h * DH_ + sl * 4;

  ushort_t qv1[4], qv2[4], kv1[4], kv2[4];
  *(uint2*)qv1 = *(const uint2*)(Q + off);
  *(uint2*)qv2 = *(const uint2*)(Q + off + 64);
  *(uint2*)kv1 = *(const uint2*)(Kb + off);
  *(uint2*)kv2 = *(const uint2*)(Kb + off + 64);

  float q1[4], q2[4], k1[4], k2[4];
  float sq = 0.f, sk = 0.f;
#pragma unroll
  for (int e = 0; e < 4; ++e) {
    q1[e] = b2f(qv1[e]); q2[e] = b2f(qv2[e]);
    k1[e] = b2f(kv1[e]); k2[e] = b2f(kv2[e]);
    sq += q1[e] * q1[e] + q2[e] * q2[e];
    sk += k1[e] * k1[e] + k2[e] * k2[e];
  }
#pragma unroll
  for (int o = 1; o < 16; o <<= 1) {
    sq += __shfl_xor(sq, o, 64);
    sk += __shfl_xor(sk, o, 64);
  }
  float rq = rsqrtf(sq + 1e-6f), rk = rsqrtf(sk + 1e-6f);
  const float g = gain[h] * 1.44269504f;  // fold log2(e): attn uses exp2
  const bool roped = (h & 1) == 0;        // ROPE_MASK tiles [1,0] over heads
#pragma unroll
  for (int e = 0; e < 4; ++e) {
    float a = q1[e] * rq, bq = q2[e] * rq;
    float c_ = k1[e] * rk, dk = k2[e] * rk;
    if (roped) {
      int j = sl * 4 + e;
      float invf = exp2f((float)j * -0.20762050593f);  // log2(10000)/64
      float th = (float)s * invf;
      float cc = cosf(th), sn = sinf(th);
      float na = a * cc - bq * sn, nb = a * sn + bq * cc;
      float nc = c_ * cc - dk * sn, nd = c_ * sn + dk * cc;
      a = na; bq = nb; c_ = nc; dk = nd;
    }
    qv1[e] = f2b(a * g); qv2[e] = f2b(bq * g);
    kv1[e] = f2b(c_);    kv2[e] = f2b(dk);
  }
  *(uint2*)(Q + off)       = *(const uint2*)qv1;
  *(uint2*)(Q + off + 64)  = *(const uint2*)qv2;
  *(uint2*)(Kb + off)      = *(const uint2*)kv1;
  *(uint2*)(Kb + off + 64) = *(const uint2*)kv2;
}

// ---------------------------------------------------------------------------
// Flash attention v3: balanced tile pairs {p, 31-p}, fixed-max softmax
// (exp2 form, log2e pre-folded into q-gain), double-buffered K/V, per-wave
// Ps, 1 barrier/iter. V layout: [dim][b*S+s]. Y written in place over Q.
// Grid (bh, p): XCD = bh%8 -> per-XCD K/V working set fits its 4MB L2.
// ---------------------------------------------------------------------------
__global__ __launch_bounds__(256, 2) void attn(ushort_t* __restrict__ QY,
                                               const ushort_t* __restrict__ Kg,
                                               const ushort_t* __restrict__ Vg) {
  __shared__ alignas(16) ushort_t Ks[2][64 * 128];
  __shared__ alignas(16) ushort_t Vs[2][128 * 64];
  __shared__ alignas(16) ushort_t Ps[2][4][16 * 64];

  const float M0 = 18.755035531f;  // 13 * log2(e)
  const int tid = threadIdx.x;
  const int wave = tid >> 6, lane = tid & 63;
  const int l15 = lane & 15, quad = lane >> 4;
  const int bh = blockIdx.x;
  const int b = bh >> 4, h = bh & 15;
  const int p = blockIdx.y;
  const int qt[2] = {p, 31 - p};

  const ushort_t* Kgb = Kg + (size_t)b * S_ * DM_ + h * DH_;
  const ushort_t* Vgb = Vg + (size_t)(h * DH_) * (B_ * S_) + b * S_;

  short8 aq[2][4];
#pragma unroll
  for (int t = 0; t < 2; ++t) {
    const ushort_t* Qg =
        QY + (size_t)(b * S_ + qt[t] * 64 + wave * 16 + l15) * DM_ + h * DH_;
#pragma unroll
    for (int ks = 0; ks < 4; ++ks)
      aq[t][ks] = *(const short8*)(Qg + ks * 32 + quad * 8);
  }

  float lsum[2][4] = {{0.f, 0.f, 0.f, 0.f}, {0.f, 0.f, 0.f, 0.f}};
  floatx4 zero = {0.f, 0.f, 0.f, 0.f};
  floatx4 oacc[2][8];
#pragma unroll
  for (int t = 0; t < 2; ++t)
#pragma unroll
    for (int d = 0; d < 8; ++d) oacc[t][d] = zero;

  const int krow_in = lane >> 4, ksd = lane & 15;
  const int vrow_in = lane >> 3, vsd = lane & 7;

  auto stage = [&](int kt, int bf) {
#pragma unroll
    for (int i = 0; i < 4; ++i) {
      int c = wave * 4 + i;
      {
        int r = c * 4 + krow_in;
        int sg = ksd ^ (r & 7);
        __builtin_amdgcn_global_load_lds(
            AS1(Kgb + (size_t)(kt * 64 + r) * DM_ + sg * 8),
            AS3((char*)Ks[bf] + c * 1024), 16, 0, 0);
      }
      {
        int r = c * 8 + vrow_in;
        int sg = vsd ^ (r & 7);
        __builtin_amdgcn_global_load_lds(
            AS1(Vgb + (size_t)r * (B_ * S_) + kt * 64 + sg * 8),
            AS3((char*)Vs[bf] + c * 1024), 16, 0, 0);
      }
    }
  };

  stage(0, 0);

  for (int kt = 0; kt <= qt[1]; ++kt) {
    const int cur = kt & 1;
    __syncthreads();
    if (kt < qt[1]) stage(kt + 1, cur ^ 1);

#pragma unroll
    for (int t = 0; t < 2; ++t) {
      if (t == 0 && kt > qt[0]) continue;
      floatx4 sacc[4];
#pragma unroll
      for (int j = 0; j < 4; ++j) sacc[j] = zero;
#pragma unroll
      for (int ks = 0; ks < 4; ++ks) {
#pragma unroll
        for (int j = 0; j < 4; ++j) {
          int row = j * 16 + l15;
          int sl = (ks * 4 + quad) ^ (row & 7);
          short8 bk = *(const short8*)&Ks[cur][row * 128 + sl * 8];
          sacc[j] = __builtin_amdgcn_mfma_f32_16x16x32_bf16(aq[t][ks], bk, sacc[j], 0, 0, 0);
        }
      }
      if (kt == qt[t]) {
#pragma unroll
        for (int j = 0; j < 4; ++j)
#pragma unroll
          for (int r = 0; r < 4; ++r) {
            int key = j * 16 + l15;
            int qr = wave * 16 + quad * 4 + r;
            if (key > qr) sacc[j][r] = -1e30f;
          }
      }
#pragma unroll
      for (int j = 0; j < 4; ++j)
#pragma unroll
        for (int r = 0; r < 4; ++r) {
          float pv = fast_exp2(sacc[j][r] - M0);
          sacc[j][r] = pv;
          lsum[t][r] += pv;
        }
#pragma unroll
      for (int j = 0; j < 4; ++j)
#pragma unroll
        for (int r = 0; r < 4; ++r) {
          int row = quad * 4 + r;
          int col = j * 16 + l15;
          int g = col >> 3, w = col & 7;
          Ps[t][wave][row * 64 + ((g ^ (row & 7)) << 3) + w] = f2b(sacc[j][r]);
        }
#pragma unroll
      for (int ks2 = 0; ks2 < 2; ++ks2) {
        short8 ap = *(const short8*)&Ps[t][wave][l15 * 64 +
                                                (((ks2 * 4 + quad) ^ (l15 & 7)) << 3)];
#pragma unroll
        for (int d = 0; d < 8; ++d) {
          int row = d * 16 + l15;
          int sl = (ks2 * 4 + quad) ^ (row & 7);
          short8 bv = *(const short8*)&Vs[cur][row * 64 + sl * 8];
          oacc[t][d] = __builtin_amdgcn_mfma_f32_16x16x32_bf16(ap, bv, oacc[t][d], 0, 0, 0);
        }
      }
    }
  }

#pragma unroll
  for (int t = 0; t < 2; ++t) {
#pragma unroll
    for (int r = 0; r < 4; ++r) {
#pragma unroll
      for (int o = 1; o < 16; o <<= 1) lsum[t][r] += __shfl_xor(lsum[t][r], o, 64);
      float inv = 1.0f / lsum[t][r];
      size_t row = (size_t)(b * S_ + qt[t] * 64 + wave * 16 + quad * 4 + r);
#pragma unroll
      for (int d = 0; d < 8; ++d) {
        size_t col = (size_t)h * DH_ + d * 16 + l15;
        QY[row * DM_ + col] = f2b(oacc[t][d][r] * inv);
      }
    }
  }
}

// ---------------------------------------------------------------------------
extern "C" void kernel_launch(void* const* d_in, const int* in_sizes, int n_in,
                              void* d_out, int out_size, void* d_ws, size_t ws_size,
                              hipStream_t stream) {
  const float* x      = (const float*)d_in[0];
  const float* w_qkv  = (const float*)d_in[1];
  const float* w_out  = (const float*)d_in[2];
  const float* q_gain = (const float*)d_in[3];
  float* out = (float*)d_out;

  // ws (56 MiB, proven): Qraw | Kraw | Vt | wvT
  // d_out (32 MiB) doubles as scratch until the final GEMM: xbf | wqkT
  char* ws = (char*)d_ws;
  const size_t bsd = (size_t)B_ * S_ * DM_;  // 8,388,608 elems
  ushort_t* Qraw = (ushort_t*)ws;
  ushort_t* Kraw = Qraw + bsd;
  ushort_t* Vt   = Kraw + bsd;                    // [dim][b*S+s]
  ushort_t* wvT  = Vt + bsd;                      // [2048][2048]
  ushort_t* xbf  = (ushort_t*)d_out;              // [4096][2048] bf16
  ushort_t* wqkT = xbf + bsd;                     // [4096][2048] bf16 (Wq|Wk)^T
  ushort_t* woutT = Kraw;                         // after attn, Kraw is dead

  convert_f32_bf16<<<dim3(bsd / (8 * 256)), 256, 0, stream>>>(x, xbf);
  transpose_wqkv<<<dim3(64, 32, 2), 256, 0, stream>>>(w_qkv, wqkT, wvT);

  // Q and K in one fused GEMM (split-C epilogue), 256^2 deep-pipeline kernel.
  gemm_bt_256<2><<<dim3(16, 16), 512, 0, stream>>>(xbf, wqkT, Qraw, Kraw,
                                                   B_ * S_, 2 * DM_, DM_);
  // V^T = WvT * x^T  -> Vt[dim][b*S+s]  (M=2048: 128^2 pipeline, 512 blocks = 2/CU)
  gemm_bt_128<0><<<dim3(32, 16), 256, 0, stream>>>(wvT, xbf, Vt,
                                                   DM_, B_ * S_, DM_);
  norm_rope<<<dim3(B_ * S_ * H_ / 16), 256, 0, stream>>>(Qraw, Kraw, q_gain);
  attn<<<dim3(B_ * H_, S_ / 128), 256, 0, stream>>>(Qraw, Kraw, Vt);
  // w_out^T into dead Kraw region, then final GEMM (f32 out over d_out)
  transpose_f32_to_bf16T<<<dim3(32, 32), 256, 0, stream>>>(w_out, woutT, DM_, DM_, 0);
  gemm_bt_128<1><<<dim3(16, 32), 256, 0, stream>>>(Qraw, woutT, out,
                                                   B_ * S_, DM_, DM_);
}

// Round 5
// 349.958 us; speedup vs baseline: 1.2003x; 1.0077x over previous
//
#include <hip/hip_runtime.h>
#include <hip/hip_bf16.h>

typedef unsigned short ushort_t;
typedef __attribute__((ext_vector_type(8))) short short8;
typedef __attribute__((ext_vector_type(4))) float floatx4;

#define B_  2
#define S_  2048
#define DM_ 2048
#define H_  16
#define DH_ 128

#define AS1(p) ((const __attribute__((address_space(1))) void*)(p))
#define AS3(p) ((__attribute__((address_space(3))) void*)(p))

static __device__ __forceinline__ float b2f(ushort_t u) {
  __hip_bfloat16 h = *reinterpret_cast<__hip_bfloat16*>(&u);
  return __bfloat162float(h);
}
static __device__ __forceinline__ ushort_t f2b(float f) {
  __hip_bfloat16 h = __float2bfloat16(f);
  return *reinterpret_cast<ushort_t*>(&h);
}
static __device__ __forceinline__ float fast_exp2(float x) {
#if defined(__has_builtin)
#if __has_builtin(__builtin_amdgcn_exp2f)
  return __builtin_amdgcn_exp2f(x);
#else
  return exp2f(x);
#endif
#else
  return exp2f(x);
#endif
}

// ---------------------------------------------------------------------------
// shared transpose body: out[c][r] = bf16(in[r][colOff+c]), 64x64 tile.
// ---------------------------------------------------------------------------
static __device__ __forceinline__ void transpose_body(const float* __restrict__ in,
                                                      ushort_t* __restrict__ out,
                                                      int R, int inC, int colOff,
                                                      int bx, int by,
                                                      ushort_t (*tile)[72], int tid) {
  const int r0 = by * 64, c0 = bx * 64;
#pragma unroll
  for (int p = 0; p < 2; ++p) {
    int li = tid + p * 256;
    int r = li >> 3, cs = (li & 7) * 8;
    const float* src = in + (size_t)(r0 + r) * inC + colOff + c0 + cs;
    float4 a = *(const float4*)src;
    float4 b = *(const float4*)(src + 4);
    ushort_t tmp[8] = {f2b(a.x), f2b(a.y), f2b(a.z), f2b(a.w),
                       f2b(b.x), f2b(b.y), f2b(b.z), f2b(b.w)};
    *(uint4*)&tile[r][cs] = *(const uint4*)tmp;
  }
  __syncthreads();
#pragma unroll
  for (int p = 0; p < 2; ++p) {
    int li = tid + p * 256;
    int cR = li >> 3, rs = (li & 7) * 8;
    ushort_t tmp[8];
#pragma unroll
    for (int e = 0; e < 8; ++e) tmp[e] = tile[rs + e][cR];
    *(uint4*)(out + (size_t)(c0 + cR) * R + r0 + rs) = *(const uint4*)tmp;
  }
}

// ---------------------------------------------------------------------------
// Fused prologue (one launch): blocks [0,4096) x->bf16 convert;
// [4096,6144) (Wq|Wk)^T transpose; [6144,7168) Wv^T transpose.
// ---------------------------------------------------------------------------
__global__ __launch_bounds__(256) void fused_pre(const float* __restrict__ x,
                                                 const float* __restrict__ w_qkv,
                                                 ushort_t* __restrict__ xbf,
                                                 ushort_t* __restrict__ wqkT,
                                                 ushort_t* __restrict__ wvT) {
  __shared__ ushort_t tile[64][72];
  const int bid = blockIdx.x;
  const int tid = threadIdx.x;
  if (bid < 4096) {
    size_t i = ((size_t)bid * 256 + tid) * 8;
    float4 a = *(const float4*)(x + i);
    float4 b = *(const float4*)(x + i + 4);
    ushort_t tmp[8] = {f2b(a.x), f2b(a.y), f2b(a.z), f2b(a.w),
                       f2b(b.x), f2b(b.y), f2b(b.z), f2b(b.w)};
    *(uint4*)(xbf + i) = *(const uint4*)tmp;
    return;
  }
  if (bid < 6144) {
    int t = bid - 4096;
    transpose_body(w_qkv, wqkT, DM_, 3 * DM_, 0, t & 63, t >> 6, tile, tid);
  } else {
    int t = bid - 6144;
    transpose_body(w_qkv, wvT, DM_, 3 * DM_, 2 * DM_, t & 31, t >> 5, tile, tid);
  }
}

#define SBAR() __builtin_amdgcn_sched_barrier(0)
#define BARR() __builtin_amdgcn_s_barrier()

// ---------------------------------------------------------------------------
// GEMM 256x256, BK=64, 8 waves (2Mx4N), 4-phase schedule, counted vmcnt,
// single closing barrier per phase (R4, verified).
// ROUND-5 CHANGE: in-tile ds_read prefetch. All fragment reads issue in
// ph1 (A0,B0,A1) and ph2 (B1); MFMA(0,0) waits lgkmcnt(8) (A0/B0 only),
// later phases have zero lgkm stall. WAR audit: each prefetched read
// completes before its consumer MFMA, which precedes >=1 closing barrier
// before the staging write to that LDS region (A1: read<=ph2, staged ph4;
// B1: read<=ph2 of kt, staged ph2 of kt+1 into same buf after 3 barriers).
// MODE 2: C bf16 split: cols [0,2048)->C0, [2048,4096)->C1, ld=2048.
// ---------------------------------------------------------------------------
#define LDS_A(qm, bb)                                                          \
  _Pragma("unroll") for (int mi = 0; mi < 4; ++mi) {                           \
    _Pragma("unroll") for (int ks = 0; ks < 2; ++ks) {                         \
      const int r_ = arow + (qm) * 64 + mi * 16;                               \
      const int cb_ = ((ks) * 64 + quad * 16) ^ swz;                           \
      afr[qm][mi][ks] =                                                        \
          *(const short8*)((const char*)As[bb] + r_ * 128 + cb_);              \
    }                                                                          \
  }

#define LDS_B(qn, bb)                                                          \
  _Pragma("unroll") for (int ni = 0; ni < 2; ++ni) {                           \
    _Pragma("unroll") for (int ks = 0; ks < 2; ++ks) {                         \
      const int r_ = brow + (qn) * 32 + ni * 16;                               \
      const int cb_ = ((ks) * 64 + quad * 16) ^ swz;                           \
      bfr[qn][ni][ks] =                                                        \
          *(const short8*)((const char*)Bs[bb] + r_ * 128 + cb_);              \
    }                                                                          \
  }

#define MMA_Q(qm, qn)                                                          \
  _Pragma("unroll") for (int mi = 0; mi < 4; ++mi) {                           \
    _Pragma("unroll") for (int ni = 0; ni < 2; ++ni) {                         \
      floatx4 t_ = acc[(qm) * 4 + mi][(qn) * 2 + ni];                          \
      t_ = __builtin_amdgcn_mfma_f32_16x16x32_bf16(afr[qm][mi][0],             \
                                                   bfr[qn][ni][0], t_, 0, 0, 0); \
      t_ = __builtin_amdgcn_mfma_f32_16x16x32_bf16(afr[qm][mi][1],             \
                                                   bfr[qn][ni][1], t_, 0, 0, 0); \
      acc[(qm) * 4 + mi][(qn) * 2 + ni] = t_;                                  \
    }                                                                          \
  }

template <int MODE>
__global__ __launch_bounds__(512, 2) void gemm_bt_256(const ushort_t* __restrict__ A,
                                                      const ushort_t* __restrict__ Bt,
                                                      void* __restrict__ C0,
                                                      void* __restrict__ C1,
                                                      int M, int N, int K) {
  __shared__ alignas(16) ushort_t As[2][256 * 64];
  __shared__ alignas(16) ushort_t Bs[2][256 * 64];
  const int tid = threadIdx.x;
  const int wave = tid >> 6, lane = tid & 63;
  const int l15 = lane & 15, quad = lane >> 4;
  const int wm = wave >> 2, wn = wave & 3;  // 2 x 4 wave grid
  const size_t m0 = (size_t)blockIdx.y * 256, n0 = (size_t)blockIdx.x * 256;
  const int nkt = K >> 6;  // K-tiles of 64

  const int srow = lane >> 3;                 // row within 8-row chunk
  const int skk = ((lane & 7) ^ srow) * 8;    // swizzled k offset (bf16)

  const int arow = wm * 128 + l15;
  const int brow = wn * 64 + l15;
  const int swz = (l15 & 7) << 4;

  floatx4 zero = {0.f, 0.f, 0.f, 0.f};
  floatx4 acc[8][4];
#pragma unroll
  for (int i = 0; i < 8; ++i)
#pragma unroll
    for (int j = 0; j < 4; ++j) acc[i][j] = zero;

  short8 afr[2][4][2];  // [qm][mi][ks]
  short8 bfr[2][2][2];  // [qn][ni][ks]

  // half-tiles: 0=A rows 0..127, 1=A rows 128..255, 2=B rows 0..127, 3=B rows 128..255
  auto stage_half = [&](int t, int ht) {
    if (t >= nkt) return;
    const int bb = t & 1;
    const int h = ht & 1;
    const int kt64 = t << 6;
    const ushort_t* G = (ht < 2) ? A : Bt;
    const size_t r0 = (ht < 2) ? m0 : n0;
    char* dst = (char*)((ht < 2) ? As[bb] : Bs[bb]) + h * 16384;
#pragma unroll
    for (int i = 0; i < 2; ++i) {
      const int c = wave * 2 + i;
      const size_t gr = r0 + h * 128 + c * 8 + srow;
      __builtin_amdgcn_global_load_lds(AS1(G + gr * K + kt64 + skk),
                                       AS3(dst + c * 1024), 16, 0, 0);
    }
  };

  // prologue: tile 0 fully + A-halves of tile 1 (12 loads/thread)
  stage_half(0, 0); stage_half(0, 1); stage_half(0, 2); stage_half(0, 3);
  stage_half(1, 0); stage_half(1, 1);
  SBAR();
  if (nkt > 1) { asm volatile("s_waitcnt vmcnt(4)" ::: "memory"); }
  else         { asm volatile("s_waitcnt vmcnt(0)" ::: "memory"); }
  SBAR(); BARR(); SBAR();

  for (int kt = 0; kt < nkt; ++kt) {
    const int bb = kt & 1;
    // ---- phase 1: reads A0,B0,A1 (A1 = prefetch); stage B0(kt+1); MFMA(0,0)
    LDS_A(0, bb); LDS_B(0, bb); LDS_A(1, bb);
    stage_half(kt + 1, 2);
    SBAR();
    __builtin_amdgcn_s_setprio(1);
    MMA_Q(0, 0);
    __builtin_amdgcn_s_setprio(0);
    SBAR(); BARR(); SBAR();
    // ---- phase 2: read B1 (prefetch); stage B1(kt+1); MFMA(1,0)
    LDS_B(1, bb);
    stage_half(kt + 1, 3);
    SBAR();
    __builtin_amdgcn_s_setprio(1);
    MMA_Q(1, 0);
    __builtin_amdgcn_s_setprio(0);
    SBAR(); BARR(); SBAR();
    // ---- phase 3: stage A0(kt+2); MFMA(1,1) (frags already in regs)
    stage_half(kt + 2, 0);
    SBAR();
    __builtin_amdgcn_s_setprio(1);
    MMA_Q(1, 1);
    __builtin_amdgcn_s_setprio(0);
    SBAR(); BARR(); SBAR();
    // ---- phase 4: stage A1(kt+2); MFMA(0,1) (frags already in regs)
    stage_half(kt + 2, 1);
    SBAR();
    __builtin_amdgcn_s_setprio(1);
    MMA_Q(0, 1);
    __builtin_amdgcn_s_setprio(0);
    SBAR();
    if (kt + 2 < nkt) { asm volatile("s_waitcnt vmcnt(4)" ::: "memory"); }
    else              { asm volatile("s_waitcnt vmcnt(0)" ::: "memory"); }
    SBAR(); BARR(); SBAR();
  }

  // epilogue
  if (MODE == 2) {
    ushort_t* Cb = (n0 >= 2048) ? (ushort_t*)C1 : (ushort_t*)C0;
    size_t nc0 = n0 & 2047;
#pragma unroll
    for (int mi8 = 0; mi8 < 8; ++mi8)
#pragma unroll
      for (int nj = 0; nj < 4; ++nj)
#pragma unroll
        for (int r = 0; r < 4; ++r) {
          size_t row = m0 + wm * 128 + (mi8 >> 2) * 64 + (mi8 & 3) * 16 + quad * 4 + r;
          size_t col = nc0 + wn * 64 + (nj >> 1) * 32 + (nj & 1) * 16 + l15;
          Cb[row * 2048 + col] = f2b(acc[mi8][nj][r]);
        }
  } else {
#pragma unroll
    for (int mi8 = 0; mi8 < 8; ++mi8)
#pragma unroll
      for (int nj = 0; nj < 4; ++nj)
#pragma unroll
        for (int r = 0; r < 4; ++r) {
          size_t row = m0 + wm * 128 + (mi8 >> 2) * 64 + (mi8 & 3) * 16 + quad * 4 + r;
          size_t col = n0 + wn * 64 + (nj >> 1) * 32 + (nj & 1) * 16 + l15;
          if (MODE == 1)
            ((float*)C0)[row * N + col] = acc[mi8][nj][r];
          else
            ((ushort_t*)C0)[row * N + col] = f2b(acc[mi8][nj][r]);
        }
  }
}

// ---------------------------------------------------------------------------
// GEMM 128x128, BK=64, 4 waves (2Mx2N), 4-phase deep-pipeline, 64 KiB LDS ->
// 2 blocks/CU. Same in-tile ds_read prefetch as gemm_bt_256 (same audit).
// MODE 0: C bf16, ld=N.  MODE 1: C f32, ld=N.
// ---------------------------------------------------------------------------
#define LDS_A8(mh, bb)                                                         \
  _Pragma("unroll") for (int mi = 0; mi < 2; ++mi) {                           \
    _Pragma("unroll") for (int ks = 0; ks < 2; ++ks) {                         \
      const int r_ = arow + ((mh) * 2 + mi) * 16;                              \
      const int cb_ = ((ks) * 64 + quad * 16) ^ swz;                           \
      afr[(mh) * 2 + mi][ks] =                                                 \
          *(const short8*)((const char*)As[bb] + r_ * 128 + cb_);              \
    }                                                                          \
  }

#define LDS_B8(nh, bb)                                                         \
  _Pragma("unroll") for (int ni = 0; ni < 2; ++ni) {                           \
    _Pragma("unroll") for (int ks = 0; ks < 2; ++ks) {                         \
      const int r_ = brow + ((nh) * 2 + ni) * 16;                              \
      const int cb_ = ((ks) * 64 + quad * 16) ^ swz;                           \
      bfr[(nh) * 2 + ni][ks] =                                                 \
          *(const short8*)((const char*)Bs[bb] + r_ * 128 + cb_);              \
    }                                                                          \
  }

#define MMA_H(mh, nh)                                                          \
  _Pragma("unroll") for (int mi = 0; mi < 2; ++mi) {                           \
    _Pragma("unroll") for (int ni = 0; ni < 2; ++ni) {                         \
      floatx4 t_ = acc[(mh) * 2 + mi][(nh) * 2 + ni];                          \
      t_ = __builtin_amdgcn_mfma_f32_16x16x32_bf16(afr[(mh) * 2 + mi][0],      \
                                                   bfr[(nh) * 2 + ni][0], t_, 0, 0, 0); \
      t_ = __builtin_amdgcn_mfma_f32_16x16x32_bf16(afr[(mh) * 2 + mi][1],      \
                                                   bfr[(nh) * 2 + ni][1], t_, 0, 0, 0); \
      acc[(mh) * 2 + mi][(nh) * 2 + ni] = t_;                                  \
    }                                                                          \
  }

template <int MODE>
__global__ __launch_bounds__(256, 2) void gemm_bt_128(const ushort_t* __restrict__ A,
                                                      const ushort_t* __restrict__ Bt,
                                                      void* __restrict__ C0,
                                                      int M, int N, int K) {
  __shared__ alignas(16) ushort_t As[2][128 * 64];
  __shared__ alignas(16) ushort_t Bs[2][128 * 64];
  const int tid = threadIdx.x;
  const int wave = tid >> 6, lane = tid & 63;
  const int l15 = lane & 15, quad = lane >> 4;
  const int wm = wave >> 1, wn = wave & 1;  // 2 x 2 wave grid
  const int lin = blockIdx.y * gridDim.x + blockIdx.x;
  const int band = lin / (4 * gridDim.x);
  const int rin = lin % (4 * gridDim.x);
  const int by = band * 4 + (rin & 3);
  const int bx = rin >> 2;
  const size_t m0 = (size_t)by * 128, n0 = (size_t)bx * 128;
  const int nkt = K >> 6;

  const int srow = lane >> 3;
  const int skk = ((lane & 7) ^ srow) * 8;

  const int arow = wm * 64 + l15;
  const int brow = wn * 64 + l15;
  const int swz = (l15 & 7) << 4;

  floatx4 zero = {0.f, 0.f, 0.f, 0.f};
  floatx4 acc[4][4];
#pragma unroll
  for (int i = 0; i < 4; ++i)
#pragma unroll
    for (int j = 0; j < 4; ++j) acc[i][j] = zero;

  short8 afr[4][2];
  short8 bfr[4][2];

  auto stage_q = [&](int t, int qt_) {
    if (t >= nkt) return;
    const int bb = t & 1;
    const int h = qt_ & 1;
    const int kt64 = t << 6;
    const ushort_t* G = (qt_ < 2) ? A : Bt;
    const size_t r0 = (qt_ < 2) ? m0 : n0;
    char* dst = (char*)((qt_ < 2) ? As[bb] : Bs[bb]) + h * 8192;
#pragma unroll
    for (int i = 0; i < 2; ++i) {
      const int c = wave * 2 + i;
      const size_t gr = r0 + h * 64 + c * 8 + srow;
      __builtin_amdgcn_global_load_lds(AS1(G + gr * K + kt64 + skk),
                                       AS3(dst + c * 1024), 16, 0, 0);
    }
  };

  stage_q(0, 0); stage_q(0, 1); stage_q(0, 2); stage_q(0, 3);
  stage_q(1, 0); stage_q(1, 1);
  SBAR();
  if (nkt > 1) { asm volatile("s_waitcnt vmcnt(4)" ::: "memory"); }
  else         { asm volatile("s_waitcnt vmcnt(0)" ::: "memory"); }
  SBAR(); BARR(); SBAR();

  for (int kt = 0; kt < nkt; ++kt) {
    const int bb = kt & 1;
    // ---- phase 1: reads A0,B0,A1 (prefetch); stage B-q0(kt+1); MFMA(0,0)
    LDS_A8(0, bb); LDS_B8(0, bb); LDS_A8(1, bb);
    stage_q(kt + 1, 2);
    SBAR();
    __builtin_amdgcn_s_setprio(1);
    MMA_H(0, 0);
    __builtin_amdgcn_s_setprio(0);
    SBAR(); BARR(); SBAR();
    // ---- phase 2: read B1 (prefetch); stage B-q1(kt+1); MFMA(1,0)
    LDS_B8(1, bb);
    stage_q(kt + 1, 3);
    SBAR();
    __builtin_amdgcn_s_setprio(1);
    MMA_H(1, 0);
    __builtin_amdgcn_s_setprio(0);
    SBAR(); BARR(); SBAR();
    // ---- phase 3: stage A-q0(kt+2); MFMA(1,1)
    stage_q(kt + 2, 0);
    SBAR();
    __builtin_amdgcn_s_setprio(1);
    MMA_H(1, 1);
    __builtin_amdgcn_s_setprio(0);
    SBAR(); BARR(); SBAR();
    // ---- phase 4: stage A-q1(kt+2); MFMA(0,1)
    stage_q(kt + 2, 1);
    SBAR();
    __builtin_amdgcn_s_setprio(1);
    MMA_H(0, 1);
    __builtin_amdgcn_s_setprio(0);
    SBAR();
    if (kt + 2 < nkt) { asm volatile("s_waitcnt vmcnt(4)" ::: "memory"); }
    else              { asm volatile("s_waitcnt vmcnt(0)" ::: "memory"); }
    SBAR(); BARR(); SBAR();
  }

#pragma unroll
  for (int i = 0; i < 4; ++i)
#pragma unroll
    for (int j = 0; j < 4; ++j)
#pragma unroll
      for (int r = 0; r < 4; ++r) {
        size_t row = m0 + wm * 64 + i * 16 + quad * 4 + r;
        size_t col = n0 + wn * 64 + j * 16 + l15;
        if (MODE == 1)
          ((float*)C0)[row * N + col] = acc[i][j][r];
        else
          ((ushort_t*)C0)[row * N + col] = f2b(acc[i][j][r]);
      }
}

// ---------------------------------------------------------------------------
// Fused mid (one launch): blocks [0,4096) norm_rope; [4096,5120) w_out^T
// transpose into the dead wvT slot (V-proj already consumed wvT).
// ---------------------------------------------------------------------------
__global__ __launch_bounds__(256) void fused_mid(ushort_t* __restrict__ Q,
                                                 ushort_t* __restrict__ Kb,
                                                 const float* __restrict__ gain,
                                                 const float* __restrict__ w_out,
                                                 ushort_t* __restrict__ woutT) {
  __shared__ ushort_t tile[64][72];
  const int bid = blockIdx.x;
  const int tid = threadIdx.x;
  if (bid >= 4096) {
    int t = bid - 4096;
    transpose_body(w_out, woutT, DM_, DM_, 0, t & 31, t >> 5, tile, tid);
    return;
  }
  const int wave = tid >> 6, lane = tid & 63;
  const int g16 = lane >> 4, sl = lane & 15;
  const int idx = (bid * 4 + wave) * 4 + g16;  // ((b*S+s)*H + h)
  const int h = idx & 15;
  const int s = (idx >> 4) & (S_ - 1);
  const size_t off = (size_t)(idx >> 4) * DM_ + h * DH_ + sl * 4;

  ushort_t qv1[4], qv2[4], kv1[4], kv2[4];
  *(uint2*)qv1 = *(const uint2*)(Q + off);
  *(uint2*)qv2 = *(const uint2*)(Q + off + 64);
  *(uint2*)kv1 = *(const uint2*)(Kb + off);
  *(uint2*)kv2 = *(const uint2*)(Kb + off + 64);

  float q1[4], q2[4], k1[4], k2[4];
  float sq = 0.f, sk = 0.f;
#pragma unroll
  for (int e = 0; e < 4; ++e) {
    q1[e] = b2f(qv1[e]); q2[e] = b2f(qv2[e]);
    k1[e] = b2f(kv1[e]); k2[e] = b2f(kv2[e]);
    sq += q1[e] * q1[e] + q2[e] * q2[e];
    sk += k1[e] * k1[e] + k2[e] * k2[e];
  }
#pragma unroll
  for (int o = 1; o < 16; o <<= 1) {
    sq += __shfl_xor(sq, o, 64);
    sk += __shfl_xor(sk, o, 64);
  }
  float rq = rsqrtf(sq + 1e-6f), rk = rsqrtf(sk + 1e-6f);
  const float g = gain[h] * 1.44269504f;  // fold log2(e): attn uses exp2
  const bool roped = (h & 1) == 0;        // ROPE_MASK tiles [1,0] over heads
#pragma unroll
  for (int e = 0; e < 4; ++e) {
    float a = q1[e] * rq, bq = q2[e] * rq;
    float c_ = k1[e] * rk, dk = k2[e] * rk;
    if (roped) {
      int j = sl * 4 + e;
      float invf = exp2f((float)j * -0.20762050593f);  // log2(10000)/64
      float th = (float)s * invf;
      float cc = cosf(th), sn = sinf(th);
      float na = a * cc - bq * sn, nb = a * sn + bq * cc;
      float nc = c_ * cc - dk * sn, nd = c_ * sn + dk * cc;
      a = na; bq = nb; c_ = nc; dk = nd;
    }
    qv1[e] = f2b(a * g); qv2[e] = f2b(bq * g);
    kv1[e] = f2b(c_);    kv2[e] = f2b(dk);
  }
  *(uint2*)(Q + off)       = *(const uint2*)qv1;
  *(uint2*)(Q + off + 64)  = *(const uint2*)qv2;
  *(uint2*)(Kb + off)      = *(const uint2*)kv1;
  *(uint2*)(Kb + off + 64) = *(const uint2*)kv2;
}

// ---------------------------------------------------------------------------
// Flash attention v3: balanced tile pairs {p, 31-p}, fixed-max softmax
// (exp2 form, log2e pre-folded into q-gain), double-buffered K/V, per-wave
// Ps, 1 barrier/iter. V layout: [dim][b*S+s]. Y written in place over Q.
// Grid (bh, p): XCD = bh%8 -> per-XCD K/V working set fits its 4MB L2.
// ---------------------------------------------------------------------------
__global__ __launch_bounds__(256, 2) void attn(ushort_t* __restrict__ QY,
                                               const ushort_t* __restrict__ Kg,
                                               const ushort_t* __restrict__ Vg) {
  __shared__ alignas(16) ushort_t Ks[2][64 * 128];
  __shared__ alignas(16) ushort_t Vs[2][128 * 64];
  __shared__ alignas(16) ushort_t Ps[2][4][16 * 64];

  const float M0 = 18.755035531f;  // 13 * log2(e)
  const int tid = threadIdx.x;
  const int wave = tid >> 6, lane = tid & 63;
  const int l15 = lane & 15, quad = lane >> 4;
  const int bh = blockIdx.x;
  const int b = bh >> 4, h = bh & 15;
  const int p = blockIdx.y;
  const int qt[2] = {p, 31 - p};

  const ushort_t* Kgb = Kg + (size_t)b * S_ * DM_ + h * DH_;
  const ushort_t* Vgb = Vg + (size_t)(h * DH_) * (B_ * S_) + b * S_;

  short8 aq[2][4];
#pragma unroll
  for (int t = 0; t < 2; ++t) {
    const ushort_t* Qg =
        QY + (size_t)(b * S_ + qt[t] * 64 + wave * 16 + l15) * DM_ + h * DH_;
#pragma unroll
    for (int ks = 0; ks < 4; ++ks)
      aq[t][ks] = *(const short8*)(Qg + ks * 32 + quad * 8);
  }

  float lsum[2][4] = {{0.f, 0.f, 0.f, 0.f}, {0.f, 0.f, 0.f, 0.f}};
  floatx4 zero = {0.f, 0.f, 0.f, 0.f};
  floatx4 oacc[2][8];
#pragma unroll
  for (int t = 0; t < 2; ++t)
#pragma unroll
    for (int d = 0; d < 8; ++d) oacc[t][d] = zero;

  const int krow_in = lane >> 4, ksd = lane & 15;
  const int vrow_in = lane >> 3, vsd = lane & 7;

  auto stage = [&](int kt, int bf) {
#pragma unroll
    for (int i = 0; i < 4; ++i) {
      int c = wave * 4 + i;
      {
        int r = c * 4 + krow_in;
        int sg = ksd ^ (r & 7);
        __builtin_amdgcn_global_load_lds(
            AS1(Kgb + (size_t)(kt * 64 + r) * DM_ + sg * 8),
            AS3((char*)Ks[bf] + c * 1024), 16, 0, 0);
      }
      {
        int r = c * 8 + vrow_in;
        int sg = vsd ^ (r & 7);
        __builtin_amdgcn_global_load_lds(
            AS1(Vgb + (size_t)r * (B_ * S_) + kt * 64 + sg * 8),
            AS3((char*)Vs[bf] + c * 1024), 16, 0, 0);
      }
    }
  };

  stage(0, 0);

  for (int kt = 0; kt <= qt[1]; ++kt) {
    const int cur = kt & 1;
    __syncthreads();
    if (kt < qt[1]) stage(kt + 1, cur ^ 1);

#pragma unroll
    for (int t = 0; t < 2; ++t) {
      if (t == 0 && kt > qt[0]) continue;
      floatx4 sacc[4];
#pragma unroll
      for (int j = 0; j < 4; ++j) sacc[j] = zero;
#pragma unroll
      for (int ks = 0; ks < 4; ++ks) {
#pragma unroll
        for (int j = 0; j < 4; ++j) {
          int row = j * 16 + l15;
          int sl = (ks * 4 + quad) ^ (row & 7);
          short8 bk = *(const short8*)&Ks[cur][row * 128 + sl * 8];
          sacc[j] = __builtin_amdgcn_mfma_f32_16x16x32_bf16(aq[t][ks], bk, sacc[j], 0, 0, 0);
        }
      }
      if (kt == qt[t]) {
#pragma unroll
        for (int j = 0; j < 4; ++j)
#pragma unroll
          for (int r = 0; r < 4; ++r) {
            int key = j * 16 + l15;
            int qr = wave * 16 + quad * 4 + r;
            if (key > qr) sacc[j][r] = -1e30f;
          }
      }
#pragma unroll
      for (int j = 0; j < 4; ++j)
#pragma unroll
        for (int r = 0; r < 4; ++r) {
          float pv = fast_exp2(sacc[j][r] - M0);
          sacc[j][r] = pv;
          lsum[t][r] += pv;
        }
#pragma unroll
      for (int j = 0; j < 4; ++j)
#pragma unroll
        for (int r = 0; r < 4; ++r) {
          int row = quad * 4 + r;
          int col = j * 16 + l15;
          int g = col >> 3, w = col & 7;
          Ps[t][wave][row * 64 + ((g ^ (row & 7)) << 3) + w] = f2b(sacc[j][r]);
        }
#pragma unroll
      for (int ks2 = 0; ks2 < 2; ++ks2) {
        short8 ap = *(const short8*)&Ps[t][wave][l15 * 64 +
                                                (((ks2 * 4 + quad) ^ (l15 & 7)) << 3)];
#pragma unroll
        for (int d = 0; d < 8; ++d) {
          int row = d * 16 + l15;
          int sl = (ks2 * 4 + quad) ^ (row & 7);
          short8 bv = *(const short8*)&Vs[cur][row * 64 + sl * 8];
          oacc[t][d] = __builtin_amdgcn_mfma_f32_16x16x32_bf16(ap, bv, oacc[t][d], 0, 0, 0);
        }
      }
    }
  }

#pragma unroll
  for (int t = 0; t < 2; ++t) {
#pragma unroll
    for (int r = 0; r < 4; ++r) {
#pragma unroll
      for (int o = 1; o < 16; o <<= 1) lsum[t][r] += __shfl_xor(lsum[t][r], o, 64);
      float inv = 1.0f / lsum[t][r];
      size_t row = (size_t)(b * S_ + qt[t] * 64 + wave * 16 + quad * 4 + r);
#pragma unroll
      for (int d = 0; d < 8; ++d) {
        size_t col = (size_t)h * DH_ + d * 16 + l15;
        QY[row * DM_ + col] = f2b(oacc[t][d][r] * inv);
      }
    }
  }
}

// ---------------------------------------------------------------------------
extern "C" void kernel_launch(void* const* d_in, const int* in_sizes, int n_in,
                              void* d_out, int out_size, void* d_ws, size_t ws_size,
                              hipStream_t stream) {
  const float* x      = (const float*)d_in[0];
  const float* w_qkv  = (const float*)d_in[1];
  const float* w_out  = (const float*)d_in[2];
  const float* q_gain = (const float*)d_in[3];
  float* out = (float*)d_out;

  // ws (56 MiB): Qraw | Kraw | Vt | wvT (wvT slot reused for w_out^T later)
  // d_out (32 MiB) doubles as scratch until the final GEMM: xbf | wqkT
  char* ws = (char*)d_ws;
  const size_t bsd = (size_t)B_ * S_ * DM_;  // 8,388,608 elems
  ushort_t* Qraw = (ushort_t*)ws;
  ushort_t* Kraw = Qraw + bsd;
  ushort_t* Vt   = Kraw + bsd;                    // [dim][b*S+s]
  ushort_t* wvT  = Vt + bsd;                      // [2048][2048]
  ushort_t* xbf  = (ushort_t*)d_out;              // [4096][2048] bf16
  ushort_t* wqkT = xbf + bsd;                     // [4096][2048] bf16 (Wq|Wk)^T
  ushort_t* woutT = wvT;                          // wvT dead after V-proj

  // 1: convert + both w_qkv transposes
  fused_pre<<<dim3(7168), 256, 0, stream>>>(x, w_qkv, xbf, wqkT, wvT);
  // 2: Q and K in one fused GEMM (split-C epilogue), 256^2 deep pipeline
  gemm_bt_256<2><<<dim3(16, 16), 512, 0, stream>>>(xbf, wqkT, Qraw, Kraw,
                                                   B_ * S_, 2 * DM_, DM_);
  // 3: V^T = WvT * x^T -> Vt[dim][b*S+s] (512 blocks = 2/CU)
  gemm_bt_128<0><<<dim3(32, 16), 256, 0, stream>>>(wvT, xbf, Vt,
                                                   DM_, B_ * S_, DM_);
  // 4: norm+rope (Q,K) + w_out^T into dead wvT slot
  fused_mid<<<dim3(5120), 256, 0, stream>>>(Qraw, Kraw, q_gain, w_out, woutT);
  // 5: attention (Y over Qraw)
  attn<<<dim3(B_ * H_, S_ / 128), 256, 0, stream>>>(Qraw, Kraw, Vt);
  // 6: out = Y @ w_out (f32 over d_out)
  gemm_bt_128<1><<<dim3(16, 32), 256, 0, stream>>>(Qraw, woutT, out,
                                                   B_ * S_, DM_, DM_);
}

// Round 7
// 342.204 us; speedup vs baseline: 1.2275x; 1.0227x over previous
//
#include <hip/hip_runtime.h>
#include <hip/hip_bf16.h>

typedef unsigned short ushort_t;
typedef __attribute__((ext_vector_type(8))) short short8;
typedef __attribute__((ext_vector_type(4))) float floatx4;

#define B_  2
#define S_  2048
#define DM_ 2048
#define H_  16
#define DH_ 128

#define AS1(p) ((const __attribute__((address_space(1))) void*)(p))
#define AS3(p) ((__attribute__((address_space(3))) void*)(p))

static __device__ __forceinline__ float b2f(ushort_t u) {
  __hip_bfloat16 h = *reinterpret_cast<__hip_bfloat16*>(&u);
  return __bfloat162float(h);
}
static __device__ __forceinline__ ushort_t f2b(float f) {
  __hip_bfloat16 h = __float2bfloat16(f);
  return *reinterpret_cast<ushort_t*>(&h);
}
static __device__ __forceinline__ float fast_exp2(float x) {
#if defined(__has_builtin)
#if __has_builtin(__builtin_amdgcn_exp2f)
  return __builtin_amdgcn_exp2f(x);
#else
  return exp2f(x);
#endif
#else
  return exp2f(x);
#endif
}

// ---------------------------------------------------------------------------
// shared transpose body: out[c][r] = bf16(in[r][colOff+c]), 64x64 tile.
// ---------------------------------------------------------------------------
static __device__ __forceinline__ void transpose_body(const float* __restrict__ in,
                                                      ushort_t* __restrict__ out,
                                                      int R, int inC, int colOff,
                                                      int bx, int by,
                                                      ushort_t (*tile)[72], int tid) {
  const int r0 = by * 64, c0 = bx * 64;
#pragma unroll
  for (int p = 0; p < 2; ++p) {
    int li = tid + p * 256;
    int r = li >> 3, cs = (li & 7) * 8;
    const float* src = in + (size_t)(r0 + r) * inC + colOff + c0 + cs;
    float4 a = *(const float4*)src;
    float4 b = *(const float4*)(src + 4);
    ushort_t tmp[8] = {f2b(a.x), f2b(a.y), f2b(a.z), f2b(a.w),
                       f2b(b.x), f2b(b.y), f2b(b.z), f2b(b.w)};
    *(uint4*)&tile[r][cs] = *(const uint4*)tmp;
  }
  __syncthreads();
#pragma unroll
  for (int p = 0; p < 2; ++p) {
    int li = tid + p * 256;
    int cR = li >> 3, rs = (li & 7) * 8;
    ushort_t tmp[8];
#pragma unroll
    for (int e = 0; e < 8; ++e) tmp[e] = tile[rs + e][cR];
    *(uint4*)(out + (size_t)(c0 + cR) * R + r0 + rs) = *(const uint4*)tmp;
  }
}

// ---------------------------------------------------------------------------
// Fused prologue (one launch): blocks [0,4096) x->bf16 convert;
// [4096,6144) (Wq|Wk)^T transpose; [6144,7168) Wv^T transpose.
// ---------------------------------------------------------------------------
__global__ __launch_bounds__(256) void fused_pre(const float* __restrict__ x,
                                                 const float* __restrict__ w_qkv,
                                                 ushort_t* __restrict__ xbf,
                                                 ushort_t* __restrict__ wqkT,
                                                 ushort_t* __restrict__ wvT) {
  __shared__ ushort_t tile[64][72];
  const int bid = blockIdx.x;
  const int tid = threadIdx.x;
  if (bid < 4096) {
    size_t i = ((size_t)bid * 256 + tid) * 8;
    float4 a = *(const float4*)(x + i);
    float4 b = *(const float4*)(x + i + 4);
    ushort_t tmp[8] = {f2b(a.x), f2b(a.y), f2b(a.z), f2b(a.w),
                       f2b(b.x), f2b(b.y), f2b(b.z), f2b(b.w)};
    *(uint4*)(xbf + i) = *(const uint4*)tmp;
    return;
  }
  if (bid < 6144) {
    int t = bid - 4096;
    transpose_body(w_qkv, wqkT, DM_, 3 * DM_, 0, t & 63, t >> 6, tile, tid);
  } else {
    int t = bid - 6144;
    transpose_body(w_qkv, wvT, DM_, 3 * DM_, 2 * DM_, t & 31, t >> 5, tile, tid);
  }
}

#define SBAR() __builtin_amdgcn_sched_barrier(0)
#define BARR() __builtin_amdgcn_s_barrier()

// ---------------------------------------------------------------------------
// GEMM 256x256, BK=64, 8 waves (2Mx4N), 4-phase schedule, counted vmcnt.
// R4 read placement (R5's bunched prefetch regressed 71.4->74.0).
// ROUND-6 CHANGE (resubmitted after infra failure): TWO barriers per K-tile
// (was 4). Hazard enumeration:
//   WAR (c) ph1-read A0 vs ph3-stage A0(kt+2)  -> mid-tile barrier (post-ph2)
//   WAR (d) ph2-read A1 vs ph4-stage A1(kt+2)  -> mid-tile barrier
//   WAR (a) kt-1.ph1-read B0 vs kt.ph1-stage B0(kt+1) -> kt-1 tile-end barrier
//   WAR (b) kt-1.ph3-read B1 vs kt.ph2-stage B1(kt+1) -> kt-1 tile-end barrier
//   RAW: As[bb] staged kt-2.ph3/4 retired by kt-1 tile-end vmcnt(4)+barrier;
//        Bs[bb] staged kt-1.ph1/2 retired by kt-1 tile-end vmcnt(4)+barrier.
// vmcnt(4) at tile end retires exactly B0,B1(kt+1), keeps A0,A1(kt+2).
// MODE 2: C bf16 split: cols [0,2048)->C0, [2048,4096)->C1, ld=2048.
// ---------------------------------------------------------------------------
#define LDS_A(qm, bb)                                                          \
  _Pragma("unroll") for (int mi = 0; mi < 4; ++mi) {                           \
    _Pragma("unroll") for (int ks = 0; ks < 2; ++ks) {                         \
      const int r_ = arow + (qm) * 64 + mi * 16;                               \
      const int cb_ = ((ks) * 64 + quad * 16) ^ swz;                           \
      afr[qm][mi][ks] =                                                        \
          *(const short8*)((const char*)As[bb] + r_ * 128 + cb_);              \
    }                                                                          \
  }

#define LDS_B(qn, bb)                                                          \
  _Pragma("unroll") for (int ni = 0; ni < 2; ++ni) {                           \
    _Pragma("unroll") for (int ks = 0; ks < 2; ++ks) {                         \
      const int r_ = brow + (qn) * 32 + ni * 16;                               \
      const int cb_ = ((ks) * 64 + quad * 16) ^ swz;                           \
      bfr[qn][ni][ks] =                                                        \
          *(const short8*)((const char*)Bs[bb] + r_ * 128 + cb_);              \
    }                                                                          \
  }

#define MMA_Q(qm, qn)                                                          \
  _Pragma("unroll") for (int mi = 0; mi < 4; ++mi) {                           \
    _Pragma("unroll") for (int ni = 0; ni < 2; ++ni) {                         \
      floatx4 t_ = acc[(qm) * 4 + mi][(qn) * 2 + ni];                          \
      t_ = __builtin_amdgcn_mfma_f32_16x16x32_bf16(afr[qm][mi][0],             \
                                                   bfr[qn][ni][0], t_, 0, 0, 0); \
      t_ = __builtin_amdgcn_mfma_f32_16x16x32_bf16(afr[qm][mi][1],             \
                                                   bfr[qn][ni][1], t_, 0, 0, 0); \
      acc[(qm) * 4 + mi][(qn) * 2 + ni] = t_;                                  \
    }                                                                          \
  }

template <int MODE>
__global__ __launch_bounds__(512, 2) void gemm_bt_256(const ushort_t* __restrict__ A,
                                                      const ushort_t* __restrict__ Bt,
                                                      void* __restrict__ C0,
                                                      void* __restrict__ C1,
                                                      int M, int N, int K) {
  __shared__ alignas(16) ushort_t As[2][256 * 64];
  __shared__ alignas(16) ushort_t Bs[2][256 * 64];
  const int tid = threadIdx.x;
  const int wave = tid >> 6, lane = tid & 63;
  const int l15 = lane & 15, quad = lane >> 4;
  const int wm = wave >> 2, wn = wave & 3;  // 2 x 4 wave grid
  const size_t m0 = (size_t)blockIdx.y * 256, n0 = (size_t)blockIdx.x * 256;
  const int nkt = K >> 6;  // K-tiles of 64

  const int srow = lane >> 3;                 // row within 8-row chunk
  const int skk = ((lane & 7) ^ srow) * 8;    // swizzled k offset (bf16)

  const int arow = wm * 128 + l15;
  const int brow = wn * 64 + l15;
  const int swz = (l15 & 7) << 4;

  floatx4 zero = {0.f, 0.f, 0.f, 0.f};
  floatx4 acc[8][4];
#pragma unroll
  for (int i = 0; i < 8; ++i)
#pragma unroll
    for (int j = 0; j < 4; ++j) acc[i][j] = zero;

  short8 afr[2][4][2];  // [qm][mi][ks]
  short8 bfr[2][2][2];  // [qn][ni][ks]

  // half-tiles: 0=A rows 0..127, 1=A rows 128..255, 2=B rows 0..127, 3=B rows 128..255
  auto stage_half = [&](int t, int ht) {
    if (t >= nkt) return;
    const int bb = t & 1;
    const int h = ht & 1;
    const int kt64 = t << 6;
    const ushort_t* G = (ht < 2) ? A : Bt;
    const size_t r0 = (ht < 2) ? m0 : n0;
    char* dst = (char*)((ht < 2) ? As[bb] : Bs[bb]) + h * 16384;
#pragma unroll
    for (int i = 0; i < 2; ++i) {
      const int c = wave * 2 + i;
      const size_t gr = r0 + h * 128 + c * 8 + srow;
      __builtin_amdgcn_global_load_lds(AS1(G + gr * K + kt64 + skk),
                                       AS3(dst + c * 1024), 16, 0, 0);
    }
  };

  // prologue: tile 0 fully + A-halves of tile 1 (12 loads/thread)
  stage_half(0, 0); stage_half(0, 1); stage_half(0, 2); stage_half(0, 3);
  stage_half(1, 0); stage_half(1, 1);
  SBAR();
  if (nkt > 1) { asm volatile("s_waitcnt vmcnt(4)" ::: "memory"); }
  else         { asm volatile("s_waitcnt vmcnt(0)" ::: "memory"); }
  SBAR(); BARR(); SBAR();

  for (int kt = 0; kt < nkt; ++kt) {
    const int bb = kt & 1;
    // ---- phase 1: read A0,B0; stage B-half0 of tile kt+1 -> other buf
    LDS_A(0, bb); LDS_B(0, bb);
    stage_half(kt + 1, 2);
    SBAR();
    __builtin_amdgcn_s_setprio(1);
    MMA_Q(0, 0);
    __builtin_amdgcn_s_setprio(0);
    SBAR();
    // ---- phase 2: read A1; stage B-half1 of tile kt+1 -> other buf
    LDS_A(1, bb);
    stage_half(kt + 1, 3);
    SBAR();
    __builtin_amdgcn_s_setprio(1);
    MMA_Q(1, 0);
    __builtin_amdgcn_s_setprio(0);
    SBAR(); BARR(); SBAR();  // mid-tile barrier (hazards c, d)
    // ---- phase 3: read B1; stage A-half0 of tile kt+2 -> this buf
    LDS_B(1, bb);
    stage_half(kt + 2, 0);
    SBAR();
    __builtin_amdgcn_s_setprio(1);
    MMA_Q(1, 1);
    __builtin_amdgcn_s_setprio(0);
    SBAR();
    // ---- phase 4: stage A-half1 of tile kt+2 -> this buf
    stage_half(kt + 2, 1);
    SBAR();
    __builtin_amdgcn_s_setprio(1);
    MMA_Q(0, 1);
    __builtin_amdgcn_s_setprio(0);
    SBAR();
    if (kt + 2 < nkt) { asm volatile("s_waitcnt vmcnt(4)" ::: "memory"); }
    else              { asm volatile("s_waitcnt vmcnt(0)" ::: "memory"); }
    SBAR(); BARR(); SBAR();  // tile-end barrier (hazards a, b + RAW visibility)
  }

  // epilogue
  if (MODE == 2) {
    ushort_t* Cb = (n0 >= 2048) ? (ushort_t*)C1 : (ushort_t*)C0;
    size_t nc0 = n0 & 2047;
#pragma unroll
    for (int mi8 = 0; mi8 < 8; ++mi8)
#pragma unroll
      for (int nj = 0; nj < 4; ++nj)
#pragma unroll
        for (int r = 0; r < 4; ++r) {
          size_t row = m0 + wm * 128 + (mi8 >> 2) * 64 + (mi8 & 3) * 16 + quad * 4 + r;
          size_t col = nc0 + wn * 64 + (nj >> 1) * 32 + (nj & 1) * 16 + l15;
          Cb[row * 2048 + col] = f2b(acc[mi8][nj][r]);
        }
  } else {
#pragma unroll
    for (int mi8 = 0; mi8 < 8; ++mi8)
#pragma unroll
      for (int nj = 0; nj < 4; ++nj)
#pragma unroll
        for (int r = 0; r < 4; ++r) {
          size_t row = m0 + wm * 128 + (mi8 >> 2) * 64 + (mi8 & 3) * 16 + quad * 4 + r;
          size_t col = n0 + wn * 64 + (nj >> 1) * 32 + (nj & 1) * 16 + l15;
          if (MODE == 1)
            ((float*)C0)[row * N + col] = acc[mi8][nj][r];
          else
            ((ushort_t*)C0)[row * N + col] = f2b(acc[mi8][nj][r]);
        }
  }
}

// ---------------------------------------------------------------------------
// GEMM 128x128, BK=64, 4 waves (2Mx2N), 64 KiB LDS -> 2 blocks/CU.
// Same R6 2-barrier-per-tile schedule as gemm_bt_256 (identical hazard set).
// MODE 0: C bf16, ld=N.  MODE 1: C f32, ld=N.
// ---------------------------------------------------------------------------
#define LDS_A8(mh, bb)                                                         \
  _Pragma("unroll") for (int mi = 0; mi < 2; ++mi) {                           \
    _Pragma("unroll") for (int ks = 0; ks < 2; ++ks) {                         \
      const int r_ = arow + ((mh) * 2 + mi) * 16;                              \
      const int cb_ = ((ks) * 64 + quad * 16) ^ swz;                           \
      afr[(mh) * 2 + mi][ks] =                                                 \
          *(const short8*)((const char*)As[bb] + r_ * 128 + cb_);              \
    }                                                                          \
  }

#define LDS_B8(nh, bb)                                                         \
  _Pragma("unroll") for (int ni = 0; ni < 2; ++ni) {                           \
    _Pragma("unroll") for (int ks = 0; ks < 2; ++ks) {                         \
      const int r_ = brow + ((nh) * 2 + ni) * 16;                              \
      const int cb_ = ((ks) * 64 + quad * 16) ^ swz;                           \
      bfr[(nh) * 2 + ni][ks] =                                                 \
          *(const short8*)((const char*)Bs[bb] + r_ * 128 + cb_);              \
    }                                                                          \
  }

#define MMA_H(mh, nh)                                                          \
  _Pragma("unroll") for (int mi = 0; mi < 2; ++mi) {                           \
    _Pragma("unroll") for (int ni = 0; ni < 2; ++ni) {                         \
      floatx4 t_ = acc[(mh) * 2 + mi][(nh) * 2 + ni];                          \
      t_ = __builtin_amdgcn_mfma_f32_16x16x32_bf16(afr[(mh) * 2 + mi][0],      \
                                                   bfr[(nh) * 2 + ni][0], t_, 0, 0, 0); \
      t_ = __builtin_amdgcn_mfma_f32_16x16x32_bf16(afr[(mh) * 2 + mi][1],      \
                                                   bfr[(nh) * 2 + ni][1], t_, 0, 0, 0); \
      acc[(mh) * 2 + mi][(nh) * 2 + ni] = t_;                                  \
    }                                                                          \
  }

template <int MODE>
__global__ __launch_bounds__(256, 2) void gemm_bt_128(const ushort_t* __restrict__ A,
                                                      const ushort_t* __restrict__ Bt,
                                                      void* __restrict__ C0,
                                                      int M, int N, int K) {
  __shared__ alignas(16) ushort_t As[2][128 * 64];
  __shared__ alignas(16) ushort_t Bs[2][128 * 64];
  const int tid = threadIdx.x;
  const int wave = tid >> 6, lane = tid & 63;
  const int l15 = lane & 15, quad = lane >> 4;
  const int wm = wave >> 1, wn = wave & 1;  // 2 x 2 wave grid
  const int lin = blockIdx.y * gridDim.x + blockIdx.x;
  const int band = lin / (4 * gridDim.x);
  const int rin = lin % (4 * gridDim.x);
  const int by = band * 4 + (rin & 3);
  const int bx = rin >> 2;
  const size_t m0 = (size_t)by * 128, n0 = (size_t)bx * 128;
  const int nkt = K >> 6;

  const int srow = lane >> 3;
  const int skk = ((lane & 7) ^ srow) * 8;

  const int arow = wm * 64 + l15;
  const int brow = wn * 64 + l15;
  const int swz = (l15 & 7) << 4;

  floatx4 zero = {0.f, 0.f, 0.f, 0.f};
  floatx4 acc[4][4];
#pragma unroll
  for (int i = 0; i < 4; ++i)
#pragma unroll
    for (int j = 0; j < 4; ++j) acc[i][j] = zero;

  short8 afr[4][2];
  short8 bfr[4][2];

  auto stage_q = [&](int t, int qt_) {
    if (t >= nkt) return;
    const int bb = t & 1;
    const int h = qt_ & 1;
    const int kt64 = t << 6;
    const ushort_t* G = (qt_ < 2) ? A : Bt;
    const size_t r0 = (qt_ < 2) ? m0 : n0;
    char* dst = (char*)((qt_ < 2) ? As[bb] : Bs[bb]) + h * 8192;
#pragma unroll
    for (int i = 0; i < 2; ++i) {
      const int c = wave * 2 + i;
      const size_t gr = r0 + h * 64 + c * 8 + srow;
      __builtin_amdgcn_global_load_lds(AS1(G + gr * K + kt64 + skk),
                                       AS3(dst + c * 1024), 16, 0, 0);
    }
  };

  stage_q(0, 0); stage_q(0, 1); stage_q(0, 2); stage_q(0, 3);
  stage_q(1, 0); stage_q(1, 1);
  SBAR();
  if (nkt > 1) { asm volatile("s_waitcnt vmcnt(4)" ::: "memory"); }
  else         { asm volatile("s_waitcnt vmcnt(0)" ::: "memory"); }
  SBAR(); BARR(); SBAR();

  for (int kt = 0; kt < nkt; ++kt) {
    const int bb = kt & 1;
    // ---- phase 1: read A0,B0; stage B-q0(kt+1)
    LDS_A8(0, bb); LDS_B8(0, bb);
    stage_q(kt + 1, 2);
    SBAR();
    __builtin_amdgcn_s_setprio(1);
    MMA_H(0, 0);
    __builtin_amdgcn_s_setprio(0);
    SBAR();
    // ---- phase 2: read A1; stage B-q1(kt+1)
    LDS_A8(1, bb);
    stage_q(kt + 1, 3);
    SBAR();
    __builtin_amdgcn_s_setprio(1);
    MMA_H(1, 0);
    __builtin_amdgcn_s_setprio(0);
    SBAR(); BARR(); SBAR();  // mid-tile barrier
    // ---- phase 3: read B1; stage A-q0(kt+2)
    LDS_B8(1, bb);
    stage_q(kt + 2, 0);
    SBAR();
    __builtin_amdgcn_s_setprio(1);
    MMA_H(1, 1);
    __builtin_amdgcn_s_setprio(0);
    SBAR();
    // ---- phase 4: stage A-q1(kt+2)
    stage_q(kt + 2, 1);
    SBAR();
    __builtin_amdgcn_s_setprio(1);
    MMA_H(0, 1);
    __builtin_amdgcn_s_setprio(0);
    SBAR();
    if (kt + 2 < nkt) { asm volatile("s_waitcnt vmcnt(4)" ::: "memory"); }
    else              { asm volatile("s_waitcnt vmcnt(0)" ::: "memory"); }
    SBAR(); BARR(); SBAR();  // tile-end barrier
  }

#pragma unroll
  for (int i = 0; i < 4; ++i)
#pragma unroll
    for (int j = 0; j < 4; ++j)
#pragma unroll
      for (int r = 0; r < 4; ++r) {
        size_t row = m0 + wm * 64 + i * 16 + quad * 4 + r;
        size_t col = n0 + wn * 64 + j * 16 + l15;
        if (MODE == 1)
          ((float*)C0)[row * N + col] = acc[i][j][r];
        else
          ((ushort_t*)C0)[row * N + col] = f2b(acc[i][j][r]);
      }
}

// ---------------------------------------------------------------------------
// Fused mid (one launch): blocks [0,4096) norm_rope; [4096,5120) w_out^T
// transpose into the dead wvT slot (V-proj already consumed wvT).
// ---------------------------------------------------------------------------
__global__ __launch_bounds__(256) void fused_mid(ushort_t* __restrict__ Q,
                                                 ushort_t* __restrict__ Kb,
                                                 const float* __restrict__ gain,
                                                 const float* __restrict__ w_out,
                                                 ushort_t* __restrict__ woutT) {
  __shared__ ushort_t tile[64][72];
  const int bid = blockIdx.x;
  const int tid = threadIdx.x;
  if (bid >= 4096) {
    int t = bid - 4096;
    transpose_body(w_out, woutT, DM_, DM_, 0, t & 31, t >> 5, tile, tid);
    return;
  }
  const int wave = tid >> 6, lane = tid & 63;
  const int g16 = lane >> 4, sl = lane & 15;
  const int idx = (bid * 4 + wave) * 4 + g16;  // ((b*S+s)*H + h)
  const int h = idx & 15;
  const int s = (idx >> 4) & (S_ - 1);
  const size_t off = (size_t)(idx >> 4) * DM_ + h * DH_ + sl * 4;

  ushort_t qv1[4], qv2[4], kv1[4], kv2[4];
  *(uint2*)qv1 = *(const uint2*)(Q + off);
  *(uint2*)qv2 = *(const uint2*)(Q + off + 64);
  *(uint2*)kv1 = *(const uint2*)(Kb + off);
  *(uint2*)kv2 = *(const uint2*)(Kb + off + 64);

  float q1[4], q2[4], k1[4], k2[4];
  float sq = 0.f, sk = 0.f;
#pragma unroll
  for (int e = 0; e < 4; ++e) {
    q1[e] = b2f(qv1[e]); q2[e] = b2f(qv2[e]);
    k1[e] = b2f(kv1[e]); k2[e] = b2f(kv2[e]);
    sq += q1[e] * q1[e] + q2[e] * q2[e];
    sk += k1[e] * k1[e] + k2[e] * k2[e];
  }
#pragma unroll
  for (int o = 1; o < 16; o <<= 1) {
    sq += __shfl_xor(sq, o, 64);
    sk += __shfl_xor(sk, o, 64);
  }
  float rq = rsqrtf(sq + 1e-6f), rk = rsqrtf(sk + 1e-6f);
  const float g = gain[h] * 1.44269504f;  // fold log2(e): attn uses exp2
  const bool roped = (h & 1) == 0;        // ROPE_MASK tiles [1,0] over heads
#pragma unroll
  for (int e = 0; e < 4; ++e) {
    float a = q1[e] * rq, bq = q2[e] * rq;
    float c_ = k1[e] * rk, dk = k2[e] * rk;
    if (roped) {
      int j = sl * 4 + e;
      float invf = exp2f((float)j * -0.20762050593f);  // log2(10000)/64
      float th = (float)s * invf;
      float cc = cosf(th), sn = sinf(th);
      float na = a * cc - bq * sn, nb = a * sn + bq * cc;
      float nc = c_ * cc - dk * sn, nd = c_ * sn + dk * cc;
      a = na; bq = nb; c_ = nc; dk = nd;
    }
    qv1[e] = f2b(a * g); qv2[e] = f2b(bq * g);
    kv1[e] = f2b(c_);    kv2[e] = f2b(dk);
  }
  *(uint2*)(Q + off)       = *(const uint2*)qv1;
  *(uint2*)(Q + off + 64)  = *(const uint2*)qv2;
  *(uint2*)(Kb + off)      = *(const uint2*)kv1;
  *(uint2*)(Kb + off + 64) = *(const uint2*)kv2;
}

// ---------------------------------------------------------------------------
// Flash attention v3: balanced tile pairs {p, 31-p}, fixed-max softmax
// (exp2 form, log2e pre-folded into q-gain), double-buffered K/V, per-wave
// Ps, 1 barrier/iter. V layout: [dim][b*S+s]. Y written in place over Q.
// Grid (bh, p): XCD = bh%8 -> per-XCD K/V working set fits its 4MB L2.
// ---------------------------------------------------------------------------
__global__ __launch_bounds__(256, 2) void attn(ushort_t* __restrict__ QY,
                                               const ushort_t* __restrict__ Kg,
                                               const ushort_t* __restrict__ Vg) {
  __shared__ alignas(16) ushort_t Ks[2][64 * 128];
  __shared__ alignas(16) ushort_t Vs[2][128 * 64];
  __shared__ alignas(16) ushort_t Ps[2][4][16 * 64];

  const float M0 = 18.755035531f;  // 13 * log2(e)
  const int tid = threadIdx.x;
  const int wave = tid >> 6, lane = tid & 63;
  const int l15 = lane & 15, quad = lane >> 4;
  const int bh = blockIdx.x;
  const int b = bh >> 4, h = bh & 15;
  const int p = blockIdx.y;
  const int qt[2] = {p, 31 - p};

  const ushort_t* Kgb = Kg + (size_t)b * S_ * DM_ + h * DH_;
  const ushort_t* Vgb = Vg + (size_t)(h * DH_) * (B_ * S_) + b * S_;

  short8 aq[2][4];
#pragma unroll
  for (int t = 0; t < 2; ++t) {
    const ushort_t* Qg =
        QY + (size_t)(b * S_ + qt[t] * 64 + wave * 16 + l15) * DM_ + h * DH_;
#pragma unroll
    for (int ks = 0; ks < 4; ++ks)
      aq[t][ks] = *(const short8*)(Qg + ks * 32 + quad * 8);
  }

  float lsum[2][4] = {{0.f, 0.f, 0.f, 0.f}, {0.f, 0.f, 0.f, 0.f}};
  floatx4 zero = {0.f, 0.f, 0.f, 0.f};
  floatx4 oacc[2][8];
#pragma unroll
  for (int t = 0; t < 2; ++t)
#pragma unroll
    for (int d = 0; d < 8; ++d) oacc[t][d] = zero;

  const int krow_in = lane >> 4, ksd = lane & 15;
  const int vrow_in = lane >> 3, vsd = lane & 7;

  auto stage = [&](int kt, int bf) {
#pragma unroll
    for (int i = 0; i < 4; ++i) {
      int c = wave * 4 + i;
      {
        int r = c * 4 + krow_in;
        int sg = ksd ^ (r & 7);
        __builtin_amdgcn_global_load_lds(
            AS1(Kgb + (size_t)(kt * 64 + r) * DM_ + sg * 8),
            AS3((char*)Ks[bf] + c * 1024), 16, 0, 0);
      }
      {
        int r = c * 8 + vrow_in;
        int sg = vsd ^ (r & 7);
        __builtin_amdgcn_global_load_lds(
            AS1(Vgb + (size_t)r * (B_ * S_) + kt * 64 + sg * 8),
            AS3((char*)Vs[bf] + c * 1024), 16, 0, 0);
      }
    }
  };

  stage(0, 0);

  for (int kt = 0; kt <= qt[1]; ++kt) {
    const int cur = kt & 1;
    __syncthreads();
    if (kt < qt[1]) stage(kt + 1, cur ^ 1);

#pragma unroll
    for (int t = 0; t < 2; ++t) {
      if (t == 0 && kt > qt[0]) continue;
      floatx4 sacc[4];
#pragma unroll
      for (int j = 0; j < 4; ++j) sacc[j] = zero;
#pragma unroll
      for (int ks = 0; ks < 4; ++ks) {
#pragma unroll
        for (int j = 0; j < 4; ++j) {
          int row = j * 16 + l15;
          int sl = (ks * 4 + quad) ^ (row & 7);
          short8 bk = *(const short8*)&Ks[cur][row * 128 + sl * 8];
          sacc[j] = __builtin_amdgcn_mfma_f32_16x16x32_bf16(aq[t][ks], bk, sacc[j], 0, 0, 0);
        }
      }
      if (kt == qt[t]) {
#pragma unroll
        for (int j = 0; j < 4; ++j)
#pragma unroll
          for (int r = 0; r < 4; ++r) {
            int key = j * 16 + l15;
            int qr = wave * 16 + quad * 4 + r;
            if (key > qr) sacc[j][r] = -1e30f;
          }
      }
#pragma unroll
      for (int j = 0; j < 4; ++j)
#pragma unroll
        for (int r = 0; r < 4; ++r) {
          float pv = fast_exp2(sacc[j][r] - M0);
          sacc[j][r] = pv;
          lsum[t][r] += pv;
        }
#pragma unroll
      for (int j = 0; j < 4; ++j)
#pragma unroll
        for (int r = 0; r < 4; ++r) {
          int row = quad * 4 + r;
          int col = j * 16 + l15;
          int g = col >> 3, w = col & 7;
          Ps[t][wave][row * 64 + ((g ^ (row & 7)) << 3) + w] = f2b(sacc[j][r]);
        }
#pragma unroll
      for (int ks2 = 0; ks2 < 2; ++ks2) {
        short8 ap = *(const short8*)&Ps[t][wave][l15 * 64 +
                                                (((ks2 * 4 + quad) ^ (l15 & 7)) << 3)];
#pragma unroll
        for (int d = 0; d < 8; ++d) {
          int row = d * 16 + l15;
          int sl = (ks2 * 4 + quad) ^ (row & 7);
          short8 bv = *(const short8*)&Vs[cur][row * 64 + sl * 8];
          oacc[t][d] = __builtin_amdgcn_mfma_f32_16x16x32_bf16(ap, bv, oacc[t][d], 0, 0, 0);
        }
      }
    }
  }

#pragma unroll
  for (int t = 0; t < 2; ++t) {
#pragma unroll
    for (int r = 0; r < 4; ++r) {
#pragma unroll
      for (int o = 1; o < 16; o <<= 1) lsum[t][r] += __shfl_xor(lsum[t][r], o, 64);
      float inv = 1.0f / lsum[t][r];
      size_t row = (size_t)(b * S_ + qt[t] * 64 + wave * 16 + quad * 4 + r);
#pragma unroll
      for (int d = 0; d < 8; ++d) {
        size_t col = (size_t)h * DH_ + d * 16 + l15;
        QY[row * DM_ + col] = f2b(oacc[t][d][r] * inv);
      }
    }
  }
}

// ---------------------------------------------------------------------------
extern "C" void kernel_launch(void* const* d_in, const int* in_sizes, int n_in,
                              void* d_out, int out_size, void* d_ws, size_t ws_size,
                              hipStream_t stream) {
  const float* x      = (const float*)d_in[0];
  const float* w_qkv  = (const float*)d_in[1];
  const float* w_out  = (const float*)d_in[2];
  const float* q_gain = (const float*)d_in[3];
  float* out = (float*)d_out;

  // ws (56 MiB): Qraw | Kraw | Vt | wvT (wvT slot reused for w_out^T later)
  // d_out (32 MiB) doubles as scratch until the final GEMM: xbf | wqkT
  char* ws = (char*)d_ws;
  const size_t bsd = (size_t)B_ * S_ * DM_;  // 8,388,608 elems
  ushort_t* Qraw = (ushort_t*)ws;
  ushort_t* Kraw = Qraw + bsd;
  ushort_t* Vt   = Kraw + bsd;                    // [dim][b*S+s]
  ushort_t* wvT  = Vt + bsd;                      // [2048][2048]
  ushort_t* xbf  = (ushort_t*)d_out;              // [4096][2048] bf16
  ushort_t* wqkT = xbf + bsd;                     // [4096][2048] bf16 (Wq|Wk)^T
  ushort_t* woutT = wvT;                          // wvT dead after V-proj

  // 1: convert + both w_qkv transposes
  fused_pre<<<dim3(7168), 256, 0, stream>>>(x, w_qkv, xbf, wqkT, wvT);
  // 2: Q and K in one fused GEMM (split-C epilogue), 256^2 deep pipeline
  gemm_bt_256<2><<<dim3(16, 16), 512, 0, stream>>>(xbf, wqkT, Qraw, Kraw,
                                                   B_ * S_, 2 * DM_, DM_);
  // 3: V^T = WvT * x^T -> Vt[dim][b*S+s] (512 blocks = 2/CU)
  gemm_bt_128<0><<<dim3(32, 16), 256, 0, stream>>>(wvT, xbf, Vt,
                                                   DM_, B_ * S_, DM_);
  // 4: norm+rope (Q,K) + w_out^T into dead wvT slot
  fused_mid<<<dim3(5120), 256, 0, stream>>>(Qraw, Kraw, q_gain, w_out, woutT);
  // 5: attention (Y over Qraw)
  attn<<<dim3(B_ * H_, S_ / 128), 256, 0, stream>>>(Qraw, Kraw, Vt);
  // 6: out = Y @ w_out (f32 over d_out)
  gemm_bt_128<1><<<dim3(16, 32), 256, 0, stream>>>(Qraw, woutT, out,
                                                   B_ * S_, DM_, DM_);
}

// Round 8
// 338.798 us; speedup vs baseline: 1.2399x; 1.0101x over previous
//
#include <hip/hip_runtime.h>
#include <hip/hip_bf16.h>

typedef unsigned short ushort_t;
typedef __attribute__((ext_vector_type(8))) short short8;
typedef __attribute__((ext_vector_type(4))) float floatx4;

#define B_  2
#define S_  2048
#define DM_ 2048
#define H_  16
#define DH_ 128

#define AS1(p) ((const __attribute__((address_space(1))) void*)(p))
#define AS3(p) ((__attribute__((address_space(3))) void*)(p))

static __device__ __forceinline__ float b2f(ushort_t u) {
  __hip_bfloat16 h = *reinterpret_cast<__hip_bfloat16*>(&u);
  return __bfloat162float(h);
}
static __device__ __forceinline__ ushort_t f2b(float f) {
  __hip_bfloat16 h = __float2bfloat16(f);
  return *reinterpret_cast<ushort_t*>(&h);
}
static __device__ __forceinline__ float fast_exp2(float x) {
#if defined(__has_builtin)
#if __has_builtin(__builtin_amdgcn_exp2f)
  return __builtin_amdgcn_exp2f(x);
#else
  return exp2f(x);
#endif
#else
  return exp2f(x);
#endif
}

// ---------------------------------------------------------------------------
// shared transpose body: out[c][r] = bf16(in[r][colOff+c]), 64x64 tile.
// ---------------------------------------------------------------------------
static __device__ __forceinline__ void transpose_body(const float* __restrict__ in,
                                                      ushort_t* __restrict__ out,
                                                      int R, int inC, int colOff,
                                                      int bx, int by,
                                                      ushort_t (*tile)[72], int tid) {
  const int r0 = by * 64, c0 = bx * 64;
#pragma unroll
  for (int p = 0; p < 2; ++p) {
    int li = tid + p * 256;
    int r = li >> 3, cs = (li & 7) * 8;
    const float* src = in + (size_t)(r0 + r) * inC + colOff + c0 + cs;
    float4 a = *(const float4*)src;
    float4 b = *(const float4*)(src + 4);
    ushort_t tmp[8] = {f2b(a.x), f2b(a.y), f2b(a.z), f2b(a.w),
                       f2b(b.x), f2b(b.y), f2b(b.z), f2b(b.w)};
    *(uint4*)&tile[r][cs] = *(const uint4*)tmp;
  }
  __syncthreads();
#pragma unroll
  for (int p = 0; p < 2; ++p) {
    int li = tid + p * 256;
    int cR = li >> 3, rs = (li & 7) * 8;
    ushort_t tmp[8];
#pragma unroll
    for (int e = 0; e < 8; ++e) tmp[e] = tile[rs + e][cR];
    *(uint4*)(out + (size_t)(c0 + cR) * R + r0 + rs) = *(const uint4*)tmp;
  }
}

// ---------------------------------------------------------------------------
// Fused prologue (one launch): blocks [0,4096) x->bf16 convert;
// [4096,6144) (Wq|Wk)^T transpose; [6144,7168) Wv^T transpose.
// ---------------------------------------------------------------------------
__global__ __launch_bounds__(256) void fused_pre(const float* __restrict__ x,
                                                 const float* __restrict__ w_qkv,
                                                 ushort_t* __restrict__ xbf,
                                                 ushort_t* __restrict__ wqkT,
                                                 ushort_t* __restrict__ wvT) {
  __shared__ ushort_t tile[64][72];
  const int bid = blockIdx.x;
  const int tid = threadIdx.x;
  if (bid < 4096) {
    size_t i = ((size_t)bid * 256 + tid) * 8;
    float4 a = *(const float4*)(x + i);
    float4 b = *(const float4*)(x + i + 4);
    ushort_t tmp[8] = {f2b(a.x), f2b(a.y), f2b(a.z), f2b(a.w),
                       f2b(b.x), f2b(b.y), f2b(b.z), f2b(b.w)};
    *(uint4*)(xbf + i) = *(const uint4*)tmp;
    return;
  }
  if (bid < 6144) {
    int t = bid - 4096;
    transpose_body(w_qkv, wqkT, DM_, 3 * DM_, 0, t & 63, t >> 6, tile, tid);
  } else {
    int t = bid - 6144;
    transpose_body(w_qkv, wvT, DM_, 3 * DM_, 2 * DM_, t & 31, t >> 5, tile, tid);
  }
}

#define SBAR() __builtin_amdgcn_sched_barrier(0)
#define BARR() __builtin_amdgcn_s_barrier()

// ---------------------------------------------------------------------------
// GEMM 256x256, BK=64, 8 waves (2Mx4N), 4-phase schedule, counted vmcnt.
// ROUND-8 CHANGE: ONE barrier per K-tile (tile-end only). Key insight:
// A-half h is READ exclusively by waves with wm==h (LDS_A rows are
// [wm*128, wm*128+128)). Staging ownership aligned to readership:
// wm=0 waves stage A-half0 (4 chunks each), wm=1 waves stage A-half1.
// The old mid-tile barrier's WAR (A-read vs A-stage-same-buf) becomes
// SAME-WAVE program order -> droppable. All B hazards are cross-tile,
// covered by the tile-end barrier. vmcnt per wave unchanged: per tile
// issue B x4 then A-own x4; at tile end outstanding = A-own(kt+1) x4 +
// B(kt+1) x4 + A-own(kt+2) x4 = 12; vmcnt(4) retires the 8 needed next
// tile, barrier publishes them.
// MODE 2: C bf16 split: cols [0,2048)->C0, [2048,4096)->C1, ld=2048.
// ---------------------------------------------------------------------------
#define LDS_A(qm, bb)                                                          \
  _Pragma("unroll") for (int mi = 0; mi < 4; ++mi) {                           \
    _Pragma("unroll") for (int ks = 0; ks < 2; ++ks) {                         \
      const int r_ = arow + (qm) * 64 + mi * 16;                               \
      const int cb_ = ((ks) * 64 + quad * 16) ^ swz;                           \
      afr[qm][mi][ks] =                                                        \
          *(const short8*)((const char*)As[bb] + r_ * 128 + cb_);              \
    }                                                                          \
  }

#define LDS_B(qn, bb)                                                          \
  _Pragma("unroll") for (int ni = 0; ni < 2; ++ni) {                           \
    _Pragma("unroll") for (int ks = 0; ks < 2; ++ks) {                         \
      const int r_ = brow + (qn) * 32 + ni * 16;                               \
      const int cb_ = ((ks) * 64 + quad * 16) ^ swz;                           \
      bfr[qn][ni][ks] =                                                        \
          *(const short8*)((const char*)Bs[bb] + r_ * 128 + cb_);              \
    }                                                                          \
  }

#define MMA_Q(qm, qn)                                                          \
  _Pragma("unroll") for (int mi = 0; mi < 4; ++mi) {                           \
    _Pragma("unroll") for (int ni = 0; ni < 2; ++ni) {                         \
      floatx4 t_ = acc[(qm) * 4 + mi][(qn) * 2 + ni];                          \
      t_ = __builtin_amdgcn_mfma_f32_16x16x32_bf16(afr[qm][mi][0],             \
                                                   bfr[qn][ni][0], t_, 0, 0, 0); \
      t_ = __builtin_amdgcn_mfma_f32_16x16x32_bf16(afr[qm][mi][1],             \
                                                   bfr[qn][ni][1], t_, 0, 0, 0); \
      acc[(qm) * 4 + mi][(qn) * 2 + ni] = t_;                                  \
    }                                                                          \
  }

template <int MODE>
__global__ __launch_bounds__(512, 2) void gemm_bt_256(const ushort_t* __restrict__ A,
                                                      const ushort_t* __restrict__ Bt,
                                                      void* __restrict__ C0,
                                                      void* __restrict__ C1,
                                                      int M, int N, int K) {
  __shared__ alignas(16) ushort_t As[2][256 * 64];
  __shared__ alignas(16) ushort_t Bs[2][256 * 64];
  const int tid = threadIdx.x;
  const int wave = tid >> 6, lane = tid & 63;
  const int l15 = lane & 15, quad = lane >> 4;
  const int wm = wave >> 2, wn = wave & 3;  // 2 x 4 wave grid
  const size_t m0 = (size_t)blockIdx.y * 256, n0 = (size_t)blockIdx.x * 256;
  const int nkt = K >> 6;  // K-tiles of 64

  const int srow = lane >> 3;                 // row within 8-row chunk
  const int skk = ((lane & 7) ^ srow) * 8;    // swizzled k offset (bf16)

  const int arow = wm * 128 + l15;
  const int brow = wn * 64 + l15;
  const int swz = (l15 & 7) << 4;

  floatx4 zero = {0.f, 0.f, 0.f, 0.f};
  floatx4 acc[8][4];
#pragma unroll
  for (int i = 0; i < 8; ++i)
#pragma unroll
    for (int j = 0; j < 4; ++j) acc[i][j] = zero;

  short8 afr[2][4][2];  // [qm][mi][ks]
  short8 bfr[2][2][2];  // [qn][ni][ks]

  // B-half h: staged by ALL 8 waves, 2 chunks each (16 chunks = 128 rows).
  auto stage_B = [&](int t, int h) {
    if (t >= nkt) return;
    const int bb = t & 1;
    const int kt64 = t << 6;
    char* dst = (char*)Bs[bb] + h * 16384;
#pragma unroll
    for (int i = 0; i < 2; ++i) {
      const int c = wave * 2 + i;
      const size_t gr = n0 + h * 128 + c * 8 + srow;
      __builtin_amdgcn_global_load_lds(AS1(Bt + gr * K + kt64 + skk),
                                       AS3(dst + c * 1024), 16, 0, 0);
    }
  };
  // A-half h: staged ONLY by its reader group (wm==h), 4 chunks/wave
  // (4 waves x 4 chunks = 16 chunks = 128 rows).
  auto stage_A = [&](int t, int h) {
    if (t >= nkt || wm != h) return;
    const int bb = t & 1;
    const int kt64 = t << 6;
    char* dst = (char*)As[bb] + h * 16384;
#pragma unroll
    for (int i = 0; i < 4; ++i) {
      const int c = (wave & 3) * 4 + i;
      const size_t gr = m0 + h * 128 + c * 8 + srow;
      __builtin_amdgcn_global_load_lds(AS1(A + gr * K + kt64 + skk),
                                       AS3(dst + c * 1024), 16, 0, 0);
    }
  };

  // prologue: 12 loads/thread: B(0) x4, A(0)-own x4, A(1)-own x4.
  stage_B(0, 0); stage_B(0, 1);
  stage_A(0, 0); stage_A(0, 1);
  stage_A(1, 0); stage_A(1, 1);
  SBAR();
  if (nkt > 1) { asm volatile("s_waitcnt vmcnt(4)" ::: "memory"); }
  else         { asm volatile("s_waitcnt vmcnt(0)" ::: "memory"); }
  SBAR(); BARR(); SBAR();

  for (int kt = 0; kt < nkt; ++kt) {
    const int bb = kt & 1;
    // ---- phase 1: read A0,B0; stage B-half0(kt+1) -> other buf
    LDS_A(0, bb); LDS_B(0, bb);
    stage_B(kt + 1, 0);
    SBAR();
    __builtin_amdgcn_s_setprio(1);
    MMA_Q(0, 0);
    __builtin_amdgcn_s_setprio(0);
    SBAR();
    // ---- phase 2: read A1; stage B-half1(kt+1) -> other buf
    LDS_A(1, bb);
    stage_B(kt + 1, 1);
    SBAR();
    __builtin_amdgcn_s_setprio(1);
    MMA_Q(1, 0);
    __builtin_amdgcn_s_setprio(0);
    SBAR();
    // ---- phase 3: read B1; wm=0 waves stage A-half0(kt+2) (own half:
    //      their A0 reads completed in ph1 by program order)
    LDS_B(1, bb);
    stage_A(kt + 2, 0);
    SBAR();
    __builtin_amdgcn_s_setprio(1);
    MMA_Q(1, 1);
    __builtin_amdgcn_s_setprio(0);
    SBAR();
    // ---- phase 4: wm=1 waves stage A-half1(kt+2) (own half)
    stage_A(kt + 2, 1);
    SBAR();
    __builtin_amdgcn_s_setprio(1);
    MMA_Q(0, 1);
    __builtin_amdgcn_s_setprio(0);
    SBAR();
    if (kt + 2 < nkt) { asm volatile("s_waitcnt vmcnt(4)" ::: "memory"); }
    else              { asm volatile("s_waitcnt vmcnt(0)" ::: "memory"); }
    SBAR(); BARR(); SBAR();  // the ONE barrier per K-tile
  }

  // epilogue
  if (MODE == 2) {
    ushort_t* Cb = (n0 >= 2048) ? (ushort_t*)C1 : (ushort_t*)C0;
    size_t nc0 = n0 & 2047;
#pragma unroll
    for (int mi8 = 0; mi8 < 8; ++mi8)
#pragma unroll
      for (int nj = 0; nj < 4; ++nj)
#pragma unroll
        for (int r = 0; r < 4; ++r) {
          size_t row = m0 + wm * 128 + (mi8 >> 2) * 64 + (mi8 & 3) * 16 + quad * 4 + r;
          size_t col = nc0 + wn * 64 + (nj >> 1) * 32 + (nj & 1) * 16 + l15;
          Cb[row * 2048 + col] = f2b(acc[mi8][nj][r]);
        }
  } else {
#pragma unroll
    for (int mi8 = 0; mi8 < 8; ++mi8)
#pragma unroll
      for (int nj = 0; nj < 4; ++nj)
#pragma unroll
        for (int r = 0; r < 4; ++r) {
          size_t row = m0 + wm * 128 + (mi8 >> 2) * 64 + (mi8 & 3) * 16 + quad * 4 + r;
          size_t col = n0 + wn * 64 + (nj >> 1) * 32 + (nj & 1) * 16 + l15;
          if (MODE == 1)
            ((float*)C0)[row * N + col] = acc[mi8][nj][r];
          else
            ((ushort_t*)C0)[row * N + col] = f2b(acc[mi8][nj][r]);
        }
  }
}

// ---------------------------------------------------------------------------
// GEMM 128x128, BK=64, 4 waves (2Mx2N), 64 KiB LDS -> 2 blocks/CU.
// Same R8 1-barrier-per-tile + reader-owned A staging (wm groups of 2
// waves, 4 chunks each; A-quarter h read only by wm==h waves).
// MODE 0: C bf16, ld=N.  MODE 1: C f32, ld=N.
// ---------------------------------------------------------------------------
#define LDS_A8(mh, bb)                                                         \
  _Pragma("unroll") for (int mi = 0; mi < 2; ++mi) {                           \
    _Pragma("unroll") for (int ks = 0; ks < 2; ++ks) {                         \
      const int r_ = arow + ((mh) * 2 + mi) * 16;                              \
      const int cb_ = ((ks) * 64 + quad * 16) ^ swz;                           \
      afr[(mh) * 2 + mi][ks] =                                                 \
          *(const short8*)((const char*)As[bb] + r_ * 128 + cb_);              \
    }                                                                          \
  }

#define LDS_B8(nh, bb)                                                         \
  _Pragma("unroll") for (int ni = 0; ni < 2; ++ni) {                           \
    _Pragma("unroll") for (int ks = 0; ks < 2; ++ks) {                         \
      const int r_ = brow + ((nh) * 2 + ni) * 16;                              \
      const int cb_ = ((ks) * 64 + quad * 16) ^ swz;                           \
      bfr[(nh) * 2 + ni][ks] =                                                 \
          *(const short8*)((const char*)Bs[bb] + r_ * 128 + cb_);              \
    }                                                                          \
  }

#define MMA_H(mh, nh)                                                          \
  _Pragma("unroll") for (int mi = 0; mi < 2; ++mi) {                           \
    _Pragma("unroll") for (int ni = 0; ni < 2; ++ni) {                         \
      floatx4 t_ = acc[(mh) * 2 + mi][(nh) * 2 + ni];                          \
      t_ = __builtin_amdgcn_mfma_f32_16x16x32_bf16(afr[(mh) * 2 + mi][0],      \
                                                   bfr[(nh) * 2 + ni][0], t_, 0, 0, 0); \
      t_ = __builtin_amdgcn_mfma_f32_16x16x32_bf16(afr[(mh) * 2 + mi][1],      \
                                                   bfr[(nh) * 2 + ni][1], t_, 0, 0, 0); \
      acc[(mh) * 2 + mi][(nh) * 2 + ni] = t_;                                  \
    }                                                                          \
  }

template <int MODE>
__global__ __launch_bounds__(256, 2) void gemm_bt_128(const ushort_t* __restrict__ A,
                                                      const ushort_t* __restrict__ Bt,
                                                      void* __restrict__ C0,
                                                      int M, int N, int K) {
  __shared__ alignas(16) ushort_t As[2][128 * 64];
  __shared__ alignas(16) ushort_t Bs[2][128 * 64];
  const int tid = threadIdx.x;
  const int wave = tid >> 6, lane = tid & 63;
  const int l15 = lane & 15, quad = lane >> 4;
  const int wm = wave >> 1, wn = wave & 1;  // 2 x 2 wave grid
  const int lin = blockIdx.y * gridDim.x + blockIdx.x;
  const int band = lin / (4 * gridDim.x);
  const int rin = lin % (4 * gridDim.x);
  const int by = band * 4 + (rin & 3);
  const int bx = rin >> 2;
  const size_t m0 = (size_t)by * 128, n0 = (size_t)bx * 128;
  const int nkt = K >> 6;

  const int srow = lane >> 3;
  const int skk = ((lane & 7) ^ srow) * 8;

  const int arow = wm * 64 + l15;
  const int brow = wn * 64 + l15;
  const int swz = (l15 & 7) << 4;

  floatx4 zero = {0.f, 0.f, 0.f, 0.f};
  floatx4 acc[4][4];
#pragma unroll
  for (int i = 0; i < 4; ++i)
#pragma unroll
    for (int j = 0; j < 4; ++j) acc[i][j] = zero;

  short8 afr[4][2];
  short8 bfr[4][2];

  // B-quarter h: all 4 waves, 2 chunks each (8 chunks = 64 rows).
  auto stage_B = [&](int t, int h) {
    if (t >= nkt) return;
    const int bb = t & 1;
    const int kt64 = t << 6;
    char* dst = (char*)Bs[bb] + h * 8192;
#pragma unroll
    for (int i = 0; i < 2; ++i) {
      const int c = wave * 2 + i;
      const size_t gr = n0 + h * 64 + c * 8 + srow;
      __builtin_amdgcn_global_load_lds(AS1(Bt + gr * K + kt64 + skk),
                                       AS3(dst + c * 1024), 16, 0, 0);
    }
  };
  // A-quarter h: staged only by reader group (wm==h), 4 chunks/wave
  // (2 waves x 4 chunks = 8 chunks = 64 rows).
  auto stage_A = [&](int t, int h) {
    if (t >= nkt || wm != h) return;
    const int bb = t & 1;
    const int kt64 = t << 6;
    char* dst = (char*)As[bb] + h * 8192;
#pragma unroll
    for (int i = 0; i < 4; ++i) {
      const int c = (wave & 1) * 4 + i;
      const size_t gr = m0 + h * 64 + c * 8 + srow;
      __builtin_amdgcn_global_load_lds(AS1(A + gr * K + kt64 + skk),
                                       AS3(dst + c * 1024), 16, 0, 0);
    }
  };

  stage_B(0, 0); stage_B(0, 1);
  stage_A(0, 0); stage_A(0, 1);
  stage_A(1, 0); stage_A(1, 1);
  SBAR();
  if (nkt > 1) { asm volatile("s_waitcnt vmcnt(4)" ::: "memory"); }
  else         { asm volatile("s_waitcnt vmcnt(0)" ::: "memory"); }
  SBAR(); BARR(); SBAR();

  for (int kt = 0; kt < nkt; ++kt) {
    const int bb = kt & 1;
    // ---- phase 1: read A0,B0; stage B-q0(kt+1)
    LDS_A8(0, bb); LDS_B8(0, bb);
    stage_B(kt + 1, 0);
    SBAR();
    __builtin_amdgcn_s_setprio(1);
    MMA_H(0, 0);
    __builtin_amdgcn_s_setprio(0);
    SBAR();
    // ---- phase 2: read A1; stage B-q1(kt+1)
    LDS_A8(1, bb);
    stage_B(kt + 1, 1);
    SBAR();
    __builtin_amdgcn_s_setprio(1);
    MMA_H(1, 0);
    __builtin_amdgcn_s_setprio(0);
    SBAR();
    // ---- phase 3: read B1; wm=0 waves stage A-q0(kt+2)
    LDS_B8(1, bb);
    stage_A(kt + 2, 0);
    SBAR();
    __builtin_amdgcn_s_setprio(1);
    MMA_H(1, 1);
    __builtin_amdgcn_s_setprio(0);
    SBAR();
    // ---- phase 4: wm=1 waves stage A-q1(kt+2)
    stage_A(kt + 2, 1);
    SBAR();
    __builtin_amdgcn_s_setprio(1);
    MMA_H(0, 1);
    __builtin_amdgcn_s_setprio(0);
    SBAR();
    if (kt + 2 < nkt) { asm volatile("s_waitcnt vmcnt(4)" ::: "memory"); }
    else              { asm volatile("s_waitcnt vmcnt(0)" ::: "memory"); }
    SBAR(); BARR(); SBAR();  // the ONE barrier per K-tile
  }

#pragma unroll
  for (int i = 0; i < 4; ++i)
#pragma unroll
    for (int j = 0; j < 4; ++j)
#pragma unroll
      for (int r = 0; r < 4; ++r) {
        size_t row = m0 + wm * 64 + i * 16 + quad * 4 + r;
        size_t col = n0 + wn * 64 + j * 16 + l15;
        if (MODE == 1)
          ((float*)C0)[row * N + col] = acc[i][j][r];
        else
          ((ushort_t*)C0)[row * N + col] = f2b(acc[i][j][r]);
      }
}

// ---------------------------------------------------------------------------
// Fused mid (one launch): blocks [0,4096) norm_rope; [4096,5120) w_out^T
// transpose into the dead wvT slot (V-proj already consumed wvT).
// ---------------------------------------------------------------------------
__global__ __launch_bounds__(256) void fused_mid(ushort_t* __restrict__ Q,
                                                 ushort_t* __restrict__ Kb,
                                                 const float* __restrict__ gain,
                                                 const float* __restrict__ w_out,
                                                 ushort_t* __restrict__ woutT) {
  __shared__ ushort_t tile[64][72];
  const int bid = blockIdx.x;
  const int tid = threadIdx.x;
  if (bid >= 4096) {
    int t = bid - 4096;
    transpose_body(w_out, woutT, DM_, DM_, 0, t & 31, t >> 5, tile, tid);
    return;
  }
  const int wave = tid >> 6, lane = tid & 63;
  const int g16 = lane >> 4, sl = lane & 15;
  const int idx = (bid * 4 + wave) * 4 + g16;  // ((b*S+s)*H + h)
  const int h = idx & 15;
  const int s = (idx >> 4) & (S_ - 1);
  const size_t off = (size_t)(idx >> 4) * DM_ + h * DH_ + sl * 4;

  ushort_t qv1[4], qv2[4], kv1[4], kv2[4];
  *(uint2*)qv1 = *(const uint2*)(Q + off);
  *(uint2*)qv2 = *(const uint2*)(Q + off + 64);
  *(uint2*)kv1 = *(const uint2*)(Kb + off);
  *(uint2*)kv2 = *(const uint2*)(Kb + off + 64);

  float q1[4], q2[4], k1[4], k2[4];
  float sq = 0.f, sk = 0.f;
#pragma unroll
  for (int e = 0; e < 4; ++e) {
    q1[e] = b2f(qv1[e]); q2[e] = b2f(qv2[e]);
    k1[e] = b2f(kv1[e]); k2[e] = b2f(kv2[e]);
    sq += q1[e] * q1[e] + q2[e] * q2[e];
    sk += k1[e] * k1[e] + k2[e] * k2[e];
  }
#pragma unroll
  for (int o = 1; o < 16; o <<= 1) {
    sq += __shfl_xor(sq, o, 64);
    sk += __shfl_xor(sk, o, 64);
  }
  float rq = rsqrtf(sq + 1e-6f), rk = rsqrtf(sk + 1e-6f);
  const float g = gain[h] * 1.44269504f;  // fold log2(e): attn uses exp2
  const bool roped = (h & 1) == 0;        // ROPE_MASK tiles [1,0] over heads
#pragma unroll
  for (int e = 0; e < 4; ++e) {
    float a = q1[e] * rq, bq = q2[e] * rq;
    float c_ = k1[e] * rk, dk = k2[e] * rk;
    if (roped) {
      int j = sl * 4 + e;
      float invf = exp2f((float)j * -0.20762050593f);  // log2(10000)/64
      float th = (float)s * invf;
      float cc = cosf(th), sn = sinf(th);
      float na = a * cc - bq * sn, nb = a * sn + bq * cc;
      float nc = c_ * cc - dk * sn, nd = c_ * sn + dk * cc;
      a = na; bq = nb; c_ = nc; dk = nd;
    }
    qv1[e] = f2b(a * g); qv2[e] = f2b(bq * g);
    kv1[e] = f2b(c_);    kv2[e] = f2b(dk);
  }
  *(uint2*)(Q + off)       = *(const uint2*)qv1;
  *(uint2*)(Q + off + 64)  = *(const uint2*)qv2;
  *(uint2*)(Kb + off)      = *(const uint2*)kv1;
  *(uint2*)(Kb + off + 64) = *(const uint2*)kv2;
}

// ---------------------------------------------------------------------------
// Flash attention v3: balanced tile pairs {p, 31-p}, fixed-max softmax
// (exp2 form, log2e pre-folded into q-gain), double-buffered K/V, per-wave
// Ps, 1 barrier/iter. V layout: [dim][b*S+s]. Y written in place over Q.
// Grid (bh, p): XCD = bh%8 -> per-XCD K/V working set fits its 4MB L2.
// ---------------------------------------------------------------------------
__global__ __launch_bounds__(256, 2) void attn(ushort_t* __restrict__ QY,
                                               const ushort_t* __restrict__ Kg,
                                               const ushort_t* __restrict__ Vg) {
  __shared__ alignas(16) ushort_t Ks[2][64 * 128];
  __shared__ alignas(16) ushort_t Vs[2][128 * 64];
  __shared__ alignas(16) ushort_t Ps[2][4][16 * 64];

  const float M0 = 18.755035531f;  // 13 * log2(e)
  const int tid = threadIdx.x;
  const int wave = tid >> 6, lane = tid & 63;
  const int l15 = lane & 15, quad = lane >> 4;
  const int bh = blockIdx.x;
  const int b = bh >> 4, h = bh & 15;
  const int p = blockIdx.y;
  const int qt[2] = {p, 31 - p};

  const ushort_t* Kgb = Kg + (size_t)b * S_ * DM_ + h * DH_;
  const ushort_t* Vgb = Vg + (size_t)(h * DH_) * (B_ * S_) + b * S_;

  short8 aq[2][4];
#pragma unroll
  for (int t = 0; t < 2; ++t) {
    const ushort_t* Qg =
        QY + (size_t)(b * S_ + qt[t] * 64 + wave * 16 + l15) * DM_ + h * DH_;
#pragma unroll
    for (int ks = 0; ks < 4; ++ks)
      aq[t][ks] = *(const short8*)(Qg + ks * 32 + quad * 8);
  }

  float lsum[2][4] = {{0.f, 0.f, 0.f, 0.f}, {0.f, 0.f, 0.f, 0.f}};
  floatx4 zero = {0.f, 0.f, 0.f, 0.f};
  floatx4 oacc[2][8];
#pragma unroll
  for (int t = 0; t < 2; ++t)
#pragma unroll
    for (int d = 0; d < 8; ++d) oacc[t][d] = zero;

  const int krow_in = lane >> 4, ksd = lane & 15;
  const int vrow_in = lane >> 3, vsd = lane & 7;

  auto stage = [&](int kt, int bf) {
#pragma unroll
    for (int i = 0; i < 4; ++i) {
      int c = wave * 4 + i;
      {
        int r = c * 4 + krow_in;
        int sg = ksd ^ (r & 7);
        __builtin_amdgcn_global_load_lds(
            AS1(Kgb + (size_t)(kt * 64 + r) * DM_ + sg * 8),
            AS3((char*)Ks[bf] + c * 1024), 16, 0, 0);
      }
      {
        int r = c * 8 + vrow_in;
        int sg = vsd ^ (r & 7);
        __builtin_amdgcn_global_load_lds(
            AS1(Vgb + (size_t)r * (B_ * S_) + kt * 64 + sg * 8),
            AS3((char*)Vs[bf] + c * 1024), 16, 0, 0);
      }
    }
  };

  stage(0, 0);

  for (int kt = 0; kt <= qt[1]; ++kt) {
    const int cur = kt & 1;
    __syncthreads();
    if (kt < qt[1]) stage(kt + 1, cur ^ 1);

#pragma unroll
    for (int t = 0; t < 2; ++t) {
      if (t == 0 && kt > qt[0]) continue;
      floatx4 sacc[4];
#pragma unroll
      for (int j = 0; j < 4; ++j) sacc[j] = zero;
#pragma unroll
      for (int ks = 0; ks < 4; ++ks) {
#pragma unroll
        for (int j = 0; j < 4; ++j) {
          int row = j * 16 + l15;
          int sl = (ks * 4 + quad) ^ (row & 7);
          short8 bk = *(const short8*)&Ks[cur][row * 128 + sl * 8];
          sacc[j] = __builtin_amdgcn_mfma_f32_16x16x32_bf16(aq[t][ks], bk, sacc[j], 0, 0, 0);
        }
      }
      if (kt == qt[t]) {
#pragma unroll
        for (int j = 0; j < 4; ++j)
#pragma unroll
          for (int r = 0; r < 4; ++r) {
            int key = j * 16 + l15;
            int qr = wave * 16 + quad * 4 + r;
            if (key > qr) sacc[j][r] = -1e30f;
          }
      }
#pragma unroll
      for (int j = 0; j < 4; ++j)
#pragma unroll
        for (int r = 0; r < 4; ++r) {
          float pv = fast_exp2(sacc[j][r] - M0);
          sacc[j][r] = pv;
          lsum[t][r] += pv;
        }
#pragma unroll
      for (int j = 0; j < 4; ++j)
#pragma unroll
        for (int r = 0; r < 4; ++r) {
          int row = quad * 4 + r;
          int col = j * 16 + l15;
          int g = col >> 3, w = col & 7;
          Ps[t][wave][row * 64 + ((g ^ (row & 7)) << 3) + w] = f2b(sacc[j][r]);
        }
#pragma unroll
      for (int ks2 = 0; ks2 < 2; ++ks2) {
        short8 ap = *(const short8*)&Ps[t][wave][l15 * 64 +
                                                (((ks2 * 4 + quad) ^ (l15 & 7)) << 3)];
#pragma unroll
        for (int d = 0; d < 8; ++d) {
          int row = d * 16 + l15;
          int sl = (ks2 * 4 + quad) ^ (row & 7);
          short8 bv = *(const short8*)&Vs[cur][row * 64 + sl * 8];
          oacc[t][d] = __builtin_amdgcn_mfma_f32_16x16x32_bf16(ap, bv, oacc[t][d], 0, 0, 0);
        }
      }
    }
  }

#pragma unroll
  for (int t = 0; t < 2; ++t) {
#pragma unroll
    for (int r = 0; r < 4; ++r) {
#pragma unroll
      for (int o = 1; o < 16; o <<= 1) lsum[t][r] += __shfl_xor(lsum[t][r], o, 64);
      float inv = 1.0f / lsum[t][r];
      size_t row = (size_t)(b * S_ + qt[t] * 64 + wave * 16 + quad * 4 + r);
#pragma unroll
      for (int d = 0; d < 8; ++d) {
        size_t col = (size_t)h * DH_ + d * 16 + l15;
        QY[row * DM_ + col] = f2b(oacc[t][d][r] * inv);
      }
    }
  }
}

// ---------------------------------------------------------------------------
extern "C" void kernel_launch(void* const* d_in, const int* in_sizes, int n_in,
                              void* d_out, int out_size, void* d_ws, size_t ws_size,
                              hipStream_t stream) {
  const float* x      = (const float*)d_in[0];
  const float* w_qkv  = (const float*)d_in[1];
  const float* w_out  = (const float*)d_in[2];
  const float* q_gain = (const float*)d_in[3];
  float* out = (float*)d_out;

  // ws (56 MiB): Qraw | Kraw | Vt | wvT (wvT slot reused for w_out^T later)
  // d_out (32 MiB) doubles as scratch until the final GEMM: xbf | wqkT
  char* ws = (char*)d_ws;
  const size_t bsd = (size_t)B_ * S_ * DM_;  // 8,388,608 elems
  ushort_t* Qraw = (ushort_t*)ws;
  ushort_t* Kraw = Qraw + bsd;
  ushort_t* Vt   = Kraw + bsd;                    // [dim][b*S+s]
  ushort_t* wvT  = Vt + bsd;                      // [2048][2048]
  ushort_t* xbf  = (ushort_t*)d_out;              // [4096][2048] bf16
  ushort_t* wqkT = xbf + bsd;                     // [4096][2048] bf16 (Wq|Wk)^T
  ushort_t* woutT = wvT;                          // wvT dead after V-proj

  // 1: convert + both w_qkv transposes
  fused_pre<<<dim3(7168), 256, 0, stream>>>(x, w_qkv, xbf, wqkT, wvT);
  // 2: Q and K in one fused GEMM (split-C epilogue), 256^2 deep pipeline
  gemm_bt_256<2><<<dim3(16, 16), 512, 0, stream>>>(xbf, wqkT, Qraw, Kraw,
                                                   B_ * S_, 2 * DM_, DM_);
  // 3: V^T = WvT * x^T -> Vt[dim][b*S+s] (512 blocks = 2/CU)
  gemm_bt_128<0><<<dim3(32, 16), 256, 0, stream>>>(wvT, xbf, Vt,
                                                   DM_, B_ * S_, DM_);
  // 4: norm+rope (Q,K) + w_out^T into dead wvT slot
  fused_mid<<<dim3(5120), 256, 0, stream>>>(Qraw, Kraw, q_gain, w_out, woutT);
  // 5: attention (Y over Qraw)
  attn<<<dim3(B_ * H_, S_ / 128), 256, 0, stream>>>(Qraw, Kraw, Vt);
  // 6: out = Y @ w_out (f32 over d_out)
  gemm_bt_128<1><<<dim3(16, 32), 256, 0, stream>>>(Qraw, woutT, out,
                                                   B_ * S_, DM_, DM_);
}